// Round 2
// baseline (379.970 us; speedup 1.0000x reference)
//
#include <hip/hip_runtime.h>
#include <hip/hip_bf16.h>

#define B_ 2
#define L_ 2048
#define D_ 512
#define P_ 32
#define M_ 1024
#define H_ 8
#define HD_ 64
#define WIN_ 256
#define S_ (P_ + L_)        // 2080
#define N_ (B_ * S_)        // 4160

typedef __hip_bfloat16 bf16;
typedef __attribute__((ext_vector_type(8))) short short8;
typedef __attribute__((ext_vector_type(4))) short short4_t;
typedef __attribute__((ext_vector_type(4))) float f32x4;

__device__ __forceinline__ int imin(int a, int b) { return a < b ? a : b; }
__device__ __forceinline__ int imax(int a, int b) { return a > b ? a : b; }

__device__ __forceinline__ float ld_in(const void* p, long i, int f32) {
    return f32 ? ((const float*)p)[i]
               : __bfloat162float(((const bf16*)p)[i]);
}

__device__ __forceinline__ short bfbits(float f) {
    bf16 h = __float2bfloat16(f);
    short s;
    __builtin_memcpy(&s, &h, 2);
    return s;
}

__device__ __forceinline__ float b2f(short s) {
    unsigned int u = ((unsigned int)(unsigned short)s) << 16;
    float f;
    __builtin_memcpy(&f, &u, 4);
    return f;
}

// async global->LDS 16B (m97).  LDS dst wave-uniform base; HW adds lane*16.
__device__ __forceinline__ void gload_lds16(const void* g, void* l) {
    __builtin_amdgcn_global_load_lds(
        (const __attribute__((address_space(1))) unsigned int*)g,
        (__attribute__((address_space(3))) unsigned int*)l, 16, 0, 0);
}

#define F_OW  10   // runtime out-dtype flag (published by prep)

// Free per-wave dtype detect (proven r13): ballot over 128 sampled u16s.
__device__ __forceinline__ int wave_detect(const void* p, int tid) {
    const unsigned short* u = (const unsigned short*)p;
    const int lane = tid & 63;
    unsigned short v0 = u[lane * 2], v1 = u[lane * 2 + 1];
    int hit = ((((v0 >> 7) & 0xFF) >= 0xC0) || (((v1 >> 7) & 0xFF) >= 0xC0)) ? 1 : 0;
    unsigned long long b = __ballot(hit);
    return (__popcll(b) >= 2) ? 1 : 0;
}

// ---------------------------------------------------------------------------
// Fused prep (ballot dtype detect): [0,8320) build_combined ;
// [8320,10368) convert mem_keys ; [10368,10880) weights -> bf16 ;
// [10880,10888) colsums of attn_Wq/k/v + out_W (bf16-rounded to match WT) ;
// [10888,10890) zero LN row-stat buffers (re-zeroed every launch).
// ---------------------------------------------------------------------------
struct Ptr8 { const void* p[8]; };

__global__ __launch_bounds__(256) void prep_kernel(
    const void* __restrict__ x, const void* __restrict__ pm,
    const void* __restrict__ mk, Ptr8 wptrs,
    bf16* __restrict__ comb, bf16* __restrict__ mkbf, bf16* __restrict__ WT,
    bf16* __restrict__ BigB, int* __restrict__ flags,
    float* __restrict__ cs, float* __restrict__ st)
{
    __shared__ short T[64][65];
    const int blk = blockIdx.x;
    const int tid = threadIdx.x;
    if (blk < 8320) {
        int i = blk * 256 + tid;
        int d = i & (D_ - 1);
        int r = i >> 9;
        int s = r % S_;
        int b = r / S_;
        const void* src = (s < P_) ? pm : x;
        const int f = wave_detect(src, tid);
        float v;
        if (s < P_) v = ld_in(pm, (long)s * D_ + d, f);
        else        v = ld_in(x, ((long)(b * L_ + (s - P_))) * D_ + d, f);
        comb[i] = __float2bfloat16(v);
        return;
    }
    if (blk < 10368) {
        const int f = wave_detect(mk, tid);
        int i = (blk - 8320) * 256 + tid;
        mkbf[i] = __float2bfloat16(ld_in(mk, i, f));
        return;
    }
    if (blk >= 10880) {
        const int t2 = blk - 10880;
        if (t2 < 8) {
            // column sums: gcol 0..1535 -> attn_Wq/Wk/Wv; 1536..2047 -> out_W
            const int gcol = t2 * 256 + tid;
            const void* src;
            int colw;
            if (gcol < 1536) { src = wptrs.p[3 + (gcol >> 9)]; colw = gcol & 511; }
            else             { src = wptrs.p[7];               colw = gcol - 1536; }
            const int f = wave_detect(src, tid);
            float s = 0.f;
            #pragma unroll 8
            for (int k = 0; k < 512; ++k)
                s += b2f(bfbits(ld_in(src, (long)k * 512 + colw, f)));
            cs[gcol] = s;
        } else {
            // zero both stat blocks: 2 * N_ * 2 floats = 16640
            const int t3 = (t2 - 8) * 256 + tid;
            for (int i = t3; i < 2 * N_ * 2; i += 512) st[i] = 0.f;
        }
        return;
    }
    const int t = blk - 10368;
    const int widx = t >> 6;
    const int rem = t & 63;
    const int r0 = (rem >> 3) * 64, c0 = (rem & 7) * 64;
    const void* in = wptrs.p[widx];
    const int flag = wave_detect(in, tid);
    if (widx == 7 && rem == 0 && tid == 0) flags[F_OW] = flag;
    short* o;
    if (widx == 0)      o = (short*)WT;
    else if (widx == 2) o = (short*)(WT + 262144);
    else if (widx == 1) o = (short*)BigB;
    else                o = (short*)(WT + (long)(widx - 1) * 262144);
    if (widx == 0 || widx == 2) {
        #pragma unroll
        for (int i = 0; i < 2; ++i) {
            int ch = tid + i * 256;
            int r = ch >> 3, c8 = (ch & 7) * 8;
            long base = (long)(r0 + r) * 512 + c0 + c8;
            short8 v;
            if (flag) {
                const float4 f0 = *reinterpret_cast<const float4*>((const float*)in + base);
                const float4 f1 = *reinterpret_cast<const float4*>((const float*)in + base + 4);
                v[0]=bfbits(f0.x); v[1]=bfbits(f0.y); v[2]=bfbits(f0.z); v[3]=bfbits(f0.w);
                v[4]=bfbits(f1.x); v[5]=bfbits(f1.y); v[6]=bfbits(f1.z); v[7]=bfbits(f1.w);
            } else {
                v = *reinterpret_cast<const short8*>((const short*)in + base);
            }
            *reinterpret_cast<short8*>(o + base) = v;
        }
        return;
    }
    #pragma unroll
    for (int i = 0; i < 2; ++i) {
        int ch = tid + i * 256;
        int r = ch >> 3, c8 = (ch & 7) * 8;
        long base = (long)(r0 + r) * 512 + c0 + c8;
        if (flag) {
            const float4 f0 = *reinterpret_cast<const float4*>((const float*)in + base);
            const float4 f1 = *reinterpret_cast<const float4*>((const float*)in + base + 4);
            T[r][c8+0]=bfbits(f0.x); T[r][c8+1]=bfbits(f0.y); T[r][c8+2]=bfbits(f0.z); T[r][c8+3]=bfbits(f0.w);
            T[r][c8+4]=bfbits(f1.x); T[r][c8+5]=bfbits(f1.y); T[r][c8+6]=bfbits(f1.z); T[r][c8+7]=bfbits(f1.w);
        } else {
            const short8 v = *reinterpret_cast<const short8*>((const short*)in + base);
            #pragma unroll
            for (int k = 0; k < 8; ++k) T[r][c8+k] = v[k];
        }
    }
    __syncthreads();
    #pragma unroll
    for (int i = 0; i < 2; ++i) {
        int ch = tid + i * 256;
        int n = ch >> 3, c8 = (ch & 7) * 8;
        #pragma unroll
        for (int k = 0; k < 8; ++k)
            o[(long)(c0 + n) * 512 + r0 + c8 + k] = T[c8 + k][n];
    }
}

// ---------------------------------------------------------------------------
// Batched bf16 transpose: in (z, R, C) -> out (z, C, R).  (only W1 -> W1T now)
// ---------------------------------------------------------------------------
__global__ __launch_bounds__(256) void transpose_b_kernel(
    const bf16* __restrict__ in_, bf16* __restrict__ out_, int R, int C)
{
    const short* in = (const short*)(in_ + (long)blockIdx.z * R * C);
    short* out = (short*)(out_ + (long)blockIdx.z * C * R);
    __shared__ short T[64][65];
    const int r0 = blockIdx.y * 64, c0 = blockIdx.x * 64;
    const int tid = threadIdx.x;
    #pragma unroll
    for (int i = 0; i < 2; ++i) {
        int ch = tid + i * 256;
        int r = ch >> 3, c8 = (ch & 7) * 8;
        int row = imin(r0 + r, R - 1);
        const short8 v = *reinterpret_cast<const short8*>(in + (long)row * C + c0 + c8);
        #pragma unroll
        for (int k = 0; k < 8; ++k) T[r][c8+k] = v[k];
    }
    __syncthreads();
    #pragma unroll
    for (int i = 0; i < 2; ++i) {
        int ch = tid + i * 256;
        int n = ch >> 3, c8 = (ch & 7) * 8;
        #pragma unroll
        for (int k = 0; k < 8; ++k) {
            int col = r0 + c8 + k;
            if (col < R) out[(long)(c0 + n) * R + col] = T[c8 + k][n];
        }
    }
}

// ---------------------------------------------------------------------------
// 64-row MFMA GEMM, UN k-subtiles per barrier pair (proven r7-r13).
// CMODE: 1 bf16 z-strided   2 runtime dtype (flags[F_OW]) (N_,512)
//        7 attn: grp0/1 (q,k) -> (B,H,S,HD) row-major; grp2 (v) -> C2 as
//        (B,H,HD,S) via in-LDS transpose.
// STAT=1: accumulate LN row stats (sum, sumsq of bf16-rounded C) into st.
// FIX=1: apply LN-algebraic fixup: val = inv_r * (val - mu_r * cs[col]).
// ---------------------------------------------------------------------------
template<int CMODE, int BN, int UN, int STAT, int FIX>
__global__ __launch_bounds__(256, 4) void gemm64(
    const bf16* __restrict__ A, const bf16* __restrict__ Bb,
    void* __restrict__ C0, void* __restrict__ C1, void* __restrict__ C2,
    const int* __restrict__ flags,
    float* __restrict__ st, const float* __restrict__ cs,
    int Mdim, int Kdim, int lda, int ldb, int ldc,
    long sA, long sB, long sC, int SK)
{
    constexpr int NH = BN / 64;
    __shared__ __align__(16) bf16 SM[UN * 2048 + UN * BN * 32];
    bf16* const As = SM;
    bf16* const Bs = SM + UN * 2048;
    const int tid = threadIdx.x, lane = tid & 63, wid = tid >> 6;
    constexpr int WNc = BN / 4;
    constexpr int NJ = WNc / 16;
    const int m0 = blockIdx.y * 64, n0 = blockIdx.x * BN;
    const int z = blockIdx.z;
    const int bz = z / SK, kc = z - bz * SK;
    const int kLen = Kdim / SK;
    const int kBeg = kc * kLen;
    const bf16* Ab = A + (long)bz * sA;
    const bf16* Bp = Bb + (long)bz * sB;

    const int sRow = tid >> 2, c8 = (tid & 3) * 8;
    int aRow = m0 + sRow;
    if (aRow >= Mdim) aRow = Mdim - 1;
    const bf16* aS = Ab + (long)aRow * lda + c8 + kBeg;
    const bf16* bS[NH];
    #pragma unroll
    for (int h = 0; h < NH; ++h)
        bS[h] = Bp + (long)(n0 + sRow + h * 64) * ldb + c8 + kBeg;

    const int g8 = (lane >> 4) * 8, l15 = lane & 15;
    f32x4 acc[4][NJ] = {};

    for (int k0 = 0; k0 < kLen; k0 += UN * 32) {
        #pragma unroll
        for (int t = 0; t < UN; ++t) {
            gload_lds16(aS + k0 + t * 32, As + t * 2048 + wid * 512);
            #pragma unroll
            for (int h = 0; h < NH; ++h)
                gload_lds16(bS[h] + k0 + t * 32, Bs + t * BN * 32 + h * 2048 + wid * 512);
        }
        __syncthreads();
        #pragma unroll
        for (int t = 0; t < UN; ++t) {
            short8 af[4], bfr[NJ];
            #pragma unroll
            for (int mi = 0; mi < 4; ++mi)
                af[mi] = *reinterpret_cast<const short8*>(
                    &As[t * 2048 + (mi * 16 + l15) * 32 + g8]);
            #pragma unroll
            for (int nj = 0; nj < NJ; ++nj)
                bfr[nj] = *reinterpret_cast<const short8*>(
                    &Bs[t * BN * 32 + (wid * WNc + nj * 16 + l15) * 32 + g8]);
            #pragma unroll
            for (int mi = 0; mi < 4; ++mi)
                #pragma unroll
                for (int nj = 0; nj < NJ; ++nj)
                    acc[mi][nj] = __builtin_amdgcn_mfma_f32_16x16x32_bf16(
                        af[mi], bfr[nj], acc[mi][nj], 0, 0, 0);
        }
        __syncthreads();
    }

    const int g4 = (lane >> 4) * 4;

    // LN-algebraic fixup (consumer side): val = inv_r*(val - mu_r*cs[col])
    if constexpr (FIX) {
        float csv[NJ];
        #pragma unroll
        for (int nj = 0; nj < NJ; ++nj)
            csv[nj] = cs[n0 + wid * WNc + nj * 16 + l15];
        #pragma unroll
        for (int mi = 0; mi < 4; ++mi) {
            #pragma unroll
            for (int r = 0; r < 4; ++r) {
                int row = m0 + mi * 16 + g4 + r;
                float sv = st[(long)row * 2], qv = st[(long)row * 2 + 1];
                float mu = sv * (1.f / 512.f);
                float iv = rsqrtf(qv * (1.f / 512.f) - mu * mu + 1e-5f);
                #pragma unroll
                for (int nj = 0; nj < NJ; ++nj)
                    acc[mi][nj][r] = iv * (acc[mi][nj][r] - mu * csv[nj]);
            }
        }
    }

    // LN row-stat accumulation (producer side), on bf16-rounded values.
    if constexpr (STAT) {
        #pragma unroll
        for (int mi = 0; mi < 4; ++mi)
            #pragma unroll
            for (int nj = 0; nj < NJ; ++nj)
                #pragma unroll
                for (int r = 0; r < 4; ++r)
                    acc[mi][nj][r] = b2f(bfbits(acc[mi][nj][r]));
        float* red = (float*)SM;
        #pragma unroll
        for (int mi = 0; mi < 4; ++mi) {
            #pragma unroll
            for (int r = 0; r < 4; ++r) {
                float sv = 0.f, qv = 0.f;
                #pragma unroll
                for (int nj = 0; nj < NJ; ++nj) {
                    float v = acc[mi][nj][r];
                    sv += v; qv += v * v;
                }
                #pragma unroll
                for (int off = 1; off < 16; off <<= 1) {
                    sv += __shfl_xor(sv, off, 64);
                    qv += __shfl_xor(qv, off, 64);
                }
                if (l15 == 0) {
                    int rr = mi * 16 + g4 + r;
                    red[(wid * 64 + rr) * 2]     = sv;
                    red[(wid * 64 + rr) * 2 + 1] = qv;
                }
            }
        }
        __syncthreads();
        if (tid < 128) {
            int rr = tid & 63, which = tid >> 6;
            if (m0 + rr < Mdim) {
                const int zrow = (int)(sC / (long)ldc) * z;
                float a = red[rr * 2 + which] + red[(64 + rr) * 2 + which]
                        + red[(128 + rr) * 2 + which] + red[(192 + rr) * 2 + which];
                atomicAdd(&st[((long)(zrow + m0 + rr)) * 2 + which], a);
            }
        }
    }

    const int oflag = (CMODE == 2) ? flags[F_OW] : 0;
    const int grp = n0 >> 9;

    if (CMODE == 7 && grp == 2) {
        // v projection -> vhT (B,H,HD,S) via in-LDS transpose.
        bf16* T = SM;
        if constexpr (STAT) __syncthreads();
        #pragma unroll
        for (int mi = 0; mi < 4; ++mi)
            #pragma unroll
            for (int nj = 0; nj < NJ; ++nj)
                #pragma unroll
                for (int r = 0; r < 4; ++r)
                    T[(wid * WNc + nj * 16 + l15) * 72 + mi * 16 + g4 + r] =
                        __float2bfloat16(acc[mi][nj][r]);
        __syncthreads();
        #pragma unroll
        for (int it = 0; it < 2; ++it) {
            int idx = tid + it * 256;
            int d = idx >> 2;            // 0..127
            int sc = (idx & 3) * 16;     // 0..48; 16-chunks never cross s=2080
            int grow = m0 + sc;
            int b = grow / S_;
            int s = grow - b * S_;
            int dg = (n0 - 1024) + d;
            int h = dg >> 6, dd = dg & 63;
            bf16* dst = (bf16*)C2 + ((long)((b * H_ + h) * HD_ + dd)) * S_ + s;
            *reinterpret_cast<short8*>(dst) =
                *reinterpret_cast<const short8*>(&T[d * 72 + sc]);
            *reinterpret_cast<short8*>(dst + 8) =
                *reinterpret_cast<const short8*>(&T[d * 72 + sc + 8]);
        }
        return;
    }

    #pragma unroll
    for (int mi = 0; mi < 4; ++mi) {
        #pragma unroll
        for (int nj = 0; nj < NJ; ++nj) {
            #pragma unroll
            for (int r = 0; r < 4; ++r) {
                int row = m0 + mi * 16 + g4 + r;
                int col = n0 + wid * WNc + nj * 16 + l15;
                if (row >= Mdim) continue;
                float val = acc[mi][nj][r];
                if (CMODE == 1) {
                    ((bf16*)C0)[(long)z * sC + (long)row * ldc + col] = __float2bfloat16(val);
                } else if (CMODE == 2) {
                    long idx = (long)row * 512 + col;
                    if (oflag) ((float*)C0)[idx] = val;
                    else       ((bf16*)C0)[idx] = __float2bfloat16(val);
                } else {            // CMODE 7, grp 0/1
                    int b = row / S_, s = row - b * S_;
                    int c = col - (grp << 9);
                    int h = c >> 6, d = c & 63;
                    long idx = ((long)(b * H_ + h) * S_ + s) * HD_ + d;
                    if (grp == 0)      ((bf16*)C0)[idx] = __float2bfloat16(val);
                    else               ((bf16*)C1)[idx] = __float2bfloat16(val);
                }
            }
        }
    }
}

// ---------------------------------------------------------------------------
// 128x128 MFMA GEMM (m97 shape; r5-proven structure), UN=2 subtiles.
// Mega GEMM only: grid (20, 33).  A (M,K) lda; B (N,K) ldb.
// Epilogue: n0<512 -> vT (B,D,S) via in-LDS transpose; n0>=512 -> Lg.
// ---------------------------------------------------------------------------
__global__ __launch_bounds__(256) void gemm128_mega(
    const bf16* __restrict__ A, const bf16* __restrict__ Bb,
    void* __restrict__ C0, void* __restrict__ C1,
    int Mdim, int Kdim, int lda, int ldb)
{
    __shared__ __align__(16) bf16 SM[4 * 4096];
    bf16* const As = SM;
    bf16* const Bs = SM + 2 * 4096;
    const int tid = threadIdx.x, lane = tid & 63, wid = tid >> 6;
    const int wr = wid >> 1, wc = wid & 1;
    const int m0 = blockIdx.y * 128, n0 = blockIdx.x * 128;

    int aRow0 = m0 + (tid >> 2);
    int aRow1 = aRow0 + 64;
    if (aRow0 >= Mdim) aRow0 = Mdim - 1;
    if (aRow1 >= Mdim) aRow1 = Mdim - 1;
    const int c8 = (tid & 3) * 8;
    const bf16* aSrc0 = A + (long)aRow0 * lda + c8;
    const bf16* aSrc1 = A + (long)aRow1 * lda + c8;
    const bf16* bSrc0 = Bb + (long)(n0 + (tid >> 2)) * ldb + c8;
    const bf16* bSrc1 = bSrc0 + 64 * (long)ldb;

    const int g8 = (lane >> 4) * 8, l15 = lane & 15;
    f32x4 acc[4][4] = {};

    for (int k0 = 0; k0 < Kdim; k0 += 64) {
        #pragma unroll
        for (int t = 0; t < 2; ++t) {
            gload_lds16(aSrc0 + k0 + t * 32, As + t * 4096 + wid * 512);
            gload_lds16(aSrc1 + k0 + t * 32, As + t * 4096 + 2048 + wid * 512);
            gload_lds16(bSrc0 + k0 + t * 32, Bs + t * 4096 + wid * 512);
            gload_lds16(bSrc1 + k0 + t * 32, Bs + t * 4096 + 2048 + wid * 512);
        }
        __syncthreads();
        #pragma unroll
        for (int t = 0; t < 2; ++t) {
            short8 af[4], bfr[4];
            #pragma unroll
            for (int mi = 0; mi < 4; ++mi)
                af[mi] = *reinterpret_cast<const short8*>(
                    &As[t * 4096 + (wr * 64 + mi * 16 + l15) * 32 + g8]);
            #pragma unroll
            for (int nj = 0; nj < 4; ++nj)
                bfr[nj] = *reinterpret_cast<const short8*>(
                    &Bs[t * 4096 + (wc * 64 + nj * 16 + l15) * 32 + g8]);
            #pragma unroll
            for (int mi = 0; mi < 4; ++mi)
                #pragma unroll
                for (int nj = 0; nj < 4; ++nj)
                    acc[mi][nj] = __builtin_amdgcn_mfma_f32_16x16x32_bf16(
                        af[mi], bfr[nj], acc[mi][nj], 0, 0, 0);
        }
        __syncthreads();
    }

    if (n0 >= 512) {
        #pragma unroll
        for (int mi = 0; mi < 4; ++mi) {
            #pragma unroll
            for (int nj = 0; nj < 4; ++nj) {
                #pragma unroll
                for (int r = 0; r < 4; ++r) {
                    int row = m0 + wr * 64 + mi * 16 + (lane >> 4) * 4 + r;
                    int col = n0 + wc * 64 + nj * 16 + l15;
                    if (row >= Mdim) continue;
                    ((bf16*)C0)[(long)row * 2048 + col - 512] =
                        __float2bfloat16(acc[mi][nj][r]);
                }
            }
        }
        return;
    }

    // v region -> vT (B, 512, S_) via in-LDS transpose, two 64-col passes.
    {
        bf16* T = SM;
        const int g4 = (lane >> 4) * 4;
        #pragma unroll
        for (int p = 0; p < 2; ++p) {
            __syncthreads();
            if (wc == p) {
                #pragma unroll
                for (int mi = 0; mi < 4; ++mi)
                    #pragma unroll
                    for (int nj = 0; nj < 4; ++nj)
                        #pragma unroll
                        for (int r = 0; r < 4; ++r)
                            T[(nj * 16 + l15) * 136 + wr * 64 + mi * 16 + g4 + r] =
                                __float2bfloat16(acc[mi][nj][r]);
            }
            __syncthreads();
            #pragma unroll
            for (int it = 0; it < 2; ++it) {
                int idx = tid + it * 256;
                int d = idx >> 3;            // 0..63
                int sc = (idx & 7) * 16;     // 0..112; 16-chunks never cross s=2080
                int grow = m0 + sc;
                if (grow >= Mdim) continue;
                int b = grow / S_;
                int s = grow - b * S_;
                bf16* dst = (bf16*)C1 + ((long)b * 512 + n0 + p * 64 + d) * S_ + s;
                *reinterpret_cast<short8*>(dst) =
                    *reinterpret_cast<const short8*>(&T[d * 136 + sc]);
                *reinterpret_cast<short8*>(dst + 8) =
                    *reinterpret_cast<const short8*>(&T[d * 136 + sc + 8]);
            }
        }
    }
}

// ---------------------------------------------------------------------------
// Reduce split-K state partials: Pst bf16 (B*5, 2^19) -> stT bf16 (B,D,M).
// ---------------------------------------------------------------------------
__global__ __launch_bounds__(256) void reduce_state_kernel(
    const bf16* __restrict__ P, bf16* __restrict__ stT)
{
    long g = ((long)blockIdx.x * 256 + threadIdx.x) * 8;
    int b = (int)(g >> 19);
    long dm = g & ((1L << 19) - 1);
    float s[8] = {};
    #pragma unroll
    for (int c = 0; c < 5; ++c) {
        const short8 v = *reinterpret_cast<const short8*>(
            (const short*)P + (((long)(b * 5 + c)) << 19) + dm);
        #pragma unroll
        for (int k = 0; k < 8; ++k) s[k] += b2f(v[k]);
    }
    short8 o;
    #pragma unroll
    for (int k = 0; k < 8; ++k) o[k] = bfbits(s[k]);
    *reinterpret_cast<short8*>((short*)stT + g) = o;
}

// ---------------------------------------------------------------------------
// Row softmax, one wave per row (no barriers).  Lg (N_, 2048) col-stacked
// [k|q]; grid (N_/4, 2).  Writes W1[hf*N_*M + row*M].
// ---------------------------------------------------------------------------
__global__ __launch_bounds__(256) void softmax_rows_kernel(
    const bf16* __restrict__ w, bf16* __restrict__ o)
{
    const int tid = threadIdx.x;
    const int lane = tid & 63;
    const int row = blockIdx.x * 4 + (tid >> 6);
    const int hf = blockIdx.y;
    const short* src = (const short*)w + (long)row * 2048 + hf * 1024 + lane * 16;
    const short8 v0 = *reinterpret_cast<const short8*>(src);
    const short8 v1 = *reinterpret_cast<const short8*>(src + 8);
    float f[16];
    #pragma unroll
    for (int k = 0; k < 8; ++k) { f[k] = b2f(v0[k]); f[8 + k] = b2f(v1[k]); }
    float mx = f[0];
    #pragma unroll
    for (int k = 1; k < 16; ++k) mx = fmaxf(mx, f[k]);
    #pragma unroll
    for (int off = 32; off > 0; off >>= 1) mx = fmaxf(mx, __shfl_xor(mx, off, 64));
    float s = 0.f;
    #pragma unroll
    for (int k = 0; k < 16; ++k) { f[k] = __expf(f[k] - mx); s += f[k]; }
    #pragma unroll
    for (int off = 32; off > 0; off >>= 1) s += __shfl_xor(s, off, 64);
    const float inv = 1.f / s;
    short8 o0, o1;
    #pragma unroll
    for (int k = 0; k < 8; ++k) { o0[k] = bfbits(f[k] * inv); o1[k] = bfbits(f[8 + k] * inv); }
    short* dst = (short*)o + (long)hf * N_ * M_ + (long)row * M_ + lane * 16;
    *reinterpret_cast<short8*>(dst) = o0;
    *reinterpret_cast<short8*>(dst + 8) = o1;
}

// ---------------------------------------------------------------------------
// MFMA flash banded attention, fixed-max softmax (proven r9).  grid (33,H,B).
// ---------------------------------------------------------------------------
#define SC2_ 0.18033688f     // 0.125 * log2(e)
#define MF2_ 11.5415603f     // 8 * log2(e)

#define PRELOAD(JT) do {                                                     \
    _Pragma("unroll")                                                        \
    for (int i = 0; i < 2; ++i) {                                            \
        int ch = tid + i * 256;                                              \
        int r = ch >> 3, cc8 = (ch & 7) * 8;                                 \
        int j = imin((JT) * 64 + r, S_ - 1);                                 \
        kreg[i] = *reinterpret_cast<const short8*>(kb + (long)j * HD_ + cc8);\
        int jc = (JT) * 64 + cc8;                                            \
        if (jc + 8 <= S_) {                                                  \
            vreg[i] = *reinterpret_cast<const short8*>(vb + (long)r * S_ + jc); \
        } else {                                                             \
            short8 v;                                                        \
            _Pragma("unroll")                                                \
            for (int k = 0; k < 8; ++k)                                      \
                v[k] = ((const short*)vb)[(long)r * S_ + imin(jc + k, S_ - 1)]; \
            vreg[i] = v;                                                     \
        }                                                                    \
    }                                                                        \
} while (0)

__global__ __launch_bounds__(256) void flash_attn_kernel(
    const bf16* __restrict__ qh, const bf16* __restrict__ kh,
    const bf16* __restrict__ vhT, bf16* __restrict__ ao)
{
    const int qt = blockIdx.x, h = blockIdx.y, b = blockIdx.z;
    const int tid = threadIdx.x, w = tid >> 6, lane = tid & 63;
    const int g = lane >> 4, l15 = lane & 15, g8 = g * 8;
    const int q0 = qt * 64;
    __shared__ __align__(16) bf16 Qs[64 * 72];
    __shared__ __align__(16) bf16 Ks[64 * 72];
    __shared__ __align__(16) bf16 Vs[64 * 72];
    __shared__ __align__(16) bf16 Ps[4 * 16 * 88];
    const long bh = (long)(b * H_ + h);
    const bf16* qb = qh + bh * S_ * HD_;
    const bf16* kb = kh + bh * S_ * HD_;
    const bf16* vb = vhT + bh * HD_ * S_;

    #pragma unroll
    for (int i = 0; i < 2; ++i) {
        int ch = tid + i * 256;
        int r = ch >> 3, c8 = (ch & 7) * 8;
        int q = imin(q0 + r, S_ - 1);
        *reinterpret_cast<short8*>(&Qs[r * 72 + c8]) =
            *reinterpret_cast<const short8*>(qb + (long)q * HD_ + c8);
    }
    float lrow[4] = {};
    f32x4 O[4] = {};
    const int tstart = imax(0, q0 - (WIN_ - 1)) >> 6;
    const int tend = imin(S_ - 1, q0 + 63 + (WIN_ - 1)) >> 6;

    short8 kreg[2], vreg[2];
    PRELOAD(tstart);
    __syncthreads();
    const short8 aq0 = *reinterpret_cast<const short8*>(&Qs[(w * 16 + l15) * 72 + g8]);
    const short8 aq1 = *reinterpret_cast<const short8*>(&Qs[(w * 16 + l15) * 72 + 32 + g8]);

    for (int jt = tstart; jt <= tend; ++jt) {
        if (jt > tstart) __syncthreads();
        #pragma unroll
        for (int i = 0; i < 2; ++i) {
            int ch = tid + i * 256;
            int r = ch >> 3, c8 = (ch & 7) * 8;
            *reinterpret_cast<short8*>(&Ks[r * 72 + c8]) = kreg[i];
            *reinterpret_cast<short8*>(&Vs[r * 72 + c8]) = vreg[i];
        }
        __syncthreads();
        if (jt < tend) PRELOAD(jt + 1);

        f32x4 s[4] = {};
        __builtin_amdgcn_s_setprio(1);
        #pragma unroll
        for (int nj = 0; nj < 4; ++nj) {
            const short8 b0 = *reinterpret_cast<const short8*>(&Ks[(nj * 16 + l15) * 72 + g8]);
            const short8 b1 = *reinterpret_cast<const short8*>(&Ks[(nj * 16 + l15) * 72 + 32 + g8]);
            s[nj] = __builtin_amdgcn_mfma_f32_16x16x32_bf16(aq0, b0, s[nj], 0, 0, 0);
            s[nj] = __builtin_amdgcn_mfma_f32_16x16x32_bf16(aq1, b1, s[nj], 0, 0, 0);
        }
        __builtin_amdgcn_s_setprio(0);
        #pragma unroll
        for (int nj = 0; nj < 4; ++nj) {
            int j = jt * 64 + nj * 16 + l15;
            #pragma unroll
            for (int r = 0; r < 4; ++r) {
                int q = q0 + w * 16 + g * 4 + r;
                int dd = q - j;
                bool ok = (dd > -WIN_) && (dd < WIN_) && (q < S_) && (j < S_);
                s[nj][r] = ok ? fmaf(s[nj][r], SC2_, -MF2_) : -1e30f;
            }
        }
        #pragma unroll
        for (int r = 0; r < 4; ++r) {
            float ps = 0.f;
            #pragma unroll
            for (int nj = 0; nj < 4; ++nj) {
                float pv = exp2f(s[nj][r]);
                s[nj][r] = pv;
                ps += pv;
            }
            #pragma unroll
            for (int off = 8; off; off >>= 1) ps += __shfl_xor(ps, off, 64);
            lrow[r] += ps;
        }
        #pragma unroll
        for (int nj = 0; nj < 4; ++nj)
            #pragma unroll
            for (int r = 0; r < 4; ++r)
                Ps[w * 1408 + (g * 4 + r) * 88 + nj * 16 + l15] = __float2bfloat16(s[nj][r]);
        const short8 ap0 = *reinterpret_cast<const short8*>(&Ps[w * 1408 + l15 * 88 + g8]);
        const short8 ap1 = *reinterpret_cast<const short8*>(&Ps[w * 1408 + l15 * 88 + 32 + g8]);
        __builtin_amdgcn_s_setprio(1);
        #pragma unroll
        for (int nj = 0; nj < 4; ++nj) {
            const short8 b0 = *reinterpret_cast<const short8*>(&Vs[(nj * 16 + l15) * 72 + g8]);
            const short8 b1 = *reinterpret_cast<const short8*>(&Vs[(nj * 16 + l15) * 72 + 32 + g8]);
            O[nj] = __builtin_amdgcn_mfma_f32_16x16x32_bf16(ap0, b0, O[nj], 0, 0, 0);
            O[nj] = __builtin_amdgcn_mfma_f32_16x16x32_bf16(ap1, b1, O[nj], 0, 0, 0);
        }
        __builtin_amdgcn_s_setprio(0);
    }
    float inv[4];
    #pragma unroll
    for (int r = 0; r < 4; ++r) inv[r] = lrow[r] > 0.f ? 1.f / lrow[r] : 0.f;
    #pragma unroll
    for (int nj = 0; nj < 4; ++nj) {
        #pragma unroll
        for (int r = 0; r < 4; ++r) {
            int q = q0 + w * 16 + g * 4 + r;
            if (q < S_)
                ao[((long)b * S_ + q) * D_ + h * HD_ + nj * 16 + l15] =
                    __float2bfloat16(O[nj][r] * inv[r]);
        }
    }
}

// ---------------------------------------------------------------------------
// Launch (12 dispatches; LN dispatches replaced by STAT/FIX GEMM epilogues)
// ---------------------------------------------------------------------------
extern "C" void kernel_launch(void* const* d_in, const int* in_sizes, int n_in,
                              void* d_out, int out_size, void* d_ws, size_t ws_size,
                              hipStream_t stream)
{
    const void* x        = d_in[0];
    const void* pm       = d_in[1];
    const void* mem_keys = d_in[2];

    char* wsb = (char*)d_ws;
    bf16*  comb  = (bf16*)(wsb + 0x0);         // combined
    bf16*  qhB   = (bf16*)(wsb + 0x820000);    // attn q (B,H,S,HD)
    bf16*  khB   = (bf16*)(wsb + 0xC30000);    // attn k (B,H,S,HD)
    bf16*  vT    = (bf16*)(wsb + 0x1040000);   // vT (B,D,S) -> later: tmp (N_,512)
    bf16*  Lg    = (bf16*)(wsb + 0x1450000);   // logits bf16 (N_,2048) 17MB
    bf16*  W1    = (bf16*)(wsb + 0x2490000);   // probs: w_write | w_read 17MB
    bf16*  W1T   = (bf16*)(wsb + 0x34D0000);   // w_write^T (B,M,S) 8.5MB
    bf16*  aobf  = (bf16*)(wsb + 0x34D0000);   // alias: ao after W1T dead
    bf16*  vhT   = (bf16*)(wsb + 0x3CF0000);   // (B,H,HD,S) 4.26MB
    bf16*  Pst   = (bf16*)(wsb + 0x4100000);   // split-K partials (10, 2^19) 10MB
    bf16*  stT   = (bf16*)(wsb + 0x4B00000);   // state^T (B,D,M) 2MB
    bf16*  BigB  = (bf16*)(wsb + 0x4D00000);   // [Wv^T | G_k | G_q] (2560,512)
    bf16*  WT    = (bf16*)(wsb + 0x4F80000);   // 7 slots: Wk,Wq plain; 5 transposed
    bf16*  mkbf  = (bf16*)(wsb + 0x5300000);   // mem_keys bf16 (M,D) 1MB
    int*   flags = (int*)(wsb + 0x5400000);
    float* csAll = (float*)(wsb + 0x5410000);  // colsums: [0,1536) qkv; [1536,2048) out
    float* stats = (float*)(wsb + 0x5420000);  // LN stats: [2][N_][2] f32
    bf16*  tmp   = vT;                          // alias: vT dead after state GEMM

    Ptr8 p8;
    p8.p[0] = d_in[3]; p8.p[1] = d_in[4]; p8.p[2] = d_in[5]; p8.p[3] = d_in[6];
    p8.p[4] = d_in[7]; p8.p[5] = d_in[8]; p8.p[6] = d_in[9]; p8.p[7] = d_in[14];
    prep_kernel<<<10890, 256, 0, stream>>>(x, pm, mem_keys, p8, comb, mkbf, WT, BigB,
                                           flags, csAll, stats);
    #define WTp(i) (WT + (long)(i) * 262144)

    // G = mem_keys @ {mem_Wk, mem_Wq}^T -> BigB rows 512..2559
    gemm64<1,64,2,0,0><<<dim3(8, 16, 2), 256, 0, stream>>>(
        mkbf, WT, BigB + 262144, nullptr, nullptr, flags, nullptr, nullptr,
        M_, 512, 512, 512, 512, 0, 262144L, 524288L, 1);

    // MEGA (128x128): comb @ BigB^T (N=2560): cols<512 -> vT (transposed); rest -> Lg
    gemm128_mega<<<dim3(20, 33), 256, 0, stream>>>(
        comb, BigB, Lg, vT, N_, 512, 512, 512);

    softmax_rows_kernel<<<dim3(N_ / 4, 2), 256, 0, stream>>>(Lg, W1);
    transpose_b_kernel<<<dim3(16, 33, 2), 256, 0, stream>>>(W1, W1T, S_, M_);

    // state^T[b] = vT[b] @ W1T[b]^T  (512 x 1024, K=2080), split-K=5
    gemm64<1,128,1,0,0><<<dim3(8, 8, 10), 256, 0, stream>>>(
        vT, W1T, Pst, nullptr, nullptr, flags, nullptr, nullptr,
        512, S_, S_, S_, 1024, (long)D_ * S_, (long)M_ * S_, (long)D_ * M_, 5);
    reduce_state_kernel<<<512, 256, 0, stream>>>(Pst, stT);

    // mem_out[b] = w_read[b] @ stT[b]^T -> tmp bf16 + LN1 row stats (stats[0])
    gemm64<1,64,2,1,0><<<dim3(8, 33, 2), 256, 0, stream>>>(
        W1 + (long)N_ * M_, stT, tmp, nullptr, nullptr, flags, stats, nullptr,
        S_, M_, M_, M_, 512, (long)S_ * M_, (long)D_ * M_, (long)S_ * D_, 1);

    // attn projections on raw tmp with LN1 fixup: q->qhB, k->khB, v->vhT
    gemm64<7,128,2,0,1><<<dim3(12, 65, 1), 256, 0, stream>>>(
        tmp, WTp(2), qhB, khB, vhT, flags, stats, csAll,
        N_, 512, 512, 512, 0, 0, 0, 0, 1);

    flash_attn_kernel<<<dim3(33, H_, B_), 256, 0, stream>>>(qhB, khB, vhT, aobf);

    // ao @ Wo^T -> tmp bf16 + LN2 row stats (stats[1])
    gemm64<1,128,2,1,0><<<dim3(4, 65, 1), 256, 0, stream>>>(
        aobf, WTp(5), tmp, nullptr, nullptr, flags, stats + 2 * N_, nullptr,
        N_, 512, 512, 512, 512, 0, 0, 0, 1);

    // out = LN2-fixup(tmp @ outW^T) -> d_out (runtime dtype)
    gemm64<2,128,2,0,1><<<dim3(4, 65, 1), 256, 0, stream>>>(
        tmp, WTp(6), d_out, nullptr, nullptr, flags, stats + 2 * N_, csAll + 1536,
        N_, 512, 512, 512, 512, 0, 0, 0, 1);
}

// Round 3
// 253.206 us; speedup vs baseline: 1.5006x; 1.5006x over previous
//
#include <hip/hip_runtime.h>
#include <hip/hip_bf16.h>

#define B_ 2
#define L_ 2048
#define D_ 512
#define P_ 32
#define M_ 1024
#define H_ 8
#define HD_ 64
#define WIN_ 256
#define S_ (P_ + L_)        // 2080
#define N_ (B_ * S_)        // 4160

typedef __hip_bfloat16 bf16;
typedef __attribute__((ext_vector_type(8))) short short8;
typedef __attribute__((ext_vector_type(4))) float f32x4;

__device__ __forceinline__ int imin(int a, int b) { return a < b ? a : b; }
__device__ __forceinline__ int imax(int a, int b) { return a > b ? a : b; }

__device__ __forceinline__ float ld_in(const void* p, long i, int f32) {
    return f32 ? ((const float*)p)[i]
               : __bfloat162float(((const bf16*)p)[i]);
}

__device__ __forceinline__ short bfbits(float f) {
    bf16 h = __float2bfloat16(f);
    short s;
    __builtin_memcpy(&s, &h, 2);
    return s;
}

__device__ __forceinline__ float b2f(short s) {
    unsigned int u = ((unsigned int)(unsigned short)s) << 16;
    float f;
    __builtin_memcpy(&f, &u, 4);
    return f;
}

// async global->LDS 16B (m97).  LDS dst wave-uniform base; HW adds lane*16.
__device__ __forceinline__ void gload_lds16(const void* g, void* l) {
    __builtin_amdgcn_global_load_lds(
        (const __attribute__((address_space(1))) unsigned int*)g,
        (__attribute__((address_space(3))) unsigned int*)l, 16, 0, 0);
}

#define F_OW  10   // runtime out-dtype flag (published by prep)

// Free per-wave dtype detect (proven r13): ballot over 128 sampled u16s.
__device__ __forceinline__ int wave_detect(const void* p, int tid) {
    const unsigned short* u = (const unsigned short*)p;
    const int lane = tid & 63;
    unsigned short v0 = u[lane * 2], v1 = u[lane * 2 + 1];
    int hit = ((((v0 >> 7) & 0xFF) >= 0xC0) || (((v1 >> 7) & 0xFF) >= 0xC0)) ? 1 : 0;
    unsigned long long b = __ballot(hit);
    return (__popcll(b) >= 2) ? 1 : 0;
}

// ---------------------------------------------------------------------------
// Fused prep (ballot dtype detect): [0,8320) build_combined ;
// [8320,10368) convert mem_keys ; [10368,10880) weights -> bf16 ;
// [10880,10882) zero LN row-stat buffers (re-zeroed every launch).
// NOTE: NO strided column-sum blocks here (r2 lesson: 8 tail blocks of
// serialized strided loads = 130us latency tail).  Colsums are computed
// for free inside the FIX GEMMs from their own B fragments.
// ---------------------------------------------------------------------------
struct Ptr8 { const void* p[8]; };

__global__ __launch_bounds__(256) void prep_kernel(
    const void* __restrict__ x, const void* __restrict__ pm,
    const void* __restrict__ mk, Ptr8 wptrs,
    bf16* __restrict__ comb, bf16* __restrict__ mkbf, bf16* __restrict__ WT,
    bf16* __restrict__ BigB, int* __restrict__ flags, float* __restrict__ st)
{
    __shared__ short T[64][65];
    const int blk = blockIdx.x;
    const int tid = threadIdx.x;
    if (blk < 8320) {
        int i = blk * 256 + tid;
        int d = i & (D_ - 1);
        int r = i >> 9;
        int s = r % S_;
        int b = r / S_;
        const void* src = (s < P_) ? pm : x;
        const int f = wave_detect(src, tid);
        float v;
        if (s < P_) v = ld_in(pm, (long)s * D_ + d, f);
        else        v = ld_in(x, ((long)(b * L_ + (s - P_))) * D_ + d, f);
        comb[i] = __float2bfloat16(v);
        return;
    }
    if (blk < 10368) {
        const int f = wave_detect(mk, tid);
        int i = (blk - 8320) * 256 + tid;
        mkbf[i] = __float2bfloat16(ld_in(mk, i, f));
        return;
    }
    if (blk >= 10880) {
        // zero both stat blocks: 2 * N_ * 2 floats = 16640
        const int t3 = (blk - 10880) * 256 + tid;
        for (int i = t3; i < 2 * N_ * 2; i += 512) st[i] = 0.f;
        return;
    }
    const int t = blk - 10368;
    const int widx = t >> 6;
    const int rem = t & 63;
    const int r0 = (rem >> 3) * 64, c0 = (rem & 7) * 64;
    const void* in = wptrs.p[widx];
    const int flag = wave_detect(in, tid);
    if (widx == 7 && rem == 0 && tid == 0) flags[F_OW] = flag;
    short* o;
    if (widx == 0)      o = (short*)WT;
    else if (widx == 2) o = (short*)(WT + 262144);
    else if (widx == 1) o = (short*)BigB;
    else                o = (short*)(WT + (long)(widx - 1) * 262144);
    if (widx == 0 || widx == 2) {
        #pragma unroll
        for (int i = 0; i < 2; ++i) {
            int ch = tid + i * 256;
            int r = ch >> 3, c8 = (ch & 7) * 8;
            long base = (long)(r0 + r) * 512 + c0 + c8;
            short8 v;
            if (flag) {
                const float4 f0 = *reinterpret_cast<const float4*>((const float*)in + base);
                const float4 f1 = *reinterpret_cast<const float4*>((const float*)in + base + 4);
                v[0]=bfbits(f0.x); v[1]=bfbits(f0.y); v[2]=bfbits(f0.z); v[3]=bfbits(f0.w);
                v[4]=bfbits(f1.x); v[5]=bfbits(f1.y); v[6]=bfbits(f1.z); v[7]=bfbits(f1.w);
            } else {
                v = *reinterpret_cast<const short8*>((const short*)in + base);
            }
            *reinterpret_cast<short8*>(o + base) = v;
        }
        return;
    }
    #pragma unroll
    for (int i = 0; i < 2; ++i) {
        int ch = tid + i * 256;
        int r = ch >> 3, c8 = (ch & 7) * 8;
        long base = (long)(r0 + r) * 512 + c0 + c8;
        if (flag) {
            const float4 f0 = *reinterpret_cast<const float4*>((const float*)in + base);
            const float4 f1 = *reinterpret_cast<const float4*>((const float*)in + base + 4);
            T[r][c8+0]=bfbits(f0.x); T[r][c8+1]=bfbits(f0.y); T[r][c8+2]=bfbits(f0.z); T[r][c8+3]=bfbits(f0.w);
            T[r][c8+4]=bfbits(f1.x); T[r][c8+5]=bfbits(f1.y); T[r][c8+6]=bfbits(f1.z); T[r][c8+7]=bfbits(f1.w);
        } else {
            const short8 v = *reinterpret_cast<const short8*>((const short*)in + base);
            #pragma unroll
            for (int k = 0; k < 8; ++k) T[r][c8+k] = v[k];
        }
    }
    __syncthreads();
    #pragma unroll
    for (int i = 0; i < 2; ++i) {
        int ch = tid + i * 256;
        int n = ch >> 3, c8 = (ch & 7) * 8;
        #pragma unroll
        for (int k = 0; k < 8; ++k)
            o[(long)(c0 + n) * 512 + r0 + c8 + k] = T[c8 + k][n];
    }
}

// ---------------------------------------------------------------------------
// Batched bf16 transpose: in (z, R, C) -> out (z, C, R).  (only W1 -> W1T now)
// ---------------------------------------------------------------------------
__global__ __launch_bounds__(256) void transpose_b_kernel(
    const bf16* __restrict__ in_, bf16* __restrict__ out_, int R, int C)
{
    const short* in = (const short*)(in_ + (long)blockIdx.z * R * C);
    short* out = (short*)(out_ + (long)blockIdx.z * C * R);
    __shared__ short T[64][65];
    const int r0 = blockIdx.y * 64, c0 = blockIdx.x * 64;
    const int tid = threadIdx.x;
    #pragma unroll
    for (int i = 0; i < 2; ++i) {
        int ch = tid + i * 256;
        int r = ch >> 3, c8 = (ch & 7) * 8;
        int row = imin(r0 + r, R - 1);
        const short8 v = *reinterpret_cast<const short8*>(in + (long)row * C + c0 + c8);
        #pragma unroll
        for (int k = 0; k < 8; ++k) T[r][c8+k] = v[k];
    }
    __syncthreads();
    #pragma unroll
    for (int i = 0; i < 2; ++i) {
        int ch = tid + i * 256;
        int n = ch >> 3, c8 = (ch & 7) * 8;
        #pragma unroll
        for (int k = 0; k < 8; ++k) {
            int col = r0 + c8 + k;
            if (col < R) out[(long)(c0 + n) * R + col] = T[c8 + k][n];
        }
    }
}

// ---------------------------------------------------------------------------
// 64-row MFMA GEMM, UN k-subtiles per barrier pair (proven r7-r13).
// CMODE: 1 bf16 z-strided   2 runtime dtype (flags[F_OW]) (N_,512)
//        7 attn: grp0/1 (q,k) -> (B,H,S,HD) row-major; grp2 (v) -> C2 as
//        (B,H,HD,S) via in-LDS transpose.
// STAT=1: accumulate LN row stats (sum, sumsq of bf16-rounded C) into st.
// FIX=1: apply LN-algebraic fixup: val = inv_r * (val - mu_r * colsum[col]);
//        colsum computed IN-LOOP from this block's own B fragments (B rows
//        are W columns; full K passes through LDS -> free exact colsum).
// ---------------------------------------------------------------------------
template<int CMODE, int BN, int UN, int STAT, int FIX>
__global__ __launch_bounds__(256, 4) void gemm64(
    const bf16* __restrict__ A, const bf16* __restrict__ Bb,
    void* __restrict__ C0, void* __restrict__ C1, void* __restrict__ C2,
    const int* __restrict__ flags, float* __restrict__ st,
    int Mdim, int Kdim, int lda, int ldb, int ldc,
    long sA, long sB, long sC, int SK)
{
    constexpr int NH = BN / 64;
    __shared__ __align__(16) bf16 SM[UN * 2048 + UN * BN * 32];
    bf16* const As = SM;
    bf16* const Bs = SM + UN * 2048;
    const int tid = threadIdx.x, lane = tid & 63, wid = tid >> 6;
    constexpr int WNc = BN / 4;
    constexpr int NJ = WNc / 16;
    const int m0 = blockIdx.y * 64, n0 = blockIdx.x * BN;
    const int z = blockIdx.z;
    const int bz = z / SK, kc = z - bz * SK;
    const int kLen = Kdim / SK;
    const int kBeg = kc * kLen;
    const bf16* Ab = A + (long)bz * sA;
    const bf16* Bp = Bb + (long)bz * sB;

    const int sRow = tid >> 2, c8 = (tid & 3) * 8;
    int aRow = m0 + sRow;
    if (aRow >= Mdim) aRow = Mdim - 1;
    const bf16* aS = Ab + (long)aRow * lda + c8 + kBeg;
    const bf16* bS[NH];
    #pragma unroll
    for (int h = 0; h < NH; ++h)
        bS[h] = Bp + (long)(n0 + sRow + h * 64) * ldb + c8 + kBeg;

    const int g8 = (lane >> 4) * 8, l15 = lane & 15;
    f32x4 acc[4][NJ] = {};
    float csv[NJ] = {};

    for (int k0 = 0; k0 < kLen; k0 += UN * 32) {
        #pragma unroll
        for (int t = 0; t < UN; ++t) {
            gload_lds16(aS + k0 + t * 32, As + t * 2048 + wid * 512);
            #pragma unroll
            for (int h = 0; h < NH; ++h)
                gload_lds16(bS[h] + k0 + t * 32, Bs + t * BN * 32 + h * 2048 + wid * 512);
        }
        __syncthreads();
        #pragma unroll
        for (int t = 0; t < UN; ++t) {
            short8 af[4], bfr[NJ];
            #pragma unroll
            for (int mi = 0; mi < 4; ++mi)
                af[mi] = *reinterpret_cast<const short8*>(
                    &As[t * 2048 + (mi * 16 + l15) * 32 + g8]);
            #pragma unroll
            for (int nj = 0; nj < NJ; ++nj)
                bfr[nj] = *reinterpret_cast<const short8*>(
                    &Bs[t * BN * 32 + (wid * WNc + nj * 16 + l15) * 32 + g8]);
            if constexpr (FIX) {
                #pragma unroll
                for (int nj = 0; nj < NJ; ++nj)
                    #pragma unroll
                    for (int e = 0; e < 8; ++e)
                        csv[nj] += b2f(bfr[nj][e]);
            }
            #pragma unroll
            for (int mi = 0; mi < 4; ++mi)
                #pragma unroll
                for (int nj = 0; nj < NJ; ++nj)
                    acc[mi][nj] = __builtin_amdgcn_mfma_f32_16x16x32_bf16(
                        af[mi], bfr[nj], acc[mi][nj], 0, 0, 0);
        }
        __syncthreads();
    }

    const int g4 = (lane >> 4) * 4;

    // LN-algebraic fixup (consumer side): val = inv_r*(val - mu_r*colsum[col])
    if constexpr (FIX) {
        #pragma unroll
        for (int nj = 0; nj < NJ; ++nj) {
            csv[nj] += __shfl_xor(csv[nj], 16, 64);   // combine 4 k-offset
            csv[nj] += __shfl_xor(csv[nj], 32, 64);   // groups (g = lane>>4)
        }
        #pragma unroll
        for (int mi = 0; mi < 4; ++mi) {
            #pragma unroll
            for (int r = 0; r < 4; ++r) {
                int row = m0 + mi * 16 + g4 + r;
                float sv = st[(long)row * 2], qv = st[(long)row * 2 + 1];
                float mu = sv * (1.f / 512.f);
                float iv = rsqrtf(qv * (1.f / 512.f) - mu * mu + 1e-5f);
                #pragma unroll
                for (int nj = 0; nj < NJ; ++nj)
                    acc[mi][nj][r] = iv * (acc[mi][nj][r] - mu * csv[nj]);
            }
        }
    }

    // LN row-stat accumulation (producer side), on bf16-rounded values.
    if constexpr (STAT) {
        #pragma unroll
        for (int mi = 0; mi < 4; ++mi)
            #pragma unroll
            for (int nj = 0; nj < NJ; ++nj)
                #pragma unroll
                for (int r = 0; r < 4; ++r)
                    acc[mi][nj][r] = b2f(bfbits(acc[mi][nj][r]));
        float* red = (float*)SM;
        #pragma unroll
        for (int mi = 0; mi < 4; ++mi) {
            #pragma unroll
            for (int r = 0; r < 4; ++r) {
                float sv = 0.f, qv = 0.f;
                #pragma unroll
                for (int nj = 0; nj < NJ; ++nj) {
                    float v = acc[mi][nj][r];
                    sv += v; qv += v * v;
                }
                #pragma unroll
                for (int off = 1; off < 16; off <<= 1) {
                    sv += __shfl_xor(sv, off, 64);
                    qv += __shfl_xor(qv, off, 64);
                }
                if (l15 == 0) {
                    int rr = mi * 16 + g4 + r;
                    red[(wid * 64 + rr) * 2]     = sv;
                    red[(wid * 64 + rr) * 2 + 1] = qv;
                }
            }
        }
        __syncthreads();
        if (tid < 128) {
            int rr = tid & 63, which = tid >> 6;
            if (m0 + rr < Mdim) {
                const int zrow = (int)(sC / (long)ldc) * z;
                float a = red[rr * 2 + which] + red[(64 + rr) * 2 + which]
                        + red[(128 + rr) * 2 + which] + red[(192 + rr) * 2 + which];
                atomicAdd(&st[((long)(zrow + m0 + rr)) * 2 + which], a);
            }
        }
    }

    const int oflag = (CMODE == 2) ? flags[F_OW] : 0;
    const int grp = n0 >> 9;

    if (CMODE == 7 && grp == 2) {
        // v projection -> vhT (B,H,HD,S) via in-LDS transpose.
        bf16* T = SM;
        if constexpr (STAT) __syncthreads();
        #pragma unroll
        for (int mi = 0; mi < 4; ++mi)
            #pragma unroll
            for (int nj = 0; nj < NJ; ++nj)
                #pragma unroll
                for (int r = 0; r < 4; ++r)
                    T[(wid * WNc + nj * 16 + l15) * 72 + mi * 16 + g4 + r] =
                        __float2bfloat16(acc[mi][nj][r]);
        __syncthreads();
        #pragma unroll
        for (int it = 0; it < 2; ++it) {
            int idx = tid + it * 256;
            int d = idx >> 2;            // 0..127
            int sc = (idx & 3) * 16;     // 0..48; 16-chunks never cross s=2080
            int grow = m0 + sc;
            int b = grow / S_;
            int s = grow - b * S_;
            int dg = (n0 - 1024) + d;
            int h = dg >> 6, dd = dg & 63;
            bf16* dst = (bf16*)C2 + ((long)((b * H_ + h) * HD_ + dd)) * S_ + s;
            *reinterpret_cast<short8*>(dst) =
                *reinterpret_cast<const short8*>(&T[d * 72 + sc]);
            *reinterpret_cast<short8*>(dst + 8) =
                *reinterpret_cast<const short8*>(&T[d * 72 + sc + 8]);
        }
        return;
    }

    #pragma unroll
    for (int mi = 0; mi < 4; ++mi) {
        #pragma unroll
        for (int nj = 0; nj < NJ; ++nj) {
            #pragma unroll
            for (int r = 0; r < 4; ++r) {
                int row = m0 + mi * 16 + g4 + r;
                int col = n0 + wid * WNc + nj * 16 + l15;
                if (row >= Mdim) continue;
                float val = acc[mi][nj][r];
                if (CMODE == 1) {
                    ((bf16*)C0)[(long)z * sC + (long)row * ldc + col] = __float2bfloat16(val);
                } else if (CMODE == 2) {
                    long idx = (long)row * 512 + col;
                    if (oflag) ((float*)C0)[idx] = val;
                    else       ((bf16*)C0)[idx] = __float2bfloat16(val);
                } else {            // CMODE 7, grp 0/1
                    int b = row / S_, s = row - b * S_;
                    int c = col - (grp << 9);
                    int h = c >> 6, d = c & 63;
                    long idx = ((long)(b * H_ + h) * S_ + s) * HD_ + d;
                    if (grp == 0)      ((bf16*)C0)[idx] = __float2bfloat16(val);
                    else               ((bf16*)C1)[idx] = __float2bfloat16(val);
                }
            }
        }
    }
}

// ---------------------------------------------------------------------------
// 128x128 MFMA GEMM (m97 shape; r5-proven structure), UN=2 subtiles.
// Mega GEMM only: grid (20, 33).  A (M,K) lda; B (N,K) ldb.
// Epilogue: n0<512 -> vT (B,D,S) via in-LDS transpose; n0>=512 -> Lg.
// ---------------------------------------------------------------------------
__global__ __launch_bounds__(256) void gemm128_mega(
    const bf16* __restrict__ A, const bf16* __restrict__ Bb,
    void* __restrict__ C0, void* __restrict__ C1,
    int Mdim, int Kdim, int lda, int ldb)
{
    __shared__ __align__(16) bf16 SM[4 * 4096];
    bf16* const As = SM;
    bf16* const Bs = SM + 2 * 4096;
    const int tid = threadIdx.x, lane = tid & 63, wid = tid >> 6;
    const int wr = wid >> 1, wc = wid & 1;
    const int m0 = blockIdx.y * 128, n0 = blockIdx.x * 128;

    int aRow0 = m0 + (tid >> 2);
    int aRow1 = aRow0 + 64;
    if (aRow0 >= Mdim) aRow0 = Mdim - 1;
    if (aRow1 >= Mdim) aRow1 = Mdim - 1;
    const int c8 = (tid & 3) * 8;
    const bf16* aSrc0 = A + (long)aRow0 * lda + c8;
    const bf16* aSrc1 = A + (long)aRow1 * lda + c8;
    const bf16* bSrc0 = Bb + (long)(n0 + (tid >> 2)) * ldb + c8;
    const bf16* bSrc1 = bSrc0 + 64 * (long)ldb;

    const int g8 = (lane >> 4) * 8, l15 = lane & 15;
    f32x4 acc[4][4] = {};

    for (int k0 = 0; k0 < Kdim; k0 += 64) {
        #pragma unroll
        for (int t = 0; t < 2; ++t) {
            gload_lds16(aSrc0 + k0 + t * 32, As + t * 4096 + wid * 512);
            gload_lds16(aSrc1 + k0 + t * 32, As + t * 4096 + 2048 + wid * 512);
            gload_lds16(bSrc0 + k0 + t * 32, Bs + t * 4096 + wid * 512);
            gload_lds16(bSrc1 + k0 + t * 32, Bs + t * 4096 + 2048 + wid * 512);
        }
        __syncthreads();
        #pragma unroll
        for (int t = 0; t < 2; ++t) {
            short8 af[4], bfr[4];
            #pragma unroll
            for (int mi = 0; mi < 4; ++mi)
                af[mi] = *reinterpret_cast<const short8*>(
                    &As[t * 4096 + (wr * 64 + mi * 16 + l15) * 32 + g8]);
            #pragma unroll
            for (int nj = 0; nj < 4; ++nj)
                bfr[nj] = *reinterpret_cast<const short8*>(
                    &Bs[t * 4096 + (wc * 64 + nj * 16 + l15) * 32 + g8]);
            #pragma unroll
            for (int mi = 0; mi < 4; ++mi)
                #pragma unroll
                for (int nj = 0; nj < 4; ++nj)
                    acc[mi][nj] = __builtin_amdgcn_mfma_f32_16x16x32_bf16(
                        af[mi], bfr[nj], acc[mi][nj], 0, 0, 0);
        }
        __syncthreads();
    }

    if (n0 >= 512) {
        #pragma unroll
        for (int mi = 0; mi < 4; ++mi) {
            #pragma unroll
            for (int nj = 0; nj < 4; ++nj) {
                #pragma unroll
                for (int r = 0; r < 4; ++r) {
                    int row = m0 + wr * 64 + mi * 16 + (lane >> 4) * 4 + r;
                    int col = n0 + wc * 64 + nj * 16 + l15;
                    if (row >= Mdim) continue;
                    ((bf16*)C0)[(long)row * 2048 + col - 512] =
                        __float2bfloat16(acc[mi][nj][r]);
                }
            }
        }
        return;
    }

    // v region -> vT (B, 512, S_) via in-LDS transpose, two 64-col passes.
    {
        bf16* T = SM;
        const int g4 = (lane >> 4) * 4;
        #pragma unroll
        for (int p = 0; p < 2; ++p) {
            __syncthreads();
            if (wc == p) {
                #pragma unroll
                for (int mi = 0; mi < 4; ++mi)
                    #pragma unroll
                    for (int nj = 0; nj < 4; ++nj)
                        #pragma unroll
                        for (int r = 0; r < 4; ++r)
                            T[(nj * 16 + l15) * 136 + wr * 64 + mi * 16 + g4 + r] =
                                __float2bfloat16(acc[mi][nj][r]);
            }
            __syncthreads();
            #pragma unroll
            for (int it = 0; it < 2; ++it) {
                int idx = tid + it * 256;
                int d = idx >> 3;            // 0..63
                int sc = (idx & 7) * 16;     // 0..112; 16-chunks never cross s=2080
                int grow = m0 + sc;
                if (grow >= Mdim) continue;
                int b = grow / S_;
                int s = grow - b * S_;
                bf16* dst = (bf16*)C1 + ((long)b * 512 + n0 + p * 64 + d) * S_ + s;
                *reinterpret_cast<short8*>(dst) =
                    *reinterpret_cast<const short8*>(&T[d * 136 + sc]);
                *reinterpret_cast<short8*>(dst + 8) =
                    *reinterpret_cast<const short8*>(&T[d * 136 + sc + 8]);
            }
        }
    }
}

// ---------------------------------------------------------------------------
// Reduce split-K state partials: Pst bf16 (B*5, 2^19) -> stT bf16 (B,D,M).
// ---------------------------------------------------------------------------
__global__ __launch_bounds__(256) void reduce_state_kernel(
    const bf16* __restrict__ P, bf16* __restrict__ stT)
{
    long g = ((long)blockIdx.x * 256 + threadIdx.x) * 8;
    int b = (int)(g >> 19);
    long dm = g & ((1L << 19) - 1);
    float s[8] = {};
    #pragma unroll
    for (int c = 0; c < 5; ++c) {
        const short8 v = *reinterpret_cast<const short8*>(
            (const short*)P + (((long)(b * 5 + c)) << 19) + dm);
        #pragma unroll
        for (int k = 0; k < 8; ++k) s[k] += b2f(v[k]);
    }
    short8 o;
    #pragma unroll
    for (int k = 0; k < 8; ++k) o[k] = bfbits(s[k]);
    *reinterpret_cast<short8*>((short*)stT + g) = o;
}

// ---------------------------------------------------------------------------
// Row softmax, one wave per row (no barriers).  Lg (N_, 2048) col-stacked
// [k|q]; grid (N_/4, 2).  Writes W1[hf*N_*M + row*M].
// ---------------------------------------------------------------------------
__global__ __launch_bounds__(256) void softmax_rows_kernel(
    const bf16* __restrict__ w, bf16* __restrict__ o)
{
    const int tid = threadIdx.x;
    const int lane = tid & 63;
    const int row = blockIdx.x * 4 + (tid >> 6);
    const int hf = blockIdx.y;
    const short* src = (const short*)w + (long)row * 2048 + hf * 1024 + lane * 16;
    const short8 v0 = *reinterpret_cast<const short8*>(src);
    const short8 v1 = *reinterpret_cast<const short8*>(src + 8);
    float f[16];
    #pragma unroll
    for (int k = 0; k < 8; ++k) { f[k] = b2f(v0[k]); f[8 + k] = b2f(v1[k]); }
    float mx = f[0];
    #pragma unroll
    for (int k = 1; k < 16; ++k) mx = fmaxf(mx, f[k]);
    #pragma unroll
    for (int off = 32; off > 0; off >>= 1) mx = fmaxf(mx, __shfl_xor(mx, off, 64));
    float s = 0.f;
    #pragma unroll
    for (int k = 0; k < 16; ++k) { f[k] = __expf(f[k] - mx); s += f[k]; }
    #pragma unroll
    for (int off = 32; off > 0; off >>= 1) s += __shfl_xor(s, off, 64);
    const float inv = 1.f / s;
    short8 o0, o1;
    #pragma unroll
    for (int k = 0; k < 8; ++k) { o0[k] = bfbits(f[k] * inv); o1[k] = bfbits(f[8 + k] * inv); }
    short* dst = (short*)o + (long)hf * N_ * M_ + (long)row * M_ + lane * 16;
    *reinterpret_cast<short8*>(dst) = o0;
    *reinterpret_cast<short8*>(dst + 8) = o1;
}

// ---------------------------------------------------------------------------
// MFMA flash banded attention, fixed-max softmax (proven r9).  grid (33,H,B).
// ---------------------------------------------------------------------------
#define SC2_ 0.18033688f     // 0.125 * log2(e)
#define MF2_ 11.5415603f     // 8 * log2(e)

#define PRELOAD(JT) do {                                                     \
    _Pragma("unroll")                                                        \
    for (int i = 0; i < 2; ++i) {                                            \
        int ch = tid + i * 256;                                              \
        int r = ch >> 3, cc8 = (ch & 7) * 8;                                 \
        int j = imin((JT) * 64 + r, S_ - 1);                                 \
        kreg[i] = *reinterpret_cast<const short8*>(kb + (long)j * HD_ + cc8);\
        int jc = (JT) * 64 + cc8;                                            \
        if (jc + 8 <= S_) {                                                  \
            vreg[i] = *reinterpret_cast<const short8*>(vb + (long)r * S_ + jc); \
        } else {                                                             \
            short8 v;                                                        \
            _Pragma("unroll")                                                \
            for (int k = 0; k < 8; ++k)                                      \
                v[k] = ((const short*)vb)[(long)r * S_ + imin(jc + k, S_ - 1)]; \
            vreg[i] = v;                                                     \
        }                                                                    \
    }                                                                        \
} while (0)

__global__ __launch_bounds__(256) void flash_attn_kernel(
    const bf16* __restrict__ qh, const bf16* __restrict__ kh,
    const bf16* __restrict__ vhT, bf16* __restrict__ ao)
{
    const int qt = blockIdx.x, h = blockIdx.y, b = blockIdx.z;
    const int tid = threadIdx.x, w = tid >> 6, lane = tid & 63;
    const int g = lane >> 4, l15 = lane & 15, g8 = g * 8;
    const int q0 = qt * 64;
    __shared__ __align__(16) bf16 Qs[64 * 72];
    __shared__ __align__(16) bf16 Ks[64 * 72];
    __shared__ __align__(16) bf16 Vs[64 * 72];
    __shared__ __align__(16) bf16 Ps[4 * 16 * 88];
    const long bh = (long)(b * H_ + h);
    const bf16* qb = qh + bh * S_ * HD_;
    const bf16* kb = kh + bh * S_ * HD_;
    const bf16* vb = vhT + bh * HD_ * S_;

    #pragma unroll
    for (int i = 0; i < 2; ++i) {
        int ch = tid + i * 256;
        int r = ch >> 3, c8 = (ch & 7) * 8;
        int q = imin(q0 + r, S_ - 1);
        *reinterpret_cast<short8*>(&Qs[r * 72 + c8]) =
            *reinterpret_cast<const short8*>(qb + (long)q * HD_ + c8);
    }
    float lrow[4] = {};
    f32x4 O[4] = {};
    const int tstart = imax(0, q0 - (WIN_ - 1)) >> 6;
    const int tend = imin(S_ - 1, q0 + 63 + (WIN_ - 1)) >> 6;

    short8 kreg[2], vreg[2];
    PRELOAD(tstart);
    __syncthreads();
    const short8 aq0 = *reinterpret_cast<const short8*>(&Qs[(w * 16 + l15) * 72 + g8]);
    const short8 aq1 = *reinterpret_cast<const short8*>(&Qs[(w * 16 + l15) * 72 + 32 + g8]);

    for (int jt = tstart; jt <= tend; ++jt) {
        if (jt > tstart) __syncthreads();
        #pragma unroll
        for (int i = 0; i < 2; ++i) {
            int ch = tid + i * 256;
            int r = ch >> 3, c8 = (ch & 7) * 8;
            *reinterpret_cast<short8*>(&Ks[r * 72 + c8]) = kreg[i];
            *reinterpret_cast<short8*>(&Vs[r * 72 + c8]) = vreg[i];
        }
        __syncthreads();
        if (jt < tend) PRELOAD(jt + 1);

        f32x4 s[4] = {};
        __builtin_amdgcn_s_setprio(1);
        #pragma unroll
        for (int nj = 0; nj < 4; ++nj) {
            const short8 b0 = *reinterpret_cast<const short8*>(&Ks[(nj * 16 + l15) * 72 + g8]);
            const short8 b1 = *reinterpret_cast<const short8*>(&Ks[(nj * 16 + l15) * 72 + 32 + g8]);
            s[nj] = __builtin_amdgcn_mfma_f32_16x16x32_bf16(aq0, b0, s[nj], 0, 0, 0);
            s[nj] = __builtin_amdgcn_mfma_f32_16x16x32_bf16(aq1, b1, s[nj], 0, 0, 0);
        }
        __builtin_amdgcn_s_setprio(0);
        #pragma unroll
        for (int nj = 0; nj < 4; ++nj) {
            int j = jt * 64 + nj * 16 + l15;
            #pragma unroll
            for (int r = 0; r < 4; ++r) {
                int q = q0 + w * 16 + g * 4 + r;
                int dd = q - j;
                bool ok = (dd > -WIN_) && (dd < WIN_) && (q < S_) && (j < S_);
                s[nj][r] = ok ? fmaf(s[nj][r], SC2_, -MF2_) : -1e30f;
            }
        }
        #pragma unroll
        for (int r = 0; r < 4; ++r) {
            float ps = 0.f;
            #pragma unroll
            for (int nj = 0; nj < 4; ++nj) {
                float pv = exp2f(s[nj][r]);
                s[nj][r] = pv;
                ps += pv;
            }
            #pragma unroll
            for (int off = 8; off; off >>= 1) ps += __shfl_xor(ps, off, 64);
            lrow[r] += ps;
        }
        #pragma unroll
        for (int nj = 0; nj < 4; ++nj)
            #pragma unroll
            for (int r = 0; r < 4; ++r)
                Ps[w * 1408 + (g * 4 + r) * 88 + nj * 16 + l15] = __float2bfloat16(s[nj][r]);
        const short8 ap0 = *reinterpret_cast<const short8*>(&Ps[w * 1408 + l15 * 88 + g8]);
        const short8 ap1 = *reinterpret_cast<const short8*>(&Ps[w * 1408 + l15 * 88 + 32 + g8]);
        __builtin_amdgcn_s_setprio(1);
        #pragma unroll
        for (int nj = 0; nj < 4; ++nj) {
            const short8 b0 = *reinterpret_cast<const short8*>(&Vs[(nj * 16 + l15) * 72 + g8]);
            const short8 b1 = *reinterpret_cast<const short8*>(&Vs[(nj * 16 + l15) * 72 + 32 + g8]);
            O[nj] = __builtin_amdgcn_mfma_f32_16x16x32_bf16(ap0, b0, O[nj], 0, 0, 0);
            O[nj] = __builtin_amdgcn_mfma_f32_16x16x32_bf16(ap1, b1, O[nj], 0, 0, 0);
        }
        __builtin_amdgcn_s_setprio(0);
    }
    float inv[4];
    #pragma unroll
    for (int r = 0; r < 4; ++r) inv[r] = lrow[r] > 0.f ? 1.f / lrow[r] : 0.f;
    #pragma unroll
    for (int nj = 0; nj < 4; ++nj) {
        #pragma unroll
        for (int r = 0; r < 4; ++r) {
            int q = q0 + w * 16 + g * 4 + r;
            if (q < S_)
                ao[((long)b * S_ + q) * D_ + h * HD_ + nj * 16 + l15] =
                    __float2bfloat16(O[nj][r] * inv[r]);
        }
    }
}

// ---------------------------------------------------------------------------
// Launch (12 dispatches; LN fused into GEMM epilogues, colsum in-loop)
// ---------------------------------------------------------------------------
extern "C" void kernel_launch(void* const* d_in, const int* in_sizes, int n_in,
                              void* d_out, int out_size, void* d_ws, size_t ws_size,
                              hipStream_t stream)
{
    const void* x        = d_in[0];
    const void* pm       = d_in[1];
    const void* mem_keys = d_in[2];

    char* wsb = (char*)d_ws;
    bf16*  comb  = (bf16*)(wsb + 0x0);         // combined
    bf16*  qhB   = (bf16*)(wsb + 0x820000);    // attn q (B,H,S,HD)
    bf16*  khB   = (bf16*)(wsb + 0xC30000);    // attn k (B,H,S,HD)
    bf16*  vT    = (bf16*)(wsb + 0x1040000);   // vT (B,D,S) -> later: tmp (N_,512)
    bf16*  Lg    = (bf16*)(wsb + 0x1450000);   // logits bf16 (N_,2048) 17MB
    bf16*  W1    = (bf16*)(wsb + 0x2490000);   // probs: w_write | w_read 17MB
    bf16*  W1T   = (bf16*)(wsb + 0x34D0000);   // w_write^T (B,M,S) 8.5MB
    bf16*  aobf  = (bf16*)(wsb + 0x34D0000);   // alias: ao after W1T dead
    bf16*  vhT   = (bf16*)(wsb + 0x3CF0000);   // (B,H,HD,S) 4.26MB
    bf16*  Pst   = (bf16*)(wsb + 0x4100000);   // split-K partials (10, 2^19) 10MB
    bf16*  stT   = (bf16*)(wsb + 0x4B00000);   // state^T (B,D,M) 2MB
    bf16*  BigB  = (bf16*)(wsb + 0x4D00000);   // [Wv^T | G_k | G_q] (2560,512)
    bf16*  WT    = (bf16*)(wsb + 0x4F80000);   // 7 slots: Wk,Wq plain; 5 transposed
    bf16*  mkbf  = (bf16*)(wsb + 0x5300000);   // mem_keys bf16 (M,D) 1MB
    int*   flags = (int*)(wsb + 0x5400000);
    float* stats = (float*)(wsb + 0x5420000);  // LN stats: [2][N_][2] f32
    bf16*  tmp   = vT;                          // alias: vT dead after state GEMM

    Ptr8 p8;
    p8.p[0] = d_in[3]; p8.p[1] = d_in[4]; p8.p[2] = d_in[5]; p8.p[3] = d_in[6];
    p8.p[4] = d_in[7]; p8.p[5] = d_in[8]; p8.p[6] = d_in[9]; p8.p[7] = d_in[14];
    prep_kernel<<<10882, 256, 0, stream>>>(x, pm, mem_keys, p8, comb, mkbf, WT, BigB,
                                           flags, stats);
    #define WTp(i) (WT + (long)(i) * 262144)

    // G = mem_keys @ {mem_Wk, mem_Wq}^T -> BigB rows 512..2559
    gemm64<1,64,2,0,0><<<dim3(8, 16, 2), 256, 0, stream>>>(
        mkbf, WT, BigB + 262144, nullptr, nullptr, flags, nullptr,
        M_, 512, 512, 512, 512, 0, 262144L, 524288L, 1);

    // MEGA (128x128): comb @ BigB^T (N=2560): cols<512 -> vT (transposed); rest -> Lg
    gemm128_mega<<<dim3(20, 33), 256, 0, stream>>>(
        comb, BigB, Lg, vT, N_, 512, 512, 512);

    softmax_rows_kernel<<<dim3(N_ / 4, 2), 256, 0, stream>>>(Lg, W1);
    transpose_b_kernel<<<dim3(16, 33, 2), 256, 0, stream>>>(W1, W1T, S_, M_);

    // state^T[b] = vT[b] @ W1T[b]^T  (512 x 1024, K=2080), split-K=5
    gemm64<1,128,1,0,0><<<dim3(8, 8, 10), 256, 0, stream>>>(
        vT, W1T, Pst, nullptr, nullptr, flags, nullptr,
        512, S_, S_, S_, 1024, (long)D_ * S_, (long)M_ * S_, (long)D_ * M_, 5);
    reduce_state_kernel<<<512, 256, 0, stream>>>(Pst, stT);

    // mem_out[b] = w_read[b] @ stT[b]^T -> tmp bf16 + LN1 row stats (stats[0])
    gemm64<1,64,2,1,0><<<dim3(8, 33, 2), 256, 0, stream>>>(
        W1 + (long)N_ * M_, stT, tmp, nullptr, nullptr, flags, stats,
        S_, M_, M_, M_, 512, (long)S_ * M_, (long)D_ * M_, (long)S_ * D_, 1);

    // attn projections on raw tmp with LN1 fixup: q->qhB, k->khB, v->vhT
    gemm64<7,128,2,0,1><<<dim3(12, 65, 1), 256, 0, stream>>>(
        tmp, WTp(2), qhB, khB, vhT, flags, stats,
        N_, 512, 512, 512, 0, 0, 0, 0, 1);

    flash_attn_kernel<<<dim3(33, H_, B_), 256, 0, stream>>>(qhB, khB, vhT, aobf);

    // ao @ Wo^T -> tmp bf16 + LN2 row stats (stats[1])
    gemm64<1,128,2,1,0><<<dim3(4, 65, 1), 256, 0, stream>>>(
        aobf, WTp(5), tmp, nullptr, nullptr, flags, stats + 2 * N_,
        N_, 512, 512, 512, 512, 0, 0, 0, 1);

    // out = LN2-fixup(tmp @ outW^T) -> d_out (runtime dtype)
    gemm64<2,128,2,0,1><<<dim3(4, 65, 1), 256, 0, stream>>>(
        tmp, WTp(6), d_out, nullptr, nullptr, flags, stats + 2 * N_,
        N_, 512, 512, 512, 512, 0, 0, 0, 1);
}

// Round 6
// 247.484 us; speedup vs baseline: 1.5353x; 1.0231x over previous
//
#include <hip/hip_runtime.h>
#include <hip/hip_bf16.h>

#define B_ 2
#define L_ 2048
#define D_ 512
#define P_ 32
#define M_ 1024
#define H_ 8
#define HD_ 64
#define WIN_ 256
#define S_ (P_ + L_)        // 2080
#define N_ (B_ * S_)        // 4160

typedef __hip_bfloat16 bf16;
typedef __attribute__((ext_vector_type(8))) short short8;
typedef __attribute__((ext_vector_type(4))) float f32x4;

__device__ __forceinline__ int imin(int a, int b) { return a < b ? a : b; }
__device__ __forceinline__ int imax(int a, int b) { return a > b ? a : b; }

__device__ __forceinline__ float ld_in(const void* p, long i, int f32) {
    return f32 ? ((const float*)p)[i]
               : __bfloat162float(((const bf16*)p)[i]);
}

__device__ __forceinline__ short bfbits(float f) {
    bf16 h = __float2bfloat16(f);
    short s;
    __builtin_memcpy(&s, &h, 2);
    return s;
}

__device__ __forceinline__ float b2f(short s) {
    unsigned int u = ((unsigned int)(unsigned short)s) << 16;
    float f;
    __builtin_memcpy(&f, &u, 4);
    return f;
}

// async global->LDS 16B (m97).  LDS dst wave-uniform base; HW adds lane*16.
__device__ __forceinline__ void gload_lds16(const void* g, void* l) {
    __builtin_amdgcn_global_load_lds(
        (const __attribute__((address_space(1))) unsigned int*)g,
        (__attribute__((address_space(3))) unsigned int*)l, 16, 0, 0);
}

#define F_OW  10   // runtime out-dtype flag (published by prep)

// Free per-wave dtype detect (proven r13): ballot over 128 sampled u16s.
__device__ __forceinline__ int wave_detect(const void* p, int tid) {
    const unsigned short* u = (const unsigned short*)p;
    const int lane = tid & 63;
    unsigned short v0 = u[lane * 2], v1 = u[lane * 2 + 1];
    int hit = ((((v0 >> 7) & 0xFF) >= 0xC0) || (((v1 >> 7) & 0xFF) >= 0xC0)) ? 1 : 0;
    unsigned long long b = __ballot(hit);
    return (__popcll(b) >= 2) ? 1 : 0;
}

// ---------------------------------------------------------------------------
// Fused prep (ballot dtype detect): [0,8320) build_combined ;
// [8320,10368) convert mem_keys ; [10368,10880) weights -> bf16 ;
// [10880,10882) zero LN row-stat buffers.
// Transposed-weight blocks (widx>=3) ALSO emit per-tile column partial sums
// into csPart[widx-3][r0/64][col] (race-free slots, values already in LDS;
// r2 lesson: never do strided colsum loads in a latency-bound tail).
// ---------------------------------------------------------------------------
struct Ptr8 { const void* p[8]; };

__global__ __launch_bounds__(256) void prep_kernel(
    const void* __restrict__ x, const void* __restrict__ pm,
    const void* __restrict__ mk, Ptr8 wptrs,
    bf16* __restrict__ comb, bf16* __restrict__ mkbf, bf16* __restrict__ WT,
    bf16* __restrict__ BigB, int* __restrict__ flags,
    float* __restrict__ csPart, float* __restrict__ st)
{
    __shared__ short T[64][65];
    __shared__ float red2[4][64];
    const int blk = blockIdx.x;
    const int tid = threadIdx.x;
    if (blk < 8320) {
        int i = blk * 256 + tid;
        int d = i & (D_ - 1);
        int r = i >> 9;
        int s = r % S_;
        int b = r / S_;
        const void* src = (s < P_) ? pm : x;
        const int f = wave_detect(src, tid);
        float v;
        if (s < P_) v = ld_in(pm, (long)s * D_ + d, f);
        else        v = ld_in(x, ((long)(b * L_ + (s - P_))) * D_ + d, f);
        comb[i] = __float2bfloat16(v);
        return;
    }
    if (blk < 10368) {
        const int f = wave_detect(mk, tid);
        int i = (blk - 8320) * 256 + tid;
        mkbf[i] = __float2bfloat16(ld_in(mk, i, f));
        return;
    }
    if (blk >= 10880) {
        // zero both stat blocks: 2 * N_ * 2 floats = 16640
        const int t3 = (blk - 10880) * 256 + tid;
        for (int i = t3; i < 2 * N_ * 2; i += 512) st[i] = 0.f;
        return;
    }
    const int t = blk - 10368;
    const int widx = t >> 6;
    const int rem = t & 63;
    const int r0 = (rem >> 3) * 64, c0 = (rem & 7) * 64;
    const void* in = wptrs.p[widx];
    const int flag = wave_detect(in, tid);
    if (widx == 7 && rem == 0 && tid == 0) flags[F_OW] = flag;
    short* o;
    if (widx == 0)      o = (short*)WT;
    else if (widx == 2) o = (short*)(WT + 262144);
    else if (widx == 1) o = (short*)BigB;
    else                o = (short*)(WT + (long)(widx - 1) * 262144);
    if (widx == 0 || widx == 2) {
        #pragma unroll
        for (int i = 0; i < 2; ++i) {
            int ch = tid + i * 256;
            int r = ch >> 3, c8 = (ch & 7) * 8;
            long base = (long)(r0 + r) * 512 + c0 + c8;
            short8 v;
            if (flag) {
                const float4 f0 = *reinterpret_cast<const float4*>((const float*)in + base);
                const float4 f1 = *reinterpret_cast<const float4*>((const float*)in + base + 4);
                v[0]=bfbits(f0.x); v[1]=bfbits(f0.y); v[2]=bfbits(f0.z); v[3]=bfbits(f0.w);
                v[4]=bfbits(f1.x); v[5]=bfbits(f1.y); v[6]=bfbits(f1.z); v[7]=bfbits(f1.w);
            } else {
                v = *reinterpret_cast<const short8*>((const short*)in + base);
            }
            *reinterpret_cast<short8*>(o + base) = v;
        }
        return;
    }
    #pragma unroll
    for (int i = 0; i < 2; ++i) {
        int ch = tid + i * 256;
        int r = ch >> 3, c8 = (ch & 7) * 8;
        long base = (long)(r0 + r) * 512 + c0 + c8;
        if (flag) {
            const float4 f0 = *reinterpret_cast<const float4*>((const float*)in + base);
            const float4 f1 = *reinterpret_cast<const float4*>((const float*)in + base + 4);
            T[r][c8+0]=bfbits(f0.x); T[r][c8+1]=bfbits(f0.y); T[r][c8+2]=bfbits(f0.z); T[r][c8+3]=bfbits(f0.w);
            T[r][c8+4]=bfbits(f1.x); T[r][c8+5]=bfbits(f1.y); T[r][c8+6]=bfbits(f1.z); T[r][c8+7]=bfbits(f1.w);
        } else {
            const short8 v = *reinterpret_cast<const short8*>((const short*)in + base);
            #pragma unroll
            for (int k = 0; k < 8; ++k) T[r][c8+k] = v[k];
        }
    }
    __syncthreads();
    #pragma unroll
    for (int i = 0; i < 2; ++i) {
        int ch = tid + i * 256;
        int n = ch >> 3, c8 = (ch & 7) * 8;
        #pragma unroll
        for (int k = 0; k < 8; ++k)
            o[(long)(c0 + n) * 512 + r0 + c8 + k] = T[c8 + k][n];
    }
    // column-sum partials (only attn_Wq/k/v, attn_Wo, out_W): T intact.
    if (widx >= 3) {
        const int c = tid & 63, q = tid >> 6;
        float s = 0.f;
        #pragma unroll
        for (int j = 0; j < 16; ++j) s += b2f(T[q * 16 + j][c]);
        red2[q][c] = s;
        __syncthreads();
        if (tid < 64) {
            float a = red2[0][tid] + red2[1][tid] + red2[2][tid] + red2[3][tid];
            csPart[(long)(widx - 3) * 4096 + (rem >> 3) * 512 + c0 + tid] = a;
        }
    }
}

// ---------------------------------------------------------------------------
// Batched bf16 transpose: in (z, R, C) -> out (z, C, R).  (only W1 -> W1T now)
// ---------------------------------------------------------------------------
__global__ __launch_bounds__(256) void transpose_b_kernel(
    const bf16* __restrict__ in_, bf16* __restrict__ out_, int R, int C)
{
    const short* in = (const short*)(in_ + (long)blockIdx.z * R * C);
    short* out = (short*)(out_ + (long)blockIdx.z * C * R);
    __shared__ short T[64][65];
    const int r0 = blockIdx.y * 64, c0 = blockIdx.x * 64;
    const int tid = threadIdx.x;
    #pragma unroll
    for (int i = 0; i < 2; ++i) {
        int ch = tid + i * 256;
        int r = ch >> 3, c8 = (ch & 7) * 8;
        int row = imin(r0 + r, R - 1);
        const short8 v = *reinterpret_cast<const short8*>(in + (long)row * C + c0 + c8);
        #pragma unroll
        for (int k = 0; k < 8; ++k) T[r][c8+k] = v[k];
    }
    __syncthreads();
    #pragma unroll
    for (int i = 0; i < 2; ++i) {
        int ch = tid + i * 256;
        int n = ch >> 3, c8 = (ch & 7) * 8;
        #pragma unroll
        for (int k = 0; k < 8; ++k) {
            int col = r0 + c8 + k;
            if (col < R) out[(long)(c0 + n) * R + col] = T[c8 + k][n];
        }
    }
}

// ---------------------------------------------------------------------------
// 64-row MFMA GEMM, UN k-subtiles per barrier pair (proven r7-r13).
// CMODE: 1 bf16 z-strided   2 runtime dtype (flags[F_OW]) (N_,512)
//        7 attn: grp0/1 (q,k) -> (B,H,S,HD) row-major; grp2 (v) -> C2 as
//        (B,H,HD,S) via in-LDS transpose.
// STAT=1: accumulate LN row stats (sum, sumsq of bf16-rounded C) into st.
// FIX=1: val = inv_r * (val - mu_r * colsum[col]); colsum read from
//        prep-computed csPart partials (8 cached loads/col, OFF the K-loop;
//        r3 lesson: in-loop csv accumulation taxes the MFMA loop).
// ---------------------------------------------------------------------------
template<int CMODE, int BN, int UN, int STAT, int FIX>
__global__ __launch_bounds__(256, 4) void gemm64(
    const bf16* __restrict__ A, const bf16* __restrict__ Bb,
    void* __restrict__ C0, void* __restrict__ C1, void* __restrict__ C2,
    const int* __restrict__ flags, float* __restrict__ st,
    const float* __restrict__ cs,
    int Mdim, int Kdim, int lda, int ldb, int ldc,
    long sA, long sB, long sC, int SK)
{
    constexpr int NH = BN / 64;
    __shared__ __align__(16) bf16 SM[UN * 2048 + UN * BN * 32];
    bf16* const As = SM;
    bf16* const Bs = SM + UN * 2048;
    const int tid = threadIdx.x, lane = tid & 63, wid = tid >> 6;
    constexpr int WNc = BN / 4;
    constexpr int NJ = WNc / 16;
    const int m0 = blockIdx.y * 64, n0 = blockIdx.x * BN;
    const int z = blockIdx.z;
    const int bz = z / SK, kc = z - bz * SK;
    const int kLen = Kdim / SK;
    const int kBeg = kc * kLen;
    const bf16* Ab = A + (long)bz * sA;
    const bf16* Bp = Bb + (long)bz * sB;

    const int sRow = tid >> 2, c8 = (tid & 3) * 8;
    int aRow = m0 + sRow;
    if (aRow >= Mdim) aRow = Mdim - 1;
    const bf16* aS = Ab + (long)aRow * lda + c8 + kBeg;
    const bf16* bS[NH];
    #pragma unroll
    for (int h = 0; h < NH; ++h)
        bS[h] = Bp + (long)(n0 + sRow + h * 64) * ldb + c8 + kBeg;

    const int g8 = (lane >> 4) * 8, l15 = lane & 15;
    f32x4 acc[4][NJ] = {};

    for (int k0 = 0; k0 < kLen; k0 += UN * 32) {
        #pragma unroll
        for (int t = 0; t < UN; ++t) {
            gload_lds16(aS + k0 + t * 32, As + t * 2048 + wid * 512);
            #pragma unroll
            for (int h = 0; h < NH; ++h)
                gload_lds16(bS[h] + k0 + t * 32, Bs + t * BN * 32 + h * 2048 + wid * 512);
        }
        __syncthreads();
        #pragma unroll
        for (int t = 0; t < UN; ++t) {
            short8 af[4], bfr[NJ];
            #pragma unroll
            for (int mi = 0; mi < 4; ++mi)
                af[mi] = *reinterpret_cast<const short8*>(
                    &As[t * 2048 + (mi * 16 + l15) * 32 + g8]);
            #pragma unroll
            for (int nj = 0; nj < NJ; ++nj)
                bfr[nj] = *reinterpret_cast<const short8*>(
                    &Bs[t * BN * 32 + (wid * WNc + nj * 16 + l15) * 32 + g8]);
            #pragma unroll
            for (int mi = 0; mi < 4; ++mi)
                #pragma unroll
                for (int nj = 0; nj < NJ; ++nj)
                    acc[mi][nj] = __builtin_amdgcn_mfma_f32_16x16x32_bf16(
                        af[mi], bfr[nj], acc[mi][nj], 0, 0, 0);
        }
        __syncthreads();
    }

    const int g4 = (lane >> 4) * 4;

    // LN-algebraic fixup (consumer side): val = inv_r*(val - mu_r*colsum[col])
    if constexpr (FIX) {
        float csv[NJ];
        #pragma unroll
        for (int nj = 0; nj < NJ; ++nj) {
            int col = n0 + wid * WNc + nj * 16 + l15;
            const float* cp = cs + (long)(col >> 9) * 4096 + (col & 511);
            float s = 0.f;
            #pragma unroll
            for (int j = 0; j < 8; ++j) s += cp[j * 512];
            csv[nj] = s;
        }
        #pragma unroll
        for (int mi = 0; mi < 4; ++mi) {
            #pragma unroll
            for (int r = 0; r < 4; ++r) {
                int row = m0 + mi * 16 + g4 + r;
                float sv = st[(long)row * 2], qv = st[(long)row * 2 + 1];
                float mu = sv * (1.f / 512.f);
                float iv = rsqrtf(qv * (1.f / 512.f) - mu * mu + 1e-5f);
                #pragma unroll
                for (int nj = 0; nj < NJ; ++nj)
                    acc[mi][nj][r] = iv * (acc[mi][nj][r] - mu * csv[nj]);
            }
        }
    }

    // LN row-stat accumulation (producer side), on bf16-rounded values.
    if constexpr (STAT) {
        #pragma unroll
        for (int mi = 0; mi < 4; ++mi)
            #pragma unroll
            for (int nj = 0; nj < NJ; ++nj)
                #pragma unroll
                for (int r = 0; r < 4; ++r)
                    acc[mi][nj][r] = b2f(bfbits(acc[mi][nj][r]));
        float* red = (float*)SM;
        #pragma unroll
        for (int mi = 0; mi < 4; ++mi) {
            #pragma unroll
            for (int r = 0; r < 4; ++r) {
                float sv = 0.f, qv = 0.f;
                #pragma unroll
                for (int nj = 0; nj < NJ; ++nj) {
                    float v = acc[mi][nj][r];
                    sv += v; qv += v * v;
                }
                #pragma unroll
                for (int off = 1; off < 16; off <<= 1) {
                    sv += __shfl_xor(sv, off, 64);
                    qv += __shfl_xor(qv, off, 64);
                }
                if (l15 == 0) {
                    int rr = mi * 16 + g4 + r;
                    red[(wid * 64 + rr) * 2]     = sv;
                    red[(wid * 64 + rr) * 2 + 1] = qv;
                }
            }
        }
        __syncthreads();
        if (tid < 128) {
            int rr = tid & 63, which = tid >> 6;
            if (m0 + rr < Mdim) {
                const int zrow = (int)(sC / (long)ldc) * z;
                float a = red[rr * 2 + which] + red[(64 + rr) * 2 + which]
                        + red[(128 + rr) * 2 + which] + red[(192 + rr) * 2 + which];
                atomicAdd(&st[((long)(zrow + m0 + rr)) * 2 + which], a);
            }
        }
    }

    const int oflag = (CMODE == 2) ? flags[F_OW] : 0;
    const int grp = n0 >> 9;

    if (CMODE == 7 && grp == 2) {
        // v projection -> vhT (B,H,HD,S) via in-LDS transpose.
        bf16* T = SM;
        if constexpr (STAT) __syncthreads();
        #pragma unroll
        for (int mi = 0; mi < 4; ++mi)
            #pragma unroll
            for (int nj = 0; nj < NJ; ++nj)
                #pragma unroll
                for (int r = 0; r < 4; ++r)
                    T[(wid * WNc + nj * 16 + l15) * 72 + mi * 16 + g4 + r] =
                        __float2bfloat16(acc[mi][nj][r]);
        __syncthreads();
        #pragma unroll
        for (int it = 0; it < 2; ++it) {
            int idx = tid + it * 256;
            int d = idx >> 2;            // 0..127
            int sc = (idx & 3) * 16;     // 0..48; 16-chunks never cross s=2080
            int grow = m0 + sc;
            int b = grow / S_;
            int s = grow - b * S_;
            int dg = (n0 - 1024) + d;
            int h = dg >> 6, dd = dg & 63;
            bf16* dst = (bf16*)C2 + ((long)((b * H_ + h) * HD_ + dd)) * S_ + s;
            *reinterpret_cast<short8*>(dst) =
                *reinterpret_cast<const short8*>(&T[d * 72 + sc]);
            *reinterpret_cast<short8*>(dst + 8) =
                *reinterpret_cast<const short8*>(&T[d * 72 + sc + 8]);
        }
        return;
    }

    #pragma unroll
    for (int mi = 0; mi < 4; ++mi) {
        #pragma unroll
        for (int nj = 0; nj < NJ; ++nj) {
            #pragma unroll
            for (int r = 0; r < 4; ++r) {
                int row = m0 + mi * 16 + g4 + r;
                int col = n0 + wid * WNc + nj * 16 + l15;
                if (row >= Mdim) continue;
                float val = acc[mi][nj][r];
                if (CMODE == 1) {
                    ((bf16*)C0)[(long)z * sC + (long)row * ldc + col] = __float2bfloat16(val);
                } else if (CMODE == 2) {
                    long idx = (long)row * 512 + col;
                    if (oflag) ((float*)C0)[idx] = val;
                    else       ((bf16*)C0)[idx] = __float2bfloat16(val);
                } else {            // CMODE 7, grp 0/1
                    int b = row / S_, s = row - b * S_;
                    int c = col - (grp << 9);
                    int h = c >> 6, d = c & 63;
                    long idx = ((long)(b * H_ + h) * S_ + s) * HD_ + d;
                    if (grp == 0)      ((bf16*)C0)[idx] = __float2bfloat16(val);
                    else               ((bf16*)C1)[idx] = __float2bfloat16(val);
                }
            }
        }
    }
}

// ---------------------------------------------------------------------------
// 128x128 MFMA GEMM (m97 shape; r5-proven structure), UN=2 subtiles.
// Mega GEMM only: grid (20, 33).  A (M,K) lda; B (N,K) ldb.
// Epilogue: n0<512 -> vT (B,D,S) via in-LDS transpose; n0>=512 -> Lg.
// ---------------------------------------------------------------------------
__global__ __launch_bounds__(256) void gemm128_mega(
    const bf16* __restrict__ A, const bf16* __restrict__ Bb,
    void* __restrict__ C0, void* __restrict__ C1,
    int Mdim, int Kdim, int lda, int ldb)
{
    __shared__ __align__(16) bf16 SM[4 * 4096];
    bf16* const As = SM;
    bf16* const Bs = SM + 2 * 4096;
    const int tid = threadIdx.x, lane = tid & 63, wid = tid >> 6;
    const int wr = wid >> 1, wc = wid & 1;
    const int m0 = blockIdx.y * 128, n0 = blockIdx.x * 128;

    int aRow0 = m0 + (tid >> 2);
    int aRow1 = aRow0 + 64;
    if (aRow0 >= Mdim) aRow0 = Mdim - 1;
    if (aRow1 >= Mdim) aRow1 = Mdim - 1;
    const int c8 = (tid & 3) * 8;
    const bf16* aSrc0 = A + (long)aRow0 * lda + c8;
    const bf16* aSrc1 = A + (long)aRow1 * lda + c8;
    const bf16* bSrc0 = Bb + (long)(n0 + (tid >> 2)) * ldb + c8;
    const bf16* bSrc1 = bSrc0 + 64 * (long)ldb;

    const int g8 = (lane >> 4) * 8, l15 = lane & 15;
    f32x4 acc[4][4] = {};

    for (int k0 = 0; k0 < Kdim; k0 += 64) {
        #pragma unroll
        for (int t = 0; t < 2; ++t) {
            gload_lds16(aSrc0 + k0 + t * 32, As + t * 4096 + wid * 512);
            gload_lds16(aSrc1 + k0 + t * 32, As + t * 4096 + 2048 + wid * 512);
            gload_lds16(bSrc0 + k0 + t * 32, Bs + t * 4096 + wid * 512);
            gload_lds16(bSrc1 + k0 + t * 32, Bs + t * 4096 + 2048 + wid * 512);
        }
        __syncthreads();
        #pragma unroll
        for (int t = 0; t < 2; ++t) {
            short8 af[4], bfr[4];
            #pragma unroll
            for (int mi = 0; mi < 4; ++mi)
                af[mi] = *reinterpret_cast<const short8*>(
                    &As[t * 4096 + (wr * 64 + mi * 16 + l15) * 32 + g8]);
            #pragma unroll
            for (int nj = 0; nj < 4; ++nj)
                bfr[nj] = *reinterpret_cast<const short8*>(
                    &Bs[t * 4096 + (wc * 64 + nj * 16 + l15) * 32 + g8]);
            #pragma unroll
            for (int mi = 0; mi < 4; ++mi)
                #pragma unroll
                for (int nj = 0; nj < 4; ++nj)
                    acc[mi][nj] = __builtin_amdgcn_mfma_f32_16x16x32_bf16(
                        af[mi], bfr[nj], acc[mi][nj], 0, 0, 0);
        }
        __syncthreads();
    }

    if (n0 >= 512) {
        #pragma unroll
        for (int mi = 0; mi < 4; ++mi) {
            #pragma unroll
            for (int nj = 0; nj < 4; ++nj) {
                #pragma unroll
                for (int r = 0; r < 4; ++r) {
                    int row = m0 + wr * 64 + mi * 16 + (lane >> 4) * 4 + r;
                    int col = n0 + wc * 64 + nj * 16 + l15;
                    if (row >= Mdim) continue;
                    ((bf16*)C0)[(long)row * 2048 + col - 512] =
                        __float2bfloat16(acc[mi][nj][r]);
                }
            }
        }
        return;
    }

    // v region -> vT (B, 512, S_) via in-LDS transpose, two 64-col passes.
    {
        bf16* T = SM;
        const int g4 = (lane >> 4) * 4;
        #pragma unroll
        for (int p = 0; p < 2; ++p) {
            __syncthreads();
            if (wc == p) {
                #pragma unroll
                for (int mi = 0; mi < 4; ++mi)
                    #pragma unroll
                    for (int nj = 0; nj < 4; ++nj)
                        #pragma unroll
                        for (int r = 0; r < 4; ++r)
                            T[(nj * 16 + l15) * 136 + wr * 64 + mi * 16 + g4 + r] =
                                __float2bfloat16(acc[mi][nj][r]);
            }
            __syncthreads();
            #pragma unroll
            for (int it = 0; it < 2; ++it) {
                int idx = tid + it * 256;
                int d = idx >> 3;            // 0..63
                int sc = (idx & 7) * 16;     // 0..112; 16-chunks never cross s=2080
                int grow = m0 + sc;
                if (grow >= Mdim) continue;
                int b = grow / S_;
                int s = grow - b * S_;
                bf16* dst = (bf16*)C1 + ((long)b * 512 + n0 + p * 64 + d) * S_ + s;
                *reinterpret_cast<short8*>(dst) =
                    *reinterpret_cast<const short8*>(&T[d * 136 + sc]);
                *reinterpret_cast<short8*>(dst + 8) =
                    *reinterpret_cast<const short8*>(&T[d * 136 + sc + 8]);
            }
        }
    }
}

// ---------------------------------------------------------------------------
// Reduce split-K state partials: Pst bf16 (B*5, 2^19) -> stT bf16 (B,D,M).
// ---------------------------------------------------------------------------
__global__ __launch_bounds__(256) void reduce_state_kernel(
    const bf16* __restrict__ P, bf16* __restrict__ stT)
{
    long g = ((long)blockIdx.x * 256 + threadIdx.x) * 8;
    int b = (int)(g >> 19);
    long dm = g & ((1L << 19) - 1);
    float s[8] = {};
    #pragma unroll
    for (int c = 0; c < 5; ++c) {
        const short8 v = *reinterpret_cast<const short8*>(
            (const short*)P + (((long)(b * 5 + c)) << 19) + dm);
        #pragma unroll
        for (int k = 0; k < 8; ++k) s[k] += b2f(v[k]);
    }
    short8 o;
    #pragma unroll
    for (int k = 0; k < 8; ++k) o[k] = bfbits(s[k]);
    *reinterpret_cast<short8*>((short*)stT + g) = o;
}

// ---------------------------------------------------------------------------
// Row softmax, one wave per row (no barriers).  Lg (N_, 2048) col-stacked
// [k|q]; grid (N_/4, 2).  Writes W1[hf*N_*M + row*M].
// ---------------------------------------------------------------------------
__global__ __launch_bounds__(256) void softmax_rows_kernel(
    const bf16* __restrict__ w, bf16* __restrict__ o)
{
    const int tid = threadIdx.x;
    const int lane = tid & 63;
    const int row = blockIdx.x * 4 + (tid >> 6);
    const int hf = blockIdx.y;
    const short* src = (const short*)w + (long)row * 2048 + hf * 1024 + lane * 16;
    const short8 v0 = *reinterpret_cast<const short8*>(src);
    const short8 v1 = *reinterpret_cast<const short8*>(src + 8);
    float f[16];
    #pragma unroll
    for (int k = 0; k < 8; ++k) { f[k] = b2f(v0[k]); f[8 + k] = b2f(v1[k]); }
    float mx = f[0];
    #pragma unroll
    for (int k = 1; k < 16; ++k) mx = fmaxf(mx, f[k]);
    #pragma unroll
    for (int off = 32; off > 0; off >>= 1) mx = fmaxf(mx, __shfl_xor(mx, off, 64));
    float s = 0.f;
    #pragma unroll
    for (int k = 0; k < 16; ++k) { f[k] = __expf(f[k] - mx); s += f[k]; }
    #pragma unroll
    for (int off = 32; off > 0; off >>= 1) s += __shfl_xor(s, off, 64);
    const float inv = 1.f / s;
    short8 o0, o1;
    #pragma unroll
    for (int k = 0; k < 8; ++k) { o0[k] = bfbits(f[k] * inv); o1[k] = bfbits(f[8 + k] * inv); }
    short* dst = (short*)o + (long)hf * N_ * M_ + (long)row * M_ + lane * 16;
    *reinterpret_cast<short8*>(dst) = o0;
    *reinterpret_cast<short8*>(dst + 8) = o1;
}

// ---------------------------------------------------------------------------
// MFMA flash banded attention, fixed-max softmax (proven r9).  grid (33,H,B).
// ---------------------------------------------------------------------------
#define SC2_ 0.18033688f     // 0.125 * log2(e)
#define MF2_ 11.5415603f     // 8 * log2(e)

#define PRELOAD(JT) do {                                                     \
    _Pragma("unroll")                                                        \
    for (int i = 0; i < 2; ++i) {                                            \
        int ch = tid + i * 256;                                              \
        int r = ch >> 3, cc8 = (ch & 7) * 8;                                 \
        int j = imin((JT) * 64 + r, S_ - 1);                                 \
        kreg[i] = *reinterpret_cast<const short8*>(kb + (long)j * HD_ + cc8);\
        int jc = (JT) * 64 + cc8;                                            \
        if (jc + 8 <= S_) {                                                  \
            vreg[i] = *reinterpret_cast<const short8*>(vb + (long)r * S_ + jc); \
        } else {                                                             \
            short8 v;                                                        \
            _Pragma("unroll")                                                \
            for (int k = 0; k < 8; ++k)                                      \
                v[k] = ((const short*)vb)[(long)r * S_ + imin(jc + k, S_ - 1)]; \
            vreg[i] = v;                                                     \
        }                                                                    \
    }                                                                        \
} while (0)

__global__ __launch_bounds__(256) void flash_attn_kernel(
    const bf16* __restrict__ qh, const bf16* __restrict__ kh,
    const bf16* __restrict__ vhT, bf16* __restrict__ ao)
{
    const int qt = blockIdx.x, h = blockIdx.y, b = blockIdx.z;
    const int tid = threadIdx.x, w = tid >> 6, lane = tid & 63;
    const int g = lane >> 4, l15 = lane & 15, g8 = g * 8;
    const int q0 = qt * 64;
    __shared__ __align__(16) bf16 Qs[64 * 72];
    __shared__ __align__(16) bf16 Ks[64 * 72];
    __shared__ __align__(16) bf16 Vs[64 * 72];
    __shared__ __align__(16) bf16 Ps[4 * 16 * 88];
    const long bh = (long)(b * H_ + h);
    const bf16* qb = qh + bh * S_ * HD_;
    const bf16* kb = kh + bh * S_ * HD_;
    const bf16* vb = vhT + bh * HD_ * S_;

    #pragma unroll
    for (int i = 0; i < 2; ++i) {
        int ch = tid + i * 256;
        int r = ch >> 3, c8 = (ch & 7) * 8;
        int q = imin(q0 + r, S_ - 1);
        *reinterpret_cast<short8*>(&Qs[r * 72 + c8]) =
            *reinterpret_cast<const short8*>(qb + (long)q * HD_ + c8);
    }
    float lrow[4] = {};
    f32x4 O[4] = {};
    const int tstart = imax(0, q0 - (WIN_ - 1)) >> 6;
    const int tend = imin(S_ - 1, q0 + 63 + (WIN_ - 1)) >> 6;

    short8 kreg[2], vreg[2];
    PRELOAD(tstart);
    __syncthreads();
    const short8 aq0 = *reinterpret_cast<const short8*>(&Qs[(w * 16 + l15) * 72 + g8]);
    const short8 aq1 = *reinterpret_cast<const short8*>(&Qs[(w * 16 + l15) * 72 + 32 + g8]);

    for (int jt = tstart; jt <= tend; ++jt) {
        if (jt > tstart) __syncthreads();
        #pragma unroll
        for (int i = 0; i < 2; ++i) {
            int ch = tid + i * 256;
            int r = ch >> 3, c8 = (ch & 7) * 8;
            *reinterpret_cast<short8*>(&Ks[r * 72 + c8]) = kreg[i];
            *reinterpret_cast<short8*>(&Vs[r * 72 + c8]) = vreg[i];
        }
        __syncthreads();
        if (jt < tend) PRELOAD(jt + 1);

        f32x4 s[4] = {};
        __builtin_amdgcn_s_setprio(1);
        #pragma unroll
        for (int nj = 0; nj < 4; ++nj) {
            const short8 b0 = *reinterpret_cast<const short8*>(&Ks[(nj * 16 + l15) * 72 + g8]);
            const short8 b1 = *reinterpret_cast<const short8*>(&Ks[(nj * 16 + l15) * 72 + 32 + g8]);
            s[nj] = __builtin_amdgcn_mfma_f32_16x16x32_bf16(aq0, b0, s[nj], 0, 0, 0);
            s[nj] = __builtin_amdgcn_mfma_f32_16x16x32_bf16(aq1, b1, s[nj], 0, 0, 0);
        }
        __builtin_amdgcn_s_setprio(0);
        #pragma unroll
        for (int nj = 0; nj < 4; ++nj) {
            int j = jt * 64 + nj * 16 + l15;
            #pragma unroll
            for (int r = 0; r < 4; ++r) {
                int q = q0 + w * 16 + g * 4 + r;
                int dd = q - j;
                bool ok = (dd > -WIN_) && (dd < WIN_) && (q < S_) && (j < S_);
                s[nj][r] = ok ? fmaf(s[nj][r], SC2_, -MF2_) : -1e30f;
            }
        }
        #pragma unroll
        for (int r = 0; r < 4; ++r) {
            float ps = 0.f;
            #pragma unroll
            for (int nj = 0; nj < 4; ++nj) {
                float pv = exp2f(s[nj][r]);
                s[nj][r] = pv;
                ps += pv;
            }
            #pragma unroll
            for (int off = 8; off; off >>= 1) ps += __shfl_xor(ps, off, 64);
            lrow[r] += ps;
        }
        #pragma unroll
        for (int nj = 0; nj < 4; ++nj)
            #pragma unroll
            for (int r = 0; r < 4; ++r)
                Ps[w * 1408 + (g * 4 + r) * 88 + nj * 16 + l15] = __float2bfloat16(s[nj][r]);
        const short8 ap0 = *reinterpret_cast<const short8*>(&Ps[w * 1408 + l15 * 88 + g8]);
        const short8 ap1 = *reinterpret_cast<const short8*>(&Ps[w * 1408 + l15 * 88 + 32 + g8]);
        __builtin_amdgcn_s_setprio(1);
        #pragma unroll
        for (int nj = 0; nj < 4; ++nj) {
            const short8 b0 = *reinterpret_cast<const short8*>(&Vs[(nj * 16 + l15) * 72 + g8]);
            const short8 b1 = *reinterpret_cast<const short8*>(&Vs[(nj * 16 + l15) * 72 + 32 + g8]);
            O[nj] = __builtin_amdgcn_mfma_f32_16x16x32_bf16(ap0, b0, O[nj], 0, 0, 0);
            O[nj] = __builtin_amdgcn_mfma_f32_16x16x32_bf16(ap1, b1, O[nj], 0, 0, 0);
        }
        __builtin_amdgcn_s_setprio(0);
    }
    float inv[4];
    #pragma unroll
    for (int r = 0; r < 4; ++r) inv[r] = lrow[r] > 0.f ? 1.f / lrow[r] : 0.f;
    #pragma unroll
    for (int nj = 0; nj < 4; ++nj) {
        #pragma unroll
        for (int r = 0; r < 4; ++r) {
            int q = q0 + w * 16 + g * 4 + r;
            if (q < S_)
                ao[((long)b * S_ + q) * D_ + h * HD_ + nj * 16 + l15] =
                    __float2bfloat16(O[nj][r] * inv[r]);
        }
    }
}

// ---------------------------------------------------------------------------
// Launch (12 dispatches; LN fused into GEMM epilogues, colsum from prep)
// ---------------------------------------------------------------------------
extern "C" void kernel_launch(void* const* d_in, const int* in_sizes, int n_in,
                              void* d_out, int out_size, void* d_ws, size_t ws_size,
                              hipStream_t stream)
{
    const void* x        = d_in[0];
    const void* pm       = d_in[1];
    const void* mem_keys = d_in[2];

    char* wsb = (char*)d_ws;
    bf16*  comb  = (bf16*)(wsb + 0x0);         // combined
    bf16*  qhB   = (bf16*)(wsb + 0x820000);    // attn q (B,H,S,HD)
    bf16*  khB   = (bf16*)(wsb + 0xC30000);    // attn k (B,H,S,HD)
    bf16*  vT    = (bf16*)(wsb + 0x1040000);   // vT (B,D,S) -> later: tmp (N_,512)
    bf16*  Lg    = (bf16*)(wsb + 0x1450000);   // logits bf16 (N_,2048) 17MB
    bf16*  W1    = (bf16*)(wsb + 0x2490000);   // probs: w_write | w_read 17MB
    bf16*  W1T   = (bf16*)(wsb + 0x34D0000);   // w_write^T (B,M,S) 8.5MB
    bf16*  aobf  = (bf16*)(wsb + 0x34D0000);   // alias: ao after W1T dead
    bf16*  vhT   = (bf16*)(wsb + 0x3CF0000);   // (B,H,HD,S) 4.26MB
    bf16*  Pst   = (bf16*)(wsb + 0x4100000);   // split-K partials (10, 2^19) 10MB
    bf16*  stT   = (bf16*)(wsb + 0x4B00000);   // state^T (B,D,M) 2MB
    bf16*  BigB  = (bf16*)(wsb + 0x4D00000);   // [Wv^T | G_k | G_q] (2560,512)
    bf16*  WT    = (bf16*)(wsb + 0x4F80000);   // 7 slots: Wk,Wq plain; 5 transposed
    bf16*  mkbf  = (bf16*)(wsb + 0x5300000);   // mem_keys bf16 (M,D) 1MB
    int*   flags = (int*)(wsb + 0x5400000);
    float* csP   = (float*)(wsb + 0x5410000);  // colsum partials [5][8][512] f32
    float* stats = (float*)(wsb + 0x5440000);  // LN stats: [2][N_][2] f32
    bf16*  tmp   = vT;                          // alias: vT dead after state GEMM

    Ptr8 p8;
    p8.p[0] = d_in[3]; p8.p[1] = d_in[4]; p8.p[2] = d_in[5]; p8.p[3] = d_in[6];
    p8.p[4] = d_in[7]; p8.p[5] = d_in[8]; p8.p[6] = d_in[9]; p8.p[7] = d_in[14];
    prep_kernel<<<10882, 256, 0, stream>>>(x, pm, mem_keys, p8, comb, mkbf, WT, BigB,
                                           flags, csP, stats);
    #define WTp(i) (WT + (long)(i) * 262144)

    // G = mem_keys @ {mem_Wk, mem_Wq}^T -> BigB rows 512..2559
    gemm64<1,64,2,0,0><<<dim3(8, 16, 2), 256, 0, stream>>>(
        mkbf, WT, BigB + 262144, nullptr, nullptr, flags, nullptr, nullptr,
        M_, 512, 512, 512, 512, 0, 262144L, 524288L, 1);

    // MEGA (128x128): comb @ BigB^T (N=2560): cols<512 -> vT (transposed); rest -> Lg
    gemm128_mega<<<dim3(20, 33), 256, 0, stream>>>(
        comb, BigB, Lg, vT, N_, 512, 512, 512);

    softmax_rows_kernel<<<dim3(N_ / 4, 2), 256, 0, stream>>>(Lg, W1);
    transpose_b_kernel<<<dim3(16, 33, 2), 256, 0, stream>>>(W1, W1T, S_, M_);

    // state^T[b] = vT[b] @ W1T[b]^T  (512 x 1024, K=2080), split-K=5
    gemm64<1,128,1,0,0><<<dim3(8, 8, 10), 256, 0, stream>>>(
        vT, W1T, Pst, nullptr, nullptr, flags, nullptr, nullptr,
        512, S_, S_, S_, 1024, (long)D_ * S_, (long)M_ * S_, (long)D_ * M_, 5);
    reduce_state_kernel<<<512, 256, 0, stream>>>(Pst, stT);

    // mem_out[b] = w_read[b] @ stT[b]^T -> tmp bf16 + LN1 row stats (stats[0])
    gemm64<1,64,2,1,0><<<dim3(8, 33, 2), 256, 0, stream>>>(
        W1 + (long)N_ * M_, stT, tmp, nullptr, nullptr, flags, stats, nullptr,
        S_, M_, M_, M_, 512, (long)S_ * M_, (long)D_ * M_, (long)S_ * D_, 1);

    // attn projections on raw tmp with LN1 fixup: q->qhB, k->khB, v->vhT
    gemm64<7,128,2,0,1><<<dim3(12, 65, 1), 256, 0, stream>>>(
        tmp, WTp(2), qhB, khB, vhT, flags, stats, csP,
        N_, 512, 512, 512, 0, 0, 0, 0, 1);

    flash_attn_kernel<<<dim3(33, H_, B_), 256, 0, stream>>>(qhB, khB, vhT, aobf);

    // ao @ Wo^T -> tmp bf16 + LN2 row stats (stats[1])
    gemm64<1,128,2,1,0><<<dim3(4, 65, 1), 256, 0, stream>>>(
        aobf, WTp(5), tmp, nullptr, nullptr, flags, stats + 2 * N_, nullptr,
        N_, 512, 512, 512, 512, 0, 0, 0, 1);

    // out = LN2-fixup(tmp @ outW^T) -> d_out (runtime dtype); cs = csPart[4]
    gemm64<2,128,2,0,1><<<dim3(4, 65, 1), 256, 0, stream>>>(
        tmp, WTp(6), d_out, nullptr, nullptr, flags, stats + 2 * N_, csP + 4 * 4096,
        N_, 512, 512, 512, 512, 0, 0, 0, 1);
}

// Round 7
// 247.025 us; speedup vs baseline: 1.5382x; 1.0019x over previous
//
#include <hip/hip_runtime.h>
#include <hip/hip_bf16.h>

#define B_ 2
#define L_ 2048
#define D_ 512
#define P_ 32
#define M_ 1024
#define H_ 8
#define HD_ 64
#define WIN_ 256
#define S_ (P_ + L_)        // 2080
#define N_ (B_ * S_)        // 4160

typedef __hip_bfloat16 bf16;
typedef __attribute__((ext_vector_type(8))) short short8;
typedef __attribute__((ext_vector_type(4))) float f32x4;

__device__ __forceinline__ int imin(int a, int b) { return a < b ? a : b; }
__device__ __forceinline__ int imax(int a, int b) { return a > b ? a : b; }

__device__ __forceinline__ float ld_in(const void* p, long i, int f32) {
    return f32 ? ((const float*)p)[i]
               : __bfloat162float(((const bf16*)p)[i]);
}

__device__ __forceinline__ short bfbits(float f) {
    bf16 h = __float2bfloat16(f);
    short s;
    __builtin_memcpy(&s, &h, 2);
    return s;
}

__device__ __forceinline__ float b2f(short s) {
    unsigned int u = ((unsigned int)(unsigned short)s) << 16;
    float f;
    __builtin_memcpy(&f, &u, 4);
    return f;
}

// async global->LDS 16B (m97).  LDS dst wave-uniform base; HW adds lane*16.
__device__ __forceinline__ void gload_lds16(const void* g, void* l) {
    __builtin_amdgcn_global_load_lds(
        (const __attribute__((address_space(1))) unsigned int*)g,
        (__attribute__((address_space(3))) unsigned int*)l, 16, 0, 0);
}

#define F_OW  10   // runtime out-dtype flag (published by prep)

// Free per-wave dtype detect (proven r13): ballot over 128 sampled u16s.
__device__ __forceinline__ int wave_detect(const void* p, int tid) {
    const unsigned short* u = (const unsigned short*)p;
    const int lane = tid & 63;
    unsigned short v0 = u[lane * 2], v1 = u[lane * 2 + 1];
    int hit = ((((v0 >> 7) & 0xFF) >= 0xC0) || (((v1 >> 7) & 0xFF) >= 0xC0)) ? 1 : 0;
    unsigned long long b = __ballot(hit);
    return (__popcll(b) >= 2) ? 1 : 0;
}

// ---------------------------------------------------------------------------
// Fused prep (ballot dtype detect): [0,8320) build_combined ;
// [8320,10368) convert mem_keys ; [10368,10880) weights -> bf16 ;
// [10880,10882) zero LN row-stat + expsum buffers (6*N_ f32 contiguous).
// Transposed-weight blocks (widx>=3) ALSO emit per-tile column partial sums
// into csPart[widx-3][r0/64][col] (race-free slots, values already in LDS).
// ---------------------------------------------------------------------------
struct Ptr8 { const void* p[8]; };

__global__ __launch_bounds__(256) void prep_kernel(
    const void* __restrict__ x, const void* __restrict__ pm,
    const void* __restrict__ mk, Ptr8 wptrs,
    bf16* __restrict__ comb, bf16* __restrict__ mkbf, bf16* __restrict__ WT,
    bf16* __restrict__ BigB, int* __restrict__ flags,
    float* __restrict__ csPart, float* __restrict__ st)
{
    __shared__ short T[64][65];
    __shared__ float red2[4][64];
    const int blk = blockIdx.x;
    const int tid = threadIdx.x;
    if (blk < 8320) {
        int i = blk * 256 + tid;
        int d = i & (D_ - 1);
        int r = i >> 9;
        int s = r % S_;
        int b = r / S_;
        const void* src = (s < P_) ? pm : x;
        const int f = wave_detect(src, tid);
        float v;
        if (s < P_) v = ld_in(pm, (long)s * D_ + d, f);
        else        v = ld_in(x, ((long)(b * L_ + (s - P_))) * D_ + d, f);
        comb[i] = __float2bfloat16(v);
        return;
    }
    if (blk < 10368) {
        const int f = wave_detect(mk, tid);
        int i = (blk - 8320) * 256 + tid;
        mkbf[i] = __float2bfloat16(ld_in(mk, i, f));
        return;
    }
    if (blk >= 10880) {
        // zero stats [2][N_][2] + expsum [2][N_]: 6*N_ f32
        const int t3 = (blk - 10880) * 256 + tid;
        for (int i = t3; i < 6 * N_; i += 512) st[i] = 0.f;
        return;
    }
    const int t = blk - 10368;
    const int widx = t >> 6;
    const int rem = t & 63;
    const int r0 = (rem >> 3) * 64, c0 = (rem & 7) * 64;
    const void* in = wptrs.p[widx];
    const int flag = wave_detect(in, tid);
    if (widx == 7 && rem == 0 && tid == 0) flags[F_OW] = flag;
    short* o;
    if (widx == 0)      o = (short*)WT;
    else if (widx == 2) o = (short*)(WT + 262144);
    else if (widx == 1) o = (short*)BigB;
    else                o = (short*)(WT + (long)(widx - 1) * 262144);
    if (widx == 0 || widx == 2) {
        #pragma unroll
        for (int i = 0; i < 2; ++i) {
            int ch = tid + i * 256;
            int r = ch >> 3, c8 = (ch & 7) * 8;
            long base = (long)(r0 + r) * 512 + c0 + c8;
            short8 v;
            if (flag) {
                const float4 f0 = *reinterpret_cast<const float4*>((const float*)in + base);
                const float4 f1 = *reinterpret_cast<const float4*>((const float*)in + base + 4);
                v[0]=bfbits(f0.x); v[1]=bfbits(f0.y); v[2]=bfbits(f0.z); v[3]=bfbits(f0.w);
                v[4]=bfbits(f1.x); v[5]=bfbits(f1.y); v[6]=bfbits(f1.z); v[7]=bfbits(f1.w);
            } else {
                v = *reinterpret_cast<const short8*>((const short*)in + base);
            }
            *reinterpret_cast<short8*>(o + base) = v;
        }
        return;
    }
    #pragma unroll
    for (int i = 0; i < 2; ++i) {
        int ch = tid + i * 256;
        int r = ch >> 3, c8 = (ch & 7) * 8;
        long base = (long)(r0 + r) * 512 + c0 + c8;
        if (flag) {
            const float4 f0 = *reinterpret_cast<const float4*>((const float*)in + base);
            const float4 f1 = *reinterpret_cast<const float4*>((const float*)in + base + 4);
            T[r][c8+0]=bfbits(f0.x); T[r][c8+1]=bfbits(f0.y); T[r][c8+2]=bfbits(f0.z); T[r][c8+3]=bfbits(f0.w);
            T[r][c8+4]=bfbits(f1.x); T[r][c8+5]=bfbits(f1.y); T[r][c8+6]=bfbits(f1.z); T[r][c8+7]=bfbits(f1.w);
        } else {
            const short8 v = *reinterpret_cast<const short8*>((const short*)in + base);
            #pragma unroll
            for (int k = 0; k < 8; ++k) T[r][c8+k] = v[k];
        }
    }
    __syncthreads();
    #pragma unroll
    for (int i = 0; i < 2; ++i) {
        int ch = tid + i * 256;
        int n = ch >> 3, c8 = (ch & 7) * 8;
        #pragma unroll
        for (int k = 0; k < 8; ++k)
            o[(long)(c0 + n) * 512 + r0 + c8 + k] = T[c8 + k][n];
    }
    // column-sum partials (only attn_Wq/k/v, attn_Wo, out_W): T intact.
    if (widx >= 3) {
        const int c = tid & 63, q = tid >> 6;
        float s = 0.f;
        #pragma unroll
        for (int j = 0; j < 16; ++j) s += b2f(T[q * 16 + j][c]);
        red2[q][c] = s;
        __syncthreads();
        if (tid < 64) {
            float a = red2[0][tid] + red2[1][tid] + red2[2][tid] + red2[3][tid];
            csPart[(long)(widx - 3) * 4096 + (rem >> 3) * 512 + c0 + tid] = a;
        }
    }
}

// ---------------------------------------------------------------------------
// Fused softmax-scale (replaces softmax + transpose dispatches).
// Mega epilogue has accumulated esum[hf][row] = sum(exp(bf16 logit)).
// x<16:  transpose+scale Lg hf0 -> W1T (B,M,S)    (w_write^T, only consumer)
// x>=16: elementwise scale Lg hf1 -> wread (N_,M) (w_read row-major)
// ---------------------------------------------------------------------------
__global__ __launch_bounds__(256) void scale_kernel(
    const bf16* __restrict__ Lg, const float* __restrict__ esum,
    bf16* __restrict__ w1t, bf16* __restrict__ wread)
{
    const int tid = threadIdx.x;
    const int z = blockIdx.z, y = blockIdx.y, x = blockIdx.x;
    if (x >= 16) {
        int gi = (z * 33 + y) * 32 + (x - 16);
        long base = (long)gi * 2048 + (long)tid * 8;
        int row = (int)(base >> 10);
        if (row >= N_) return;
        int col = (int)(base & 1023);
        const float inv = 1.f / esum[N_ + row];
        const short8 v = *reinterpret_cast<const short8*>(
            (const short*)Lg + (long)row * 2048 + 1024 + col);
        short8 o;
        #pragma unroll
        for (int k = 0; k < 8; ++k) o[k] = bfbits(__expf(b2f(v[k])) * inv);
        *reinterpret_cast<short8*>((short*)wread + (long)row * 1024 + col) = o;
        return;
    }
    __shared__ short T[64][65];
    const int r0 = y * 64, c0 = x * 64;
    short* out = (short*)w1t + (long)z * M_ * S_;
    #pragma unroll
    for (int i = 0; i < 2; ++i) {
        int ch = tid + i * 256;
        int r = ch >> 3, c8 = (ch & 7) * 8;
        int s = imin(r0 + r, S_ - 1);
        long grow = (long)z * S_ + s;
        const float inv = 1.f / esum[grow];
        const short8 v = *reinterpret_cast<const short8*>(
            (const short*)Lg + grow * 2048 + c0 + c8);
        #pragma unroll
        for (int k = 0; k < 8; ++k) T[r][c8+k] = bfbits(__expf(b2f(v[k])) * inv);
    }
    __syncthreads();
    #pragma unroll
    for (int i = 0; i < 2; ++i) {
        int ch = tid + i * 256;
        int n = ch >> 3, c8 = (ch & 7) * 8;
        #pragma unroll
        for (int k = 0; k < 8; ++k) {
            int col = r0 + c8 + k;
            if (col < S_) out[(long)(c0 + n) * S_ + col] = T[c8 + k][n];
        }
    }
}

// ---------------------------------------------------------------------------
// 64-row MFMA GEMM, UN k-subtiles per barrier pair (proven r7-r13).
// CMODE: 1 bf16 z-strided   2 runtime dtype (flags[F_OW]) (N_,512)
//        7 attn: grp0/1 (q,k) -> (B,H,S,HD) row-major; grp2 (v) -> C2 as
//        (B,H,HD,S) via in-LDS transpose.
// STAT=1: accumulate LN row stats (sum, sumsq of bf16-rounded C) into st.
// FIX=1: val = inv_r * (val - mu_r * colsum[col]); colsum from prep csPart
//        (8 cached loads/col, OFF the K-loop; r3 lesson).
// ---------------------------------------------------------------------------
template<int CMODE, int BN, int UN, int STAT, int FIX>
__global__ __launch_bounds__(256, 4) void gemm64(
    const bf16* __restrict__ A, const bf16* __restrict__ Bb,
    void* __restrict__ C0, void* __restrict__ C1, void* __restrict__ C2,
    const int* __restrict__ flags, float* __restrict__ st,
    const float* __restrict__ cs,
    int Mdim, int Kdim, int lda, int ldb, int ldc,
    long sA, long sB, long sC, int SK)
{
    constexpr int NH = BN / 64;
    __shared__ __align__(16) bf16 SM[UN * 2048 + UN * BN * 32];
    bf16* const As = SM;
    bf16* const Bs = SM + UN * 2048;
    const int tid = threadIdx.x, lane = tid & 63, wid = tid >> 6;
    constexpr int WNc = BN / 4;
    constexpr int NJ = WNc / 16;
    const int m0 = blockIdx.y * 64, n0 = blockIdx.x * BN;
    const int z = blockIdx.z;
    const int bz = z / SK, kc = z - bz * SK;
    const int kLen = Kdim / SK;
    const int kBeg = kc * kLen;
    const bf16* Ab = A + (long)bz * sA;
    const bf16* Bp = Bb + (long)bz * sB;

    const int sRow = tid >> 2, c8 = (tid & 3) * 8;
    int aRow = m0 + sRow;
    if (aRow >= Mdim) aRow = Mdim - 1;
    const bf16* aS = Ab + (long)aRow * lda + c8 + kBeg;
    const bf16* bS[NH];
    #pragma unroll
    for (int h = 0; h < NH; ++h)
        bS[h] = Bp + (long)(n0 + sRow + h * 64) * ldb + c8 + kBeg;

    const int g8 = (lane >> 4) * 8, l15 = lane & 15;
    f32x4 acc[4][NJ] = {};

    for (int k0 = 0; k0 < kLen; k0 += UN * 32) {
        #pragma unroll
        for (int t = 0; t < UN; ++t) {
            gload_lds16(aS + k0 + t * 32, As + t * 2048 + wid * 512);
            #pragma unroll
            for (int h = 0; h < NH; ++h)
                gload_lds16(bS[h] + k0 + t * 32, Bs + t * BN * 32 + h * 2048 + wid * 512);
        }
        __syncthreads();
        #pragma unroll
        for (int t = 0; t < UN; ++t) {
            short8 af[4], bfr[NJ];
            #pragma unroll
            for (int mi = 0; mi < 4; ++mi)
                af[mi] = *reinterpret_cast<const short8*>(
                    &As[t * 2048 + (mi * 16 + l15) * 32 + g8]);
            #pragma unroll
            for (int nj = 0; nj < NJ; ++nj)
                bfr[nj] = *reinterpret_cast<const short8*>(
                    &Bs[t * BN * 32 + (wid * WNc + nj * 16 + l15) * 32 + g8]);
            #pragma unroll
            for (int mi = 0; mi < 4; ++mi)
                #pragma unroll
                for (int nj = 0; nj < NJ; ++nj)
                    acc[mi][nj] = __builtin_amdgcn_mfma_f32_16x16x32_bf16(
                        af[mi], bfr[nj], acc[mi][nj], 0, 0, 0);
        }
        __syncthreads();
    }

    const int g4 = (lane >> 4) * 4;

    // LN-algebraic fixup (consumer side): val = inv_r*(val - mu_r*colsum[col])
    if constexpr (FIX) {
        float csv[NJ];
        #pragma unroll
        for (int nj = 0; nj < NJ; ++nj) {
            int col = n0 + wid * WNc + nj * 16 + l15;
            const float* cp = cs + (long)(col >> 9) * 4096 + (col & 511);
            float s = 0.f;
            #pragma unroll
            for (int j = 0; j < 8; ++j) s += cp[j * 512];
            csv[nj] = s;
        }
        #pragma unroll
        for (int mi = 0; mi < 4; ++mi) {
            #pragma unroll
            for (int r = 0; r < 4; ++r) {
                int row = m0 + mi * 16 + g4 + r;
                float sv = st[(long)row * 2], qv = st[(long)row * 2 + 1];
                float mu = sv * (1.f / 512.f);
                float iv = rsqrtf(qv * (1.f / 512.f) - mu * mu + 1e-5f);
                #pragma unroll
                for (int nj = 0; nj < NJ; ++nj)
                    acc[mi][nj][r] = iv * (acc[mi][nj][r] - mu * csv[nj]);
            }
        }
    }

    // LN row-stat accumulation (producer side), on bf16-rounded values.
    if constexpr (STAT) {
        #pragma unroll
        for (int mi = 0; mi < 4; ++mi)
            #pragma unroll
            for (int nj = 0; nj < NJ; ++nj)
                #pragma unroll
                for (int r = 0; r < 4; ++r)
                    acc[mi][nj][r] = b2f(bfbits(acc[mi][nj][r]));
        float* red = (float*)SM;
        #pragma unroll
        for (int mi = 0; mi < 4; ++mi) {
            #pragma unroll
            for (int r = 0; r < 4; ++r) {
                float sv = 0.f, qv = 0.f;
                #pragma unroll
                for (int nj = 0; nj < NJ; ++nj) {
                    float v = acc[mi][nj][r];
                    sv += v; qv += v * v;
                }
                #pragma unroll
                for (int off = 1; off < 16; off <<= 1) {
                    sv += __shfl_xor(sv, off, 64);
                    qv += __shfl_xor(qv, off, 64);
                }
                if (l15 == 0) {
                    int rr = mi * 16 + g4 + r;
                    red[(wid * 64 + rr) * 2]     = sv;
                    red[(wid * 64 + rr) * 2 + 1] = qv;
                }
            }
        }
        __syncthreads();
        if (tid < 128) {
            int rr = tid & 63, which = tid >> 6;
            if (m0 + rr < Mdim) {
                const int zrow = (int)(sC / (long)ldc) * z;
                float a = red[rr * 2 + which] + red[(64 + rr) * 2 + which]
                        + red[(128 + rr) * 2 + which] + red[(192 + rr) * 2 + which];
                atomicAdd(&st[((long)(zrow + m0 + rr)) * 2 + which], a);
            }
        }
    }

    const int oflag = (CMODE == 2) ? flags[F_OW] : 0;
    const int grp = n0 >> 9;

    if (CMODE == 7 && grp == 2) {
        // v projection -> vhT (B,H,HD,S) via in-LDS transpose.
        bf16* T = SM;
        if constexpr (STAT) __syncthreads();
        #pragma unroll
        for (int mi = 0; mi < 4; ++mi)
            #pragma unroll
            for (int nj = 0; nj < NJ; ++nj)
                #pragma unroll
                for (int r = 0; r < 4; ++r)
                    T[(wid * WNc + nj * 16 + l15) * 72 + mi * 16 + g4 + r] =
                        __float2bfloat16(acc[mi][nj][r]);
        __syncthreads();
        #pragma unroll
        for (int it = 0; it < 2; ++it) {
            int idx = tid + it * 256;
            int d = idx >> 2;            // 0..127
            int sc = (idx & 3) * 16;     // 0..48; 16-chunks never cross s=2080
            int grow = m0 + sc;
            int b = grow / S_;
            int s = grow - b * S_;
            int dg = (n0 - 1024) + d;
            int h = dg >> 6, dd = dg & 63;
            bf16* dst = (bf16*)C2 + ((long)((b * H_ + h) * HD_ + dd)) * S_ + s;
            *reinterpret_cast<short8*>(dst) =
                *reinterpret_cast<const short8*>(&T[d * 72 + sc]);
            *reinterpret_cast<short8*>(dst + 8) =
                *reinterpret_cast<const short8*>(&T[d * 72 + sc + 8]);
        }
        return;
    }

    #pragma unroll
    for (int mi = 0; mi < 4; ++mi) {
        #pragma unroll
        for (int nj = 0; nj < NJ; ++nj) {
            #pragma unroll
            for (int r = 0; r < 4; ++r) {
                int row = m0 + mi * 16 + g4 + r;
                int col = n0 + wid * WNc + nj * 16 + l15;
                if (row >= Mdim) continue;
                float val = acc[mi][nj][r];
                if (CMODE == 1) {
                    ((bf16*)C0)[(long)z * sC + (long)row * ldc + col] = __float2bfloat16(val);
                } else if (CMODE == 2) {
                    long idx = (long)row * 512 + col;
                    if (oflag) ((float*)C0)[idx] = val;
                    else       ((bf16*)C0)[idx] = __float2bfloat16(val);
                } else {            // CMODE 7, grp 0/1
                    int b = row / S_, s = row - b * S_;
                    int c = col - (grp << 9);
                    int h = c >> 6, d = c & 63;
                    long idx = ((long)(b * H_ + h) * S_ + s) * HD_ + d;
                    if (grp == 0)      ((bf16*)C0)[idx] = __float2bfloat16(val);
                    else               ((bf16*)C1)[idx] = __float2bfloat16(val);
                }
            }
        }
    }
}

// ---------------------------------------------------------------------------
// 128x128 MFMA GEMM (m97 shape; r5-proven structure), UN=2 subtiles.
// Mega GEMM only: grid (20, 33).  A (M,K) lda; B (N,K) ldb.
// Epilogue: n0<512 -> vT (B,D,S) via in-LDS transpose; n0>=512 -> Lg
// + per-row exp-sum accumulation into esum (enables scale_kernel softmax).
// ---------------------------------------------------------------------------
__global__ __launch_bounds__(256) void gemm128_mega(
    const bf16* __restrict__ A, const bf16* __restrict__ Bb,
    void* __restrict__ C0, void* __restrict__ C1, float* __restrict__ esum,
    int Mdim, int Kdim, int lda, int ldb)
{
    __shared__ __align__(16) bf16 SM[4 * 4096];
    bf16* const As = SM;
    bf16* const Bs = SM + 2 * 4096;
    const int tid = threadIdx.x, lane = tid & 63, wid = tid >> 6;
    const int wr = wid >> 1, wc = wid & 1;
    const int m0 = blockIdx.y * 128, n0 = blockIdx.x * 128;

    int aRow0 = m0 + (tid >> 2);
    int aRow1 = aRow0 + 64;
    if (aRow0 >= Mdim) aRow0 = Mdim - 1;
    if (aRow1 >= Mdim) aRow1 = Mdim - 1;
    const int c8 = (tid & 3) * 8;
    const bf16* aSrc0 = A + (long)aRow0 * lda + c8;
    const bf16* aSrc1 = A + (long)aRow1 * lda + c8;
    const bf16* bSrc0 = Bb + (long)(n0 + (tid >> 2)) * ldb + c8;
    const bf16* bSrc1 = bSrc0 + 64 * (long)ldb;

    const int g8 = (lane >> 4) * 8, l15 = lane & 15;
    f32x4 acc[4][4] = {};

    for (int k0 = 0; k0 < Kdim; k0 += 64) {
        #pragma unroll
        for (int t = 0; t < 2; ++t) {
            gload_lds16(aSrc0 + k0 + t * 32, As + t * 4096 + wid * 512);
            gload_lds16(aSrc1 + k0 + t * 32, As + t * 4096 + 2048 + wid * 512);
            gload_lds16(bSrc0 + k0 + t * 32, Bs + t * 4096 + wid * 512);
            gload_lds16(bSrc1 + k0 + t * 32, Bs + t * 4096 + 2048 + wid * 512);
        }
        __syncthreads();
        #pragma unroll
        for (int t = 0; t < 2; ++t) {
            short8 af[4], bfr[4];
            #pragma unroll
            for (int mi = 0; mi < 4; ++mi)
                af[mi] = *reinterpret_cast<const short8*>(
                    &As[t * 4096 + (wr * 64 + mi * 16 + l15) * 32 + g8]);
            #pragma unroll
            for (int nj = 0; nj < 4; ++nj)
                bfr[nj] = *reinterpret_cast<const short8*>(
                    &Bs[t * 4096 + (wc * 64 + nj * 16 + l15) * 32 + g8]);
            #pragma unroll
            for (int mi = 0; mi < 4; ++mi)
                #pragma unroll
                for (int nj = 0; nj < 4; ++nj)
                    acc[mi][nj] = __builtin_amdgcn_mfma_f32_16x16x32_bf16(
                        af[mi], bfr[nj], acc[mi][nj], 0, 0, 0);
        }
        __syncthreads();
    }

    if (n0 >= 512) {
        // logits -> Lg + exp-sum accumulation (off K-loop; bounded logits)
        const int hfo = (n0 >= 1536) ? N_ : 0;
        #pragma unroll
        for (int mi = 0; mi < 4; ++mi) {
            #pragma unroll
            for (int r = 0; r < 4; ++r) {
                int row = m0 + wr * 64 + mi * 16 + (lane >> 4) * 4 + r;
                float ps = 0.f;
                short sb[4];
                #pragma unroll
                for (int nj = 0; nj < 4; ++nj) {
                    short bb = bfbits(acc[mi][nj][r]);
                    sb[nj] = bb;
                    ps += __expf(b2f(bb));
                }
                #pragma unroll
                for (int off = 1; off < 16; off <<= 1) ps += __shfl_xor(ps, off, 64);
                if (row < Mdim) {
                    #pragma unroll
                    for (int nj = 0; nj < 4; ++nj) {
                        int col = n0 + wc * 64 + nj * 16 + l15;
                        ((short*)C0)[(long)row * 2048 + col - 512] = sb[nj];
                    }
                    if (l15 == 0) atomicAdd(&esum[hfo + row], ps);
                }
            }
        }
        return;
    }

    // v region -> vT (B, 512, S_) via in-LDS transpose, two 64-col passes.
    {
        bf16* T = SM;
        const int g4 = (lane >> 4) * 4;
        #pragma unroll
        for (int p = 0; p < 2; ++p) {
            __syncthreads();
            if (wc == p) {
                #pragma unroll
                for (int mi = 0; mi < 4; ++mi)
                    #pragma unroll
                    for (int nj = 0; nj < 4; ++nj)
                        #pragma unroll
                        for (int r = 0; r < 4; ++r)
                            T[(nj * 16 + l15) * 136 + wr * 64 + mi * 16 + g4 + r] =
                                __float2bfloat16(acc[mi][nj][r]);
            }
            __syncthreads();
            #pragma unroll
            for (int it = 0; it < 2; ++it) {
                int idx = tid + it * 256;
                int d = idx >> 3;            // 0..63
                int sc = (idx & 7) * 16;     // 0..112; 16-chunks never cross s=2080
                int grow = m0 + sc;
                if (grow >= Mdim) continue;
                int b = grow / S_;
                int s = grow - b * S_;
                bf16* dst = (bf16*)C1 + ((long)b * 512 + n0 + p * 64 + d) * S_ + s;
                *reinterpret_cast<short8*>(dst) =
                    *reinterpret_cast<const short8*>(&T[d * 136 + sc]);
                *reinterpret_cast<short8*>(dst + 8) =
                    *reinterpret_cast<const short8*>(&T[d * 136 + sc + 8]);
            }
        }
    }
}

// ---------------------------------------------------------------------------
// Reduce split-K state partials: Pst bf16 (B*5, 2^19) -> stT bf16 (B,D,M).
// ---------------------------------------------------------------------------
__global__ __launch_bounds__(256) void reduce_state_kernel(
    const bf16* __restrict__ P, bf16* __restrict__ stT)
{
    long g = ((long)blockIdx.x * 256 + threadIdx.x) * 8;
    int b = (int)(g >> 19);
    long dm = g & ((1L << 19) - 1);
    float s[8] = {};
    #pragma unroll
    for (int c = 0; c < 5; ++c) {
        const short8 v = *reinterpret_cast<const short8*>(
            (const short*)P + (((long)(b * 5 + c)) << 19) + dm);
        #pragma unroll
        for (int k = 0; k < 8; ++k) s[k] += b2f(v[k]);
    }
    short8 o;
    #pragma unroll
    for (int k = 0; k < 8; ++k) o[k] = bfbits(s[k]);
    *reinterpret_cast<short8*>((short*)stT + g) = o;
}

// ---------------------------------------------------------------------------
// MFMA flash banded attention, fixed-max softmax (proven r9).  grid (33,H,B).
// ---------------------------------------------------------------------------
#define SC2_ 0.18033688f     // 0.125 * log2(e)
#define MF2_ 11.5415603f     // 8 * log2(e)

#define PRELOAD(JT) do {                                                     \
    _Pragma("unroll")                                                        \
    for (int i = 0; i < 2; ++i) {                                            \
        int ch = tid + i * 256;                                              \
        int r = ch >> 3, cc8 = (ch & 7) * 8;                                 \
        int j = imin((JT) * 64 + r, S_ - 1);                                 \
        kreg[i] = *reinterpret_cast<const short8*>(kb + (long)j * HD_ + cc8);\
        int jc = (JT) * 64 + cc8;                                            \
        if (jc + 8 <= S_) {                                                  \
            vreg[i] = *reinterpret_cast<const short8*>(vb + (long)r * S_ + jc); \
        } else {                                                             \
            short8 v;                                                        \
            _Pragma("unroll")                                                \
            for (int k = 0; k < 8; ++k)                                      \
                v[k] = ((const short*)vb)[(long)r * S_ + imin(jc + k, S_ - 1)]; \
            vreg[i] = v;                                                     \
        }                                                                    \
    }                                                                        \
} while (0)

__global__ __launch_bounds__(256) void flash_attn_kernel(
    const bf16* __restrict__ qh, const bf16* __restrict__ kh,
    const bf16* __restrict__ vhT, bf16* __restrict__ ao)
{
    const int qt = blockIdx.x, h = blockIdx.y, b = blockIdx.z;
    const int tid = threadIdx.x, w = tid >> 6, lane = tid & 63;
    const int g = lane >> 4, l15 = lane & 15, g8 = g * 8;
    const int q0 = qt * 64;
    __shared__ __align__(16) bf16 Qs[64 * 72];
    __shared__ __align__(16) bf16 Ks[64 * 72];
    __shared__ __align__(16) bf16 Vs[64 * 72];
    __shared__ __align__(16) bf16 Ps[4 * 16 * 88];
    const long bh = (long)(b * H_ + h);
    const bf16* qb = qh + bh * S_ * HD_;
    const bf16* kb = kh + bh * S_ * HD_;
    const bf16* vb = vhT + bh * HD_ * S_;

    #pragma unroll
    for (int i = 0; i < 2; ++i) {
        int ch = tid + i * 256;
        int r = ch >> 3, c8 = (ch & 7) * 8;
        int q = imin(q0 + r, S_ - 1);
        *reinterpret_cast<short8*>(&Qs[r * 72 + c8]) =
            *reinterpret_cast<const short8*>(qb + (long)q * HD_ + c8);
    }
    float lrow[4] = {};
    f32x4 O[4] = {};
    const int tstart = imax(0, q0 - (WIN_ - 1)) >> 6;
    const int tend = imin(S_ - 1, q0 + 63 + (WIN_ - 1)) >> 6;

    short8 kreg[2], vreg[2];
    PRELOAD(tstart);
    __syncthreads();
    const short8 aq0 = *reinterpret_cast<const short8*>(&Qs[(w * 16 + l15) * 72 + g8]);
    const short8 aq1 = *reinterpret_cast<const short8*>(&Qs[(w * 16 + l15) * 72 + 32 + g8]);

    for (int jt = tstart; jt <= tend; ++jt) {
        if (jt > tstart) __syncthreads();
        #pragma unroll
        for (int i = 0; i < 2; ++i) {
            int ch = tid + i * 256;
            int r = ch >> 3, c8 = (ch & 7) * 8;
            *reinterpret_cast<short8*>(&Ks[r * 72 + c8]) = kreg[i];
            *reinterpret_cast<short8*>(&Vs[r * 72 + c8]) = vreg[i];
        }
        __syncthreads();
        if (jt < tend) PRELOAD(jt + 1);

        f32x4 s[4] = {};
        __builtin_amdgcn_s_setprio(1);
        #pragma unroll
        for (int nj = 0; nj < 4; ++nj) {
            const short8 b0 = *reinterpret_cast<const short8*>(&Ks[(nj * 16 + l15) * 72 + g8]);
            const short8 b1 = *reinterpret_cast<const short8*>(&Ks[(nj * 16 + l15) * 72 + 32 + g8]);
            s[nj] = __builtin_amdgcn_mfma_f32_16x16x32_bf16(aq0, b0, s[nj], 0, 0, 0);
            s[nj] = __builtin_amdgcn_mfma_f32_16x16x32_bf16(aq1, b1, s[nj], 0, 0, 0);
        }
        __builtin_amdgcn_s_setprio(0);
        #pragma unroll
        for (int nj = 0; nj < 4; ++nj) {
            int j = jt * 64 + nj * 16 + l15;
            #pragma unroll
            for (int r = 0; r < 4; ++r) {
                int q = q0 + w * 16 + g * 4 + r;
                int dd = q - j;
                bool ok = (dd > -WIN_) && (dd < WIN_) && (q < S_) && (j < S_);
                s[nj][r] = ok ? fmaf(s[nj][r], SC2_, -MF2_) : -1e30f;
            }
        }
        #pragma unroll
        for (int r = 0; r < 4; ++r) {
            float ps = 0.f;
            #pragma unroll
            for (int nj = 0; nj < 4; ++nj) {
                float pv = exp2f(s[nj][r]);
                s[nj][r] = pv;
                ps += pv;
            }
            #pragma unroll
            for (int off = 8; off; off >>= 1) ps += __shfl_xor(ps, off, 64);
            lrow[r] += ps;
        }
        #pragma unroll
        for (int nj = 0; nj < 4; ++nj)
            #pragma unroll
            for (int r = 0; r < 4; ++r)
                Ps[w * 1408 + (g * 4 + r) * 88 + nj * 16 + l15] = __float2bfloat16(s[nj][r]);
        const short8 ap0 = *reinterpret_cast<const short8*>(&Ps[w * 1408 + l15 * 88 + g8]);
        const short8 ap1 = *reinterpret_cast<const short8*>(&Ps[w * 1408 + l15 * 88 + 32 + g8]);
        __builtin_amdgcn_s_setprio(1);
        #pragma unroll
        for (int nj = 0; nj < 4; ++nj) {
            const short8 b0 = *reinterpret_cast<const short8*>(&Vs[(nj * 16 + l15) * 72 + g8]);
            const short8 b1 = *reinterpret_cast<const short8*>(&Vs[(nj * 16 + l15) * 72 + 32 + g8]);
            O[nj] = __builtin_amdgcn_mfma_f32_16x16x32_bf16(ap0, b0, O[nj], 0, 0, 0);
            O[nj] = __builtin_amdgcn_mfma_f32_16x16x32_bf16(ap1, b1, O[nj], 0, 0, 0);
        }
        __builtin_amdgcn_s_setprio(0);
    }
    float inv[4];
    #pragma unroll
    for (int r = 0; r < 4; ++r) inv[r] = lrow[r] > 0.f ? 1.f / lrow[r] : 0.f;
    #pragma unroll
    for (int nj = 0; nj < 4; ++nj) {
        #pragma unroll
        for (int r = 0; r < 4; ++r) {
            int q = q0 + w * 16 + g * 4 + r;
            if (q < S_)
                ao[((long)b * S_ + q) * D_ + h * HD_ + nj * 16 + l15] =
                    __float2bfloat16(O[nj][r] * inv[r]);
        }
    }
}

// ---------------------------------------------------------------------------
// Launch (11 dispatches; softmax+transpose fused into scale_kernel,
// exp-sums accumulated in mega epilogue)
// ---------------------------------------------------------------------------
extern "C" void kernel_launch(void* const* d_in, const int* in_sizes, int n_in,
                              void* d_out, int out_size, void* d_ws, size_t ws_size,
                              hipStream_t stream)
{
    const void* x        = d_in[0];
    const void* pm       = d_in[1];
    const void* mem_keys = d_in[2];

    char* wsb = (char*)d_ws;
    bf16*  comb  = (bf16*)(wsb + 0x0);         // combined
    bf16*  qhB   = (bf16*)(wsb + 0x820000);    // attn q (B,H,S,HD)
    bf16*  khB   = (bf16*)(wsb + 0xC30000);    // attn k (B,H,S,HD)
    bf16*  vT    = (bf16*)(wsb + 0x1040000);   // vT (B,D,S) -> later: tmp (N_,512)
    bf16*  Lg    = (bf16*)(wsb + 0x1450000);   // logits bf16 (N_,2048) 17MB
    bf16*  W1    = (bf16*)(wsb + 0x2490000);   // probs: [unused | w_read] 17MB
    bf16*  W1T   = (bf16*)(wsb + 0x34D0000);   // w_write^T (B,M,S) 8.5MB
    bf16*  aobf  = (bf16*)(wsb + 0x34D0000);   // alias: ao after W1T dead
    bf16*  vhT   = (bf16*)(wsb + 0x3CF0000);   // (B,H,HD,S) 4.26MB
    bf16*  Pst   = (bf16*)(wsb + 0x4100000);   // split-K partials (10, 2^19) 10MB
    bf16*  stT   = (bf16*)(wsb + 0x4B00000);   // state^T (B,D,M) 2MB
    bf16*  BigB  = (bf16*)(wsb + 0x4D00000);   // [Wv^T | G_k | G_q] (2560,512)
    bf16*  WT    = (bf16*)(wsb + 0x4F80000);   // 7 slots: Wk,Wq plain; 5 transposed
    bf16*  mkbf  = (bf16*)(wsb + 0x5300000);   // mem_keys bf16 (M,D) 1MB
    int*   flags = (int*)(wsb + 0x5400000);
    float* csP   = (float*)(wsb + 0x5410000);  // colsum partials [5][8][512] f32
    float* stats = (float*)(wsb + 0x5440000);  // LN stats [2][N_][2] f32
    float* esum  = stats + 4 * N_;             // expsum [2][N_] f32 (contiguous)
    bf16*  tmp   = vT;                          // alias: vT dead after state GEMM

    Ptr8 p8;
    p8.p[0] = d_in[3]; p8.p[1] = d_in[4]; p8.p[2] = d_in[5]; p8.p[3] = d_in[6];
    p8.p[4] = d_in[7]; p8.p[5] = d_in[8]; p8.p[6] = d_in[9]; p8.p[7] = d_in[14];
    prep_kernel<<<10882, 256, 0, stream>>>(x, pm, mem_keys, p8, comb, mkbf, WT, BigB,
                                           flags, csP, stats);
    #define WTp(i) (WT + (long)(i) * 262144)

    // G = mem_keys @ {mem_Wk, mem_Wq}^T -> BigB rows 512..2559
    gemm64<1,64,2,0,0><<<dim3(8, 16, 2), 256, 0, stream>>>(
        mkbf, WT, BigB + 262144, nullptr, nullptr, flags, nullptr, nullptr,
        M_, 512, 512, 512, 512, 0, 262144L, 524288L, 1);

    // MEGA (128x128): comb @ BigB^T: cols<512 -> vT (transposed); rest -> Lg + esum
    gemm128_mega<<<dim3(20, 33), 256, 0, stream>>>(
        comb, BigB, Lg, vT, esum, N_, 512, 512, 512);

    // fused softmax-scale: hf0 -> W1T (transposed), hf1 -> w_read row-major
    scale_kernel<<<dim3(48, 33, 2), 256, 0, stream>>>(Lg, esum, W1T, W1 + (long)N_ * M_);

    // state^T[b] = vT[b] @ W1T[b]^T  (512 x 1024, K=2080), split-K=5
    gemm64<1,128,1,0,0><<<dim3(8, 8, 10), 256, 0, stream>>>(
        vT, W1T, Pst, nullptr, nullptr, flags, nullptr, nullptr,
        512, S_, S_, S_, 1024, (long)D_ * S_, (long)M_ * S_, (long)D_ * M_, 5);
    reduce_state_kernel<<<512, 256, 0, stream>>>(Pst, stT);

    // mem_out[b] = w_read[b] @ stT[b]^T -> tmp bf16 + LN1 row stats (stats[0])
    gemm64<1,64,2,1,0><<<dim3(8, 33, 2), 256, 0, stream>>>(
        W1 + (long)N_ * M_, stT, tmp, nullptr, nullptr, flags, stats, nullptr,
        S_, M_, M_, M_, 512, (long)S_ * M_, (long)D_ * M_, (long)S_ * D_, 1);

    // attn projections on raw tmp with LN1 fixup: q->qhB, k->khB, v->vhT
    gemm64<7,128,2,0,1><<<dim3(12, 65, 1), 256, 0, stream>>>(
        tmp, WTp(2), qhB, khB, vhT, flags, stats, csP,
        N_, 512, 512, 512, 0, 0, 0, 0, 1);

    flash_attn_kernel<<<dim3(33, H_, B_), 256, 0, stream>>>(qhB, khB, vhT, aobf);

    // ao @ Wo^T -> tmp bf16 + LN2 row stats (stats[1])
    gemm64<1,128,2,1,0><<<dim3(4, 65, 1), 256, 0, stream>>>(
        aobf, WTp(5), tmp, nullptr, nullptr, flags, stats + 2 * N_, nullptr,
        N_, 512, 512, 512, 512, 0, 0, 0, 1);

    // out = LN2-fixup(tmp @ outW^T) -> d_out (runtime dtype); cs = csPart[4]
    gemm64<2,128,2,0,1><<<dim3(4, 65, 1), 256, 0, stream>>>(
        tmp, WTp(6), d_out, nullptr, nullptr, flags, stats + 2 * N_, csP + 4 * 4096,
        N_, 512, 512, 512, 512, 0, 0, 0, 1);
}

// Round 8
// 243.337 us; speedup vs baseline: 1.5615x; 1.0152x over previous
//
#include <hip/hip_runtime.h>
#include <hip/hip_bf16.h>

#define B_ 2
#define L_ 2048
#define D_ 512
#define P_ 32
#define M_ 1024
#define H_ 8
#define HD_ 64
#define WIN_ 256
#define S_ (P_ + L_)        // 2080
#define N_ (B_ * S_)        // 4160

typedef __hip_bfloat16 bf16;
typedef __attribute__((ext_vector_type(8))) short short8;
typedef __attribute__((ext_vector_type(4))) float f32x4;

__device__ __forceinline__ int imin(int a, int b) { return a < b ? a : b; }
__device__ __forceinline__ int imax(int a, int b) { return a > b ? a : b; }

__device__ __forceinline__ float ld_in(const void* p, long i, int f32) {
    return f32 ? ((const float*)p)[i]
               : __bfloat162float(((const bf16*)p)[i]);
}

__device__ __forceinline__ short bfbits(float f) {
    bf16 h = __float2bfloat16(f);
    short s;
    __builtin_memcpy(&s, &h, 2);
    return s;
}

__device__ __forceinline__ float b2f(short s) {
    unsigned int u = ((unsigned int)(unsigned short)s) << 16;
    float f;
    __builtin_memcpy(&f, &u, 4);
    return f;
}

// async global->LDS 16B (m97).  LDS dst wave-uniform base; HW adds lane*16.
__device__ __forceinline__ void gload_lds16(const void* g, void* l) {
    __builtin_amdgcn_global_load_lds(
        (const __attribute__((address_space(1))) unsigned int*)g,
        (__attribute__((address_space(3))) unsigned int*)l, 16, 0, 0);
}

#define F_OW  10   // runtime out-dtype flag (published by prep)

// Free per-wave dtype detect (proven r13): ballot over 128 sampled u16s.
__device__ __forceinline__ int wave_detect(const void* p, int tid) {
    const unsigned short* u = (const unsigned short*)p;
    const int lane = tid & 63;
    unsigned short v0 = u[lane * 2], v1 = u[lane * 2 + 1];
    int hit = ((((v0 >> 7) & 0xFF) >= 0xC0) || (((v1 >> 7) & 0xFF) >= 0xC0)) ? 1 : 0;
    unsigned long long b = __ballot(hit);
    return (__popcll(b) >= 2) ? 1 : 0;
}

// load 8 consecutive elems (bf16 bits) from src at elem offset base
__device__ __forceinline__ short8 ld8(const void* src, long base, int f) {
    short8 o;
    if (f) {
        const float4 f0 = *reinterpret_cast<const float4*>((const float*)src + base);
        const float4 f1 = *reinterpret_cast<const float4*>((const float*)src + base + 4);
        o[0]=bfbits(f0.x); o[1]=bfbits(f0.y); o[2]=bfbits(f0.z); o[3]=bfbits(f0.w);
        o[4]=bfbits(f1.x); o[5]=bfbits(f1.y); o[6]=bfbits(f1.z); o[7]=bfbits(f1.w);
    } else {
        o = *reinterpret_cast<const short8*>((const short*)src + base);
    }
    return o;
}

// ---------------------------------------------------------------------------
// Fused prep (ballot dtype detect), VECTORIZED x8 (r8: scalar loads were
// Common-mistake #2): [0,1040) build_combined ; [1040,1296) mem_keys ;
// [1296,1808) weights -> bf16 ; [1808,1810) zero LN/expsum stat buffers.
// Transposed-weight blocks (widx>=3) ALSO emit per-tile column partial sums
// into csPart[widx-3][r0/64][col] (race-free slots, values already in LDS).
// ---------------------------------------------------------------------------
struct Ptr8 { const void* p[8]; };

__global__ __launch_bounds__(256) void prep_kernel(
    const void* __restrict__ x, const void* __restrict__ pm,
    const void* __restrict__ mk, Ptr8 wptrs,
    bf16* __restrict__ comb, bf16* __restrict__ mkbf, bf16* __restrict__ WT,
    bf16* __restrict__ BigB, int* __restrict__ flags,
    float* __restrict__ csPart, float* __restrict__ st)
{
    __shared__ short T[64][65];
    __shared__ float red2[4][64];
    const int blk = blockIdx.x;
    const int tid = threadIdx.x;
    if (blk < 1040) {
        long i8 = ((long)blk * 256 + tid) * 8;
        int d = (int)(i8 & (D_ - 1));
        int r = (int)(i8 >> 9);
        int s = r % S_;
        int b = r / S_;
        const void* src = (s < P_) ? pm : x;
        const int f = wave_detect(src, tid);
        long base = (s < P_) ? ((long)s * D_ + d)
                             : (((long)(b * L_ + (s - P_))) * D_ + d);
        *reinterpret_cast<short8*>((short*)comb + i8) = ld8(src, base, f);
        return;
    }
    if (blk < 1296) {
        const int f = wave_detect(mk, tid);
        long i8 = ((long)(blk - 1040) * 256 + tid) * 8;
        *reinterpret_cast<short8*>((short*)mkbf + i8) = ld8(mk, i8, f);
        return;
    }
    if (blk >= 1808) {
        // zero stats [2][N_][2] + expsum [2][N_]: 6*N_ f32
        const int t3 = (blk - 1808) * 256 + tid;
        for (int i = t3; i < 6 * N_; i += 512) st[i] = 0.f;
        return;
    }
    const int t = blk - 1296;
    const int widx = t >> 6;
    const int rem = t & 63;
    const int r0 = (rem >> 3) * 64, c0 = (rem & 7) * 64;
    const void* in = wptrs.p[widx];
    const int flag = wave_detect(in, tid);
    if (widx == 7 && rem == 0 && tid == 0) flags[F_OW] = flag;
    short* o;
    if (widx == 0)      o = (short*)WT;
    else if (widx == 2) o = (short*)(WT + 262144);
    else if (widx == 1) o = (short*)BigB;
    else                o = (short*)(WT + (long)(widx - 1) * 262144);
    if (widx == 0 || widx == 2) {
        #pragma unroll
        for (int i = 0; i < 2; ++i) {
            int ch = tid + i * 256;
            int r = ch >> 3, c8 = (ch & 7) * 8;
            long base = (long)(r0 + r) * 512 + c0 + c8;
            *reinterpret_cast<short8*>(o + base) = ld8(in, base, flag);
        }
        return;
    }
    #pragma unroll
    for (int i = 0; i < 2; ++i) {
        int ch = tid + i * 256;
        int r = ch >> 3, c8 = (ch & 7) * 8;
        long base = (long)(r0 + r) * 512 + c0 + c8;
        const short8 v = ld8(in, base, flag);
        #pragma unroll
        for (int k = 0; k < 8; ++k) T[r][c8+k] = v[k];
    }
    __syncthreads();
    #pragma unroll
    for (int i = 0; i < 2; ++i) {
        int ch = tid + i * 256;
        int n = ch >> 3, c8 = (ch & 7) * 8;
        #pragma unroll
        for (int k = 0; k < 8; ++k)
            o[(long)(c0 + n) * 512 + r0 + c8 + k] = T[c8 + k][n];
    }
    // column-sum partials (only attn_Wq/k/v, attn_Wo, out_W): T intact.
    if (widx >= 3) {
        const int c = tid & 63, q = tid >> 6;
        float s = 0.f;
        #pragma unroll
        for (int j = 0; j < 16; ++j) s += b2f(T[q * 16 + j][c]);
        red2[q][c] = s;
        __syncthreads();
        if (tid < 64) {
            float a = red2[0][tid] + red2[1][tid] + red2[2][tid] + red2[3][tid];
            csPart[(long)(widx - 3) * 4096 + (rem >> 3) * 512 + c0 + tid] = a;
        }
    }
}

// ---------------------------------------------------------------------------
// Fused softmax-scale (replaces softmax + transpose dispatches).
// Mega epilogue has accumulated esum[hf][row] = sum(exp(bf16 logit)).
// x<16:  transpose+scale Lg hf0 -> W1T (B,M,S)    (w_write^T, only consumer)
// x>=16: elementwise scale Lg hf1 -> wread (N_,M) (w_read row-major)
// ---------------------------------------------------------------------------
__global__ __launch_bounds__(256) void scale_kernel(
    const bf16* __restrict__ Lg, const float* __restrict__ esum,
    bf16* __restrict__ w1t, bf16* __restrict__ wread)
{
    const int tid = threadIdx.x;
    const int z = blockIdx.z, y = blockIdx.y, x = blockIdx.x;
    if (x >= 16) {
        int gi = (z * 33 + y) * 32 + (x - 16);
        long base = (long)gi * 2048 + (long)tid * 8;
        int row = (int)(base >> 10);
        if (row >= N_) return;
        int col = (int)(base & 1023);
        const float inv = 1.f / esum[N_ + row];
        const short8 v = *reinterpret_cast<const short8*>(
            (const short*)Lg + (long)row * 2048 + 1024 + col);
        short8 o;
        #pragma unroll
        for (int k = 0; k < 8; ++k) o[k] = bfbits(__expf(b2f(v[k])) * inv);
        *reinterpret_cast<short8*>((short*)wread + (long)row * 1024 + col) = o;
        return;
    }
    __shared__ short T[64][65];
    const int r0 = y * 64, c0 = x * 64;
    short* out = (short*)w1t + (long)z * M_ * S_;
    #pragma unroll
    for (int i = 0; i < 2; ++i) {
        int ch = tid + i * 256;
        int r = ch >> 3, c8 = (ch & 7) * 8;
        int s = imin(r0 + r, S_ - 1);
        long grow = (long)z * S_ + s;
        const float inv = 1.f / esum[grow];
        const short8 v = *reinterpret_cast<const short8*>(
            (const short*)Lg + grow * 2048 + c0 + c8);
        #pragma unroll
        for (int k = 0; k < 8; ++k) T[r][c8+k] = bfbits(__expf(b2f(v[k])) * inv);
    }
    __syncthreads();
    #pragma unroll
    for (int i = 0; i < 2; ++i) {
        int ch = tid + i * 256;
        int n = ch >> 3, c8 = (ch & 7) * 8;
        #pragma unroll
        for (int k = 0; k < 8; ++k) {
            int col = r0 + c8 + k;
            if (col < S_) out[(long)(c0 + n) * S_ + col] = T[c8 + k][n];
        }
    }
}

// ---------------------------------------------------------------------------
// 64-row MFMA GEMM, UN k-subtiles per barrier pair (proven r7-r13).
// CMODE: 1 bf16 z-strided   2 runtime dtype (flags[F_OW]) (N_,512)
//        7 attn: grp0/1 (q,k) -> (B,H,S,HD) row-major; grp2 (v) -> C2 as
//        (B,H,HD,S) via in-LDS transpose.
// STAT=1: accumulate LN row stats (sum, sumsq of bf16-rounded C) into st.
// FIX=1: val = inv_r * (val - mu_r * colsum[col]); colsum from prep csPart
//        (8 cached loads/col, OFF the K-loop; r3 lesson).
// ---------------------------------------------------------------------------
template<int CMODE, int BN, int UN, int STAT, int FIX>
__global__ __launch_bounds__(256, 4) void gemm64(
    const bf16* __restrict__ A, const bf16* __restrict__ Bb,
    void* __restrict__ C0, void* __restrict__ C1, void* __restrict__ C2,
    const int* __restrict__ flags, float* __restrict__ st,
    const float* __restrict__ cs,
    int Mdim, int Kdim, int lda, int ldb, int ldc,
    long sA, long sB, long sC, int SK)
{
    constexpr int NH = BN / 64;
    __shared__ __align__(16) bf16 SM[UN * 2048 + UN * BN * 32];
    bf16* const As = SM;
    bf16* const Bs = SM + UN * 2048;
    const int tid = threadIdx.x, lane = tid & 63, wid = tid >> 6;
    constexpr int WNc = BN / 4;
    constexpr int NJ = WNc / 16;
    const int m0 = blockIdx.y * 64, n0 = blockIdx.x * BN;
    const int z = blockIdx.z;
    const int bz = z / SK, kc = z - bz * SK;
    const int kLen = Kdim / SK;
    const int kBeg = kc * kLen;
    const bf16* Ab = A + (long)bz * sA;
    const bf16* Bp = Bb + (long)bz * sB;

    const int sRow = tid >> 2, c8 = (tid & 3) * 8;
    int aRow = m0 + sRow;
    if (aRow >= Mdim) aRow = Mdim - 1;
    const bf16* aS = Ab + (long)aRow * lda + c8 + kBeg;
    const bf16* bS[NH];
    #pragma unroll
    for (int h = 0; h < NH; ++h)
        bS[h] = Bp + (long)(n0 + sRow + h * 64) * ldb + c8 + kBeg;

    const int g8 = (lane >> 4) * 8, l15 = lane & 15;
    f32x4 acc[4][NJ] = {};

    for (int k0 = 0; k0 < kLen; k0 += UN * 32) {
        #pragma unroll
        for (int t = 0; t < UN; ++t) {
            gload_lds16(aS + k0 + t * 32, As + t * 2048 + wid * 512);
            #pragma unroll
            for (int h = 0; h < NH; ++h)
                gload_lds16(bS[h] + k0 + t * 32, Bs + t * BN * 32 + h * 2048 + wid * 512);
        }
        __syncthreads();
        #pragma unroll
        for (int t = 0; t < UN; ++t) {
            short8 af[4], bfr[NJ];
            #pragma unroll
            for (int mi = 0; mi < 4; ++mi)
                af[mi] = *reinterpret_cast<const short8*>(
                    &As[t * 2048 + (mi * 16 + l15) * 32 + g8]);
            #pragma unroll
            for (int nj = 0; nj < NJ; ++nj)
                bfr[nj] = *reinterpret_cast<const short8*>(
                    &Bs[t * BN * 32 + (wid * WNc + nj * 16 + l15) * 32 + g8]);
            #pragma unroll
            for (int mi = 0; mi < 4; ++mi)
                #pragma unroll
                for (int nj = 0; nj < NJ; ++nj)
                    acc[mi][nj] = __builtin_amdgcn_mfma_f32_16x16x32_bf16(
                        af[mi], bfr[nj], acc[mi][nj], 0, 0, 0);
        }
        __syncthreads();
    }

    const int g4 = (lane >> 4) * 4;

    // LN-algebraic fixup (consumer side): val = inv_r*(val - mu_r*colsum[col])
    if constexpr (FIX) {
        float csv[NJ];
        #pragma unroll
        for (int nj = 0; nj < NJ; ++nj) {
            int col = n0 + wid * WNc + nj * 16 + l15;
            const float* cp = cs + (long)(col >> 9) * 4096 + (col & 511);
            float s = 0.f;
            #pragma unroll
            for (int j = 0; j < 8; ++j) s += cp[j * 512];
            csv[nj] = s;
        }
        #pragma unroll
        for (int mi = 0; mi < 4; ++mi) {
            #pragma unroll
            for (int r = 0; r < 4; ++r) {
                int row = m0 + mi * 16 + g4 + r;
                float sv = st[(long)row * 2], qv = st[(long)row * 2 + 1];
                float mu = sv * (1.f / 512.f);
                float iv = rsqrtf(qv * (1.f / 512.f) - mu * mu + 1e-5f);
                #pragma unroll
                for (int nj = 0; nj < NJ; ++nj)
                    acc[mi][nj][r] = iv * (acc[mi][nj][r] - mu * csv[nj]);
            }
        }
    }

    // LN row-stat accumulation (producer side), on bf16-rounded values.
    if constexpr (STAT) {
        #pragma unroll
        for (int mi = 0; mi < 4; ++mi)
            #pragma unroll
            for (int nj = 0; nj < NJ; ++nj)
                #pragma unroll
                for (int r = 0; r < 4; ++r)
                    acc[mi][nj][r] = b2f(bfbits(acc[mi][nj][r]));
        float* red = (float*)SM;
        #pragma unroll
        for (int mi = 0; mi < 4; ++mi) {
            #pragma unroll
            for (int r = 0; r < 4; ++r) {
                float sv = 0.f, qv = 0.f;
                #pragma unroll
                for (int nj = 0; nj < NJ; ++nj) {
                    float v = acc[mi][nj][r];
                    sv += v; qv += v * v;
                }
                #pragma unroll
                for (int off = 1; off < 16; off <<= 1) {
                    sv += __shfl_xor(sv, off, 64);
                    qv += __shfl_xor(qv, off, 64);
                }
                if (l15 == 0) {
                    int rr = mi * 16 + g4 + r;
                    red[(wid * 64 + rr) * 2]     = sv;
                    red[(wid * 64 + rr) * 2 + 1] = qv;
                }
            }
        }
        __syncthreads();
        if (tid < 128) {
            int rr = tid & 63, which = tid >> 6;
            if (m0 + rr < Mdim) {
                const int zrow = (int)(sC / (long)ldc) * z;
                float a = red[rr * 2 + which] + red[(64 + rr) * 2 + which]
                        + red[(128 + rr) * 2 + which] + red[(192 + rr) * 2 + which];
                atomicAdd(&st[((long)(zrow + m0 + rr)) * 2 + which], a);
            }
        }
    }

    const int oflag = (CMODE == 2) ? flags[F_OW] : 0;
    const int grp = n0 >> 9;

    if (CMODE == 7 && grp == 2) {
        // v projection -> vhT (B,H,HD,S) via in-LDS transpose.
        bf16* T = SM;
        if constexpr (STAT) __syncthreads();
        #pragma unroll
        for (int mi = 0; mi < 4; ++mi)
            #pragma unroll
            for (int nj = 0; nj < NJ; ++nj)
                #pragma unroll
                for (int r = 0; r < 4; ++r)
                    T[(wid * WNc + nj * 16 + l15) * 72 + mi * 16 + g4 + r] =
                        __float2bfloat16(acc[mi][nj][r]);
        __syncthreads();
        #pragma unroll
        for (int it = 0; it < 2; ++it) {
            int idx = tid + it * 256;
            int d = idx >> 2;            // 0..127
            int sc = (idx & 3) * 16;     // 0..48; 16-chunks never cross s=2080
            int grow = m0 + sc;
            int b = grow / S_;
            int s = grow - b * S_;
            int dg = (n0 - 1024) + d;
            int h = dg >> 6, dd = dg & 63;
            bf16* dst = (bf16*)C2 + ((long)((b * H_ + h) * HD_ + dd)) * S_ + s;
            *reinterpret_cast<short8*>(dst) =
                *reinterpret_cast<const short8*>(&T[d * 72 + sc]);
            *reinterpret_cast<short8*>(dst + 8) =
                *reinterpret_cast<const short8*>(&T[d * 72 + sc + 8]);
        }
        return;
    }

    #pragma unroll
    for (int mi = 0; mi < 4; ++mi) {
        #pragma unroll
        for (int nj = 0; nj < NJ; ++nj) {
            #pragma unroll
            for (int r = 0; r < 4; ++r) {
                int row = m0 + mi * 16 + g4 + r;
                int col = n0 + wid * WNc + nj * 16 + l15;
                if (row >= Mdim) continue;
                float val = acc[mi][nj][r];
                if (CMODE == 1) {
                    ((bf16*)C0)[(long)z * sC + (long)row * ldc + col] = __float2bfloat16(val);
                } else if (CMODE == 2) {
                    long idx = (long)row * 512 + col;
                    if (oflag) ((float*)C0)[idx] = val;
                    else       ((bf16*)C0)[idx] = __float2bfloat16(val);
                } else {            // CMODE 7, grp 0/1
                    int b = row / S_, s = row - b * S_;
                    int c = col - (grp << 9);
                    int h = c >> 6, d = c & 63;
                    long idx = ((long)(b * H_ + h) * S_ + s) * HD_ + d;
                    if (grp == 0)      ((bf16*)C0)[idx] = __float2bfloat16(val);
                    else               ((bf16*)C1)[idx] = __float2bfloat16(val);
                }
            }
        }
    }
}

// ---------------------------------------------------------------------------
// 128x128 MFMA GEMM (m97 shape; r5-proven structure), UN=2 subtiles.
// Mega GEMM only: grid (20, 33).  A (M,K) lda; B (N,K) ldb.
// Epilogue: n0<512 -> vT (B,D,S) via in-LDS transpose; n0>=512 -> Lg
// + per-row exp-sum accumulation into esum (enables scale_kernel softmax).
// ---------------------------------------------------------------------------
__global__ __launch_bounds__(256) void gemm128_mega(
    const bf16* __restrict__ A, const bf16* __restrict__ Bb,
    void* __restrict__ C0, void* __restrict__ C1, float* __restrict__ esum,
    int Mdim, int Kdim, int lda, int ldb)
{
    __shared__ __align__(16) bf16 SM[4 * 4096];
    bf16* const As = SM;
    bf16* const Bs = SM + 2 * 4096;
    const int tid = threadIdx.x, lane = tid & 63, wid = tid >> 6;
    const int wr = wid >> 1, wc = wid & 1;
    const int m0 = blockIdx.y * 128, n0 = blockIdx.x * 128;

    int aRow0 = m0 + (tid >> 2);
    int aRow1 = aRow0 + 64;
    if (aRow0 >= Mdim) aRow0 = Mdim - 1;
    if (aRow1 >= Mdim) aRow1 = Mdim - 1;
    const int c8 = (tid & 3) * 8;
    const bf16* aSrc0 = A + (long)aRow0 * lda + c8;
    const bf16* aSrc1 = A + (long)aRow1 * lda + c8;
    const bf16* bSrc0 = Bb + (long)(n0 + (tid >> 2)) * ldb + c8;
    const bf16* bSrc1 = bSrc0 + 64 * (long)ldb;

    const int g8 = (lane >> 4) * 8, l15 = lane & 15;
    f32x4 acc[4][4] = {};

    for (int k0 = 0; k0 < Kdim; k0 += 64) {
        #pragma unroll
        for (int t = 0; t < 2; ++t) {
            gload_lds16(aSrc0 + k0 + t * 32, As + t * 4096 + wid * 512);
            gload_lds16(aSrc1 + k0 + t * 32, As + t * 4096 + 2048 + wid * 512);
            gload_lds16(bSrc0 + k0 + t * 32, Bs + t * 4096 + wid * 512);
            gload_lds16(bSrc1 + k0 + t * 32, Bs + t * 4096 + 2048 + wid * 512);
        }
        __syncthreads();
        #pragma unroll
        for (int t = 0; t < 2; ++t) {
            short8 af[4], bfr[4];
            #pragma unroll
            for (int mi = 0; mi < 4; ++mi)
                af[mi] = *reinterpret_cast<const short8*>(
                    &As[t * 4096 + (wr * 64 + mi * 16 + l15) * 32 + g8]);
            #pragma unroll
            for (int nj = 0; nj < 4; ++nj)
                bfr[nj] = *reinterpret_cast<const short8*>(
                    &Bs[t * 4096 + (wc * 64 + nj * 16 + l15) * 32 + g8]);
            #pragma unroll
            for (int mi = 0; mi < 4; ++mi)
                #pragma unroll
                for (int nj = 0; nj < 4; ++nj)
                    acc[mi][nj] = __builtin_amdgcn_mfma_f32_16x16x32_bf16(
                        af[mi], bfr[nj], acc[mi][nj], 0, 0, 0);
        }
        __syncthreads();
    }

    if (n0 >= 512) {
        // logits -> Lg + exp-sum accumulation (off K-loop; bounded logits)
        const int hfo = (n0 >= 1536) ? N_ : 0;
        #pragma unroll
        for (int mi = 0; mi < 4; ++mi) {
            #pragma unroll
            for (int r = 0; r < 4; ++r) {
                int row = m0 + wr * 64 + mi * 16 + (lane >> 4) * 4 + r;
                float ps = 0.f;
                short sb[4];
                #pragma unroll
                for (int nj = 0; nj < 4; ++nj) {
                    short bb = bfbits(acc[mi][nj][r]);
                    sb[nj] = bb;
                    ps += __expf(b2f(bb));
                }
                #pragma unroll
                for (int off = 1; off < 16; off <<= 1) ps += __shfl_xor(ps, off, 64);
                if (row < Mdim) {
                    #pragma unroll
                    for (int nj = 0; nj < 4; ++nj) {
                        int col = n0 + wc * 64 + nj * 16 + l15;
                        ((short*)C0)[(long)row * 2048 + col - 512] = sb[nj];
                    }
                    if (l15 == 0) atomicAdd(&esum[hfo + row], ps);
                }
            }
        }
        return;
    }

    // v region -> vT (B, 512, S_) via in-LDS transpose, two 64-col passes.
    {
        bf16* T = SM;
        const int g4 = (lane >> 4) * 4;
        #pragma unroll
        for (int p = 0; p < 2; ++p) {
            __syncthreads();
            if (wc == p) {
                #pragma unroll
                for (int mi = 0; mi < 4; ++mi)
                    #pragma unroll
                    for (int nj = 0; nj < 4; ++nj)
                        #pragma unroll
                        for (int r = 0; r < 4; ++r)
                            T[(nj * 16 + l15) * 136 + wr * 64 + mi * 16 + g4 + r] =
                                __float2bfloat16(acc[mi][nj][r]);
            }
            __syncthreads();
            #pragma unroll
            for (int it = 0; it < 2; ++it) {
                int idx = tid + it * 256;
                int d = idx >> 3;            // 0..63
                int sc = (idx & 7) * 16;     // 0..112; 16-chunks never cross s=2080
                int grow = m0 + sc;
                if (grow >= Mdim) continue;
                int b = grow / S_;
                int s = grow - b * S_;
                bf16* dst = (bf16*)C1 + ((long)b * 512 + n0 + p * 64 + d) * S_ + s;
                *reinterpret_cast<short8*>(dst) =
                    *reinterpret_cast<const short8*>(&T[d * 136 + sc]);
                *reinterpret_cast<short8*>(dst + 8) =
                    *reinterpret_cast<const short8*>(&T[d * 136 + sc + 8]);
            }
        }
    }
}

// ---------------------------------------------------------------------------
// Reduce split-K state partials: Pst bf16 (B*5, 2^19) -> stT bf16 (B,D,M).
// ---------------------------------------------------------------------------
__global__ __launch_bounds__(256) void reduce_state_kernel(
    const bf16* __restrict__ P, bf16* __restrict__ stT)
{
    long g = ((long)blockIdx.x * 256 + threadIdx.x) * 8;
    int b = (int)(g >> 19);
    long dm = g & ((1L << 19) - 1);
    float s[8] = {};
    #pragma unroll
    for (int c = 0; c < 5; ++c) {
        const short8 v = *reinterpret_cast<const short8*>(
            (const short*)P + (((long)(b * 5 + c)) << 19) + dm);
        #pragma unroll
        for (int k = 0; k < 8; ++k) s[k] += b2f(v[k]);
    }
    short8 o;
    #pragma unroll
    for (int k = 0; k < 8; ++k) o[k] = bfbits(s[k]);
    *reinterpret_cast<short8*>((short*)stT + g) = o;
}

// ---------------------------------------------------------------------------
// MFMA flash banded attention, fixed-max softmax (proven r9).  grid (33,H,B).
// ---------------------------------------------------------------------------
#define SC2_ 0.18033688f     // 0.125 * log2(e)
#define MF2_ 11.5415603f     // 8 * log2(e)

#define PRELOAD(JT) do {                                                     \
    _Pragma("unroll")                                                        \
    for (int i = 0; i < 2; ++i) {                                            \
        int ch = tid + i * 256;                                              \
        int r = ch >> 3, cc8 = (ch & 7) * 8;                                 \
        int j = imin((JT) * 64 + r, S_ - 1);                                 \
        kreg[i] = *reinterpret_cast<const short8*>(kb + (long)j * HD_ + cc8);\
        int jc = (JT) * 64 + cc8;                                            \
        if (jc + 8 <= S_) {                                                  \
            vreg[i] = *reinterpret_cast<const short8*>(vb + (long)r * S_ + jc); \
        } else {                                                             \
            short8 v;                                                        \
            _Pragma("unroll")                                                \
            for (int k = 0; k < 8; ++k)                                      \
                v[k] = ((const short*)vb)[(long)r * S_ + imin(jc + k, S_ - 1)]; \
            vreg[i] = v;                                                     \
        }                                                                    \
    }                                                                        \
} while (0)

__global__ __launch_bounds__(256) void flash_attn_kernel(
    const bf16* __restrict__ qh, const bf16* __restrict__ kh,
    const bf16* __restrict__ vhT, bf16* __restrict__ ao)
{
    const int qt = blockIdx.x, h = blockIdx.y, b = blockIdx.z;
    const int tid = threadIdx.x, w = tid >> 6, lane = tid & 63;
    const int g = lane >> 4, l15 = lane & 15, g8 = g * 8;
    const int q0 = qt * 64;
    __shared__ __align__(16) bf16 Qs[64 * 72];
    __shared__ __align__(16) bf16 Ks[64 * 72];
    __shared__ __align__(16) bf16 Vs[64 * 72];
    __shared__ __align__(16) bf16 Ps[4 * 16 * 88];
    const long bh = (long)(b * H_ + h);
    const bf16* qb = qh + bh * S_ * HD_;
    const bf16* kb = kh + bh * S_ * HD_;
    const bf16* vb = vhT + bh * HD_ * S_;

    #pragma unroll
    for (int i = 0; i < 2; ++i) {
        int ch = tid + i * 256;
        int r = ch >> 3, c8 = (ch & 7) * 8;
        int q = imin(q0 + r, S_ - 1);
        *reinterpret_cast<short8*>(&Qs[r * 72 + c8]) =
            *reinterpret_cast<const short8*>(qb + (long)q * HD_ + c8);
    }
    float lrow[4] = {};
    f32x4 O[4] = {};
    const int tstart = imax(0, q0 - (WIN_ - 1)) >> 6;
    const int tend = imin(S_ - 1, q0 + 63 + (WIN_ - 1)) >> 6;

    short8 kreg[2], vreg[2];
    PRELOAD(tstart);
    __syncthreads();
    const short8 aq0 = *reinterpret_cast<const short8*>(&Qs[(w * 16 + l15) * 72 + g8]);
    const short8 aq1 = *reinterpret_cast<const short8*>(&Qs[(w * 16 + l15) * 72 + 32 + g8]);

    for (int jt = tstart; jt <= tend; ++jt) {
        if (jt > tstart) __syncthreads();
        #pragma unroll
        for (int i = 0; i < 2; ++i) {
            int ch = tid + i * 256;
            int r = ch >> 3, c8 = (ch & 7) * 8;
            *reinterpret_cast<short8*>(&Ks[r * 72 + c8]) = kreg[i];
            *reinterpret_cast<short8*>(&Vs[r * 72 + c8]) = vreg[i];
        }
        __syncthreads();
        if (jt < tend) PRELOAD(jt + 1);

        f32x4 s[4] = {};
        __builtin_amdgcn_s_setprio(1);
        #pragma unroll
        for (int nj = 0; nj < 4; ++nj) {
            const short8 b0 = *reinterpret_cast<const short8*>(&Ks[(nj * 16 + l15) * 72 + g8]);
            const short8 b1 = *reinterpret_cast<const short8*>(&Ks[(nj * 16 + l15) * 72 + 32 + g8]);
            s[nj] = __builtin_amdgcn_mfma_f32_16x16x32_bf16(aq0, b0, s[nj], 0, 0, 0);
            s[nj] = __builtin_amdgcn_mfma_f32_16x16x32_bf16(aq1, b1, s[nj], 0, 0, 0);
        }
        __builtin_amdgcn_s_setprio(0);
        #pragma unroll
        for (int nj = 0; nj < 4; ++nj) {
            int j = jt * 64 + nj * 16 + l15;
            #pragma unroll
            for (int r = 0; r < 4; ++r) {
                int q = q0 + w * 16 + g * 4 + r;
                int dd = q - j;
                bool ok = (dd > -WIN_) && (dd < WIN_) && (q < S_) && (j < S_);
                s[nj][r] = ok ? fmaf(s[nj][r], SC2_, -MF2_) : -1e30f;
            }
        }
        #pragma unroll
        for (int r = 0; r < 4; ++r) {
            float ps = 0.f;
            #pragma unroll
            for (int nj = 0; nj < 4; ++nj) {
                float pv = exp2f(s[nj][r]);
                s[nj][r] = pv;
                ps += pv;
            }
            #pragma unroll
            for (int off = 8; off; off >>= 1) ps += __shfl_xor(ps, off, 64);
            lrow[r] += ps;
        }
        #pragma unroll
        for (int nj = 0; nj < 4; ++nj)
            #pragma unroll
            for (int r = 0; r < 4; ++r)
                Ps[w * 1408 + (g * 4 + r) * 88 + nj * 16 + l15] = __float2bfloat16(s[nj][r]);
        const short8 ap0 = *reinterpret_cast<const short8*>(&Ps[w * 1408 + l15 * 88 + g8]);
        const short8 ap1 = *reinterpret_cast<const short8*>(&Ps[w * 1408 + l15 * 88 + 32 + g8]);
        __builtin_amdgcn_s_setprio(1);
        #pragma unroll
        for (int nj = 0; nj < 4; ++nj) {
            const short8 b0 = *reinterpret_cast<const short8*>(&Vs[(nj * 16 + l15) * 72 + g8]);
            const short8 b1 = *reinterpret_cast<const short8*>(&Vs[(nj * 16 + l15) * 72 + 32 + g8]);
            O[nj] = __builtin_amdgcn_mfma_f32_16x16x32_bf16(ap0, b0, O[nj], 0, 0, 0);
            O[nj] = __builtin_amdgcn_mfma_f32_16x16x32_bf16(ap1, b1, O[nj], 0, 0, 0);
        }
        __builtin_amdgcn_s_setprio(0);
    }
    float inv[4];
    #pragma unroll
    for (int r = 0; r < 4; ++r) inv[r] = lrow[r] > 0.f ? 1.f / lrow[r] : 0.f;
    #pragma unroll
    for (int nj = 0; nj < 4; ++nj) {
        #pragma unroll
        for (int r = 0; r < 4; ++r) {
            int q = q0 + w * 16 + g * 4 + r;
            if (q < S_)
                ao[((long)b * S_ + q) * D_ + h * HD_ + nj * 16 + l15] =
                    __float2bfloat16(O[nj][r] * inv[r]);
        }
    }
}

// ---------------------------------------------------------------------------
// Launch (11 dispatches; r8: vectorized prep, BN=64 for the two 260-block
// GEMMs -> 520 blocks = 2/CU so inter-block overlap hides barrier drains)
// ---------------------------------------------------------------------------
extern "C" void kernel_launch(void* const* d_in, const int* in_sizes, int n_in,
                              void* d_out, int out_size, void* d_ws, size_t ws_size,
                              hipStream_t stream)
{
    const void* x        = d_in[0];
    const void* pm       = d_in[1];
    const void* mem_keys = d_in[2];

    char* wsb = (char*)d_ws;
    bf16*  comb  = (bf16*)(wsb + 0x0);         // combined
    bf16*  qhB   = (bf16*)(wsb + 0x820000);    // attn q (B,H,S,HD)
    bf16*  khB   = (bf16*)(wsb + 0xC30000);    // attn k (B,H,S,HD)
    bf16*  vT    = (bf16*)(wsb + 0x1040000);   // vT (B,D,S) -> later: tmp (N_,512)
    bf16*  Lg    = (bf16*)(wsb + 0x1450000);   // logits bf16 (N_,2048) 17MB
    bf16*  W1    = (bf16*)(wsb + 0x2490000);   // probs: [unused | w_read] 17MB
    bf16*  W1T   = (bf16*)(wsb + 0x34D0000);   // w_write^T (B,M,S) 8.5MB
    bf16*  aobf  = (bf16*)(wsb + 0x34D0000);   // alias: ao after W1T dead
    bf16*  vhT   = (bf16*)(wsb + 0x3CF0000);   // (B,H,HD,S) 4.26MB
    bf16*  Pst   = (bf16*)(wsb + 0x4100000);   // split-K partials (10, 2^19) 10MB
    bf16*  stT   = (bf16*)(wsb + 0x4B00000);   // state^T (B,D,M) 2MB
    bf16*  BigB  = (bf16*)(wsb + 0x4D00000);   // [Wv^T | G_k | G_q] (2560,512)
    bf16*  WT    = (bf16*)(wsb + 0x4F80000);   // 7 slots: Wk,Wq plain; 5 transposed
    bf16*  mkbf  = (bf16*)(wsb + 0x5300000);   // mem_keys bf16 (M,D) 1MB
    int*   flags = (int*)(wsb + 0x5400000);
    float* csP   = (float*)(wsb + 0x5410000);  // colsum partials [5][8][512] f32
    float* stats = (float*)(wsb + 0x5440000);  // LN stats [2][N_][2] f32
    float* esum  = stats + 4 * N_;             // expsum [2][N_] f32 (contiguous)
    bf16*  tmp   = vT;                          // alias: vT dead after state GEMM

    Ptr8 p8;
    p8.p[0] = d_in[3]; p8.p[1] = d_in[4]; p8.p[2] = d_in[5]; p8.p[3] = d_in[6];
    p8.p[4] = d_in[7]; p8.p[5] = d_in[8]; p8.p[6] = d_in[9]; p8.p[7] = d_in[14];
    prep_kernel<<<1810, 256, 0, stream>>>(x, pm, mem_keys, p8, comb, mkbf, WT, BigB,
                                          flags, csP, stats);
    #define WTp(i) (WT + (long)(i) * 262144)

    // G = mem_keys @ {mem_Wk, mem_Wq}^T -> BigB rows 512..2559
    gemm64<1,64,2,0,0><<<dim3(8, 16, 2), 256, 0, stream>>>(
        mkbf, WT, BigB + 262144, nullptr, nullptr, flags, nullptr, nullptr,
        M_, 512, 512, 512, 512, 0, 262144L, 524288L, 1);

    // MEGA (128x128): comb @ BigB^T: cols<512 -> vT (transposed); rest -> Lg + esum
    gemm128_mega<<<dim3(20, 33), 256, 0, stream>>>(
        comb, BigB, Lg, vT, esum, N_, 512, 512, 512);

    // fused softmax-scale: hf0 -> W1T (transposed), hf1 -> w_read row-major
    scale_kernel<<<dim3(48, 33, 2), 256, 0, stream>>>(Lg, esum, W1T, W1 + (long)N_ * M_);

    // state^T[b] = vT[b] @ W1T[b]^T  (512 x 1024, K=2080), split-K=5
    gemm64<1,128,1,0,0><<<dim3(8, 8, 10), 256, 0, stream>>>(
        vT, W1T, Pst, nullptr, nullptr, flags, nullptr, nullptr,
        512, S_, S_, S_, 1024, (long)D_ * S_, (long)M_ * S_, (long)D_ * M_, 5);
    reduce_state_kernel<<<512, 256, 0, stream>>>(Pst, stT);

    // mem_out[b] = w_read[b] @ stT[b]^T -> tmp bf16 + LN1 row stats (stats[0])
    gemm64<1,64,2,1,0><<<dim3(8, 33, 2), 256, 0, stream>>>(
        W1 + (long)N_ * M_, stT, tmp, nullptr, nullptr, flags, stats, nullptr,
        S_, M_, M_, M_, 512, (long)S_ * M_, (long)D_ * M_, (long)S_ * D_, 1);

    // attn projections on raw tmp with LN1 fixup: q->qhB, k->khB, v->vhT
    gemm64<7,128,2,0,1><<<dim3(12, 65, 1), 256, 0, stream>>>(
        tmp, WTp(2), qhB, khB, vhT, flags, stats, csP,
        N_, 512, 512, 512, 0, 0, 0, 0, 1);

    flash_attn_kernel<<<dim3(33, H_, B_), 256, 0, stream>>>(qhB, khB, vhT, aobf);

    // ao @ Wo^T -> tmp bf16 + LN2 row stats (stats[1]); BN=64 -> 520 blocks
    gemm64<1,64,2,1,0><<<dim3(8, 65, 1), 256, 0, stream>>>(
        aobf, WTp(5), tmp, nullptr, nullptr, flags, stats + 2 * N_, nullptr,
        N_, 512, 512, 512, 512, 0, 0, 0, 1);

    // out = LN2-fixup(tmp @ outW^T) -> d_out; BN=64 -> 520 blocks; cs = csPart[4]
    gemm64<2,64,2,0,1><<<dim3(8, 65, 1), 256, 0, stream>>>(
        tmp, WTp(6), d_out, nullptr, nullptr, flags, stats + 2 * N_, csP + 4 * 4096,
        N_, 512, 512, 512, 512, 0, 0, 0, 1);
}

// Round 9
// 239.200 us; speedup vs baseline: 1.5885x; 1.0173x over previous
//
#include <hip/hip_runtime.h>
#include <hip/hip_bf16.h>

#define B_ 2
#define L_ 2048
#define D_ 512
#define P_ 32
#define M_ 1024
#define H_ 8
#define HD_ 64
#define WIN_ 256
#define S_ (P_ + L_)        // 2080
#define N_ (B_ * S_)        // 4160

typedef __hip_bfloat16 bf16;
typedef __attribute__((ext_vector_type(8))) short short8;
typedef __attribute__((ext_vector_type(4))) float f32x4;

__device__ __forceinline__ int imin(int a, int b) { return a < b ? a : b; }
__device__ __forceinline__ int imax(int a, int b) { return a > b ? a : b; }

__device__ __forceinline__ float ld_in(const void* p, long i, int f32) {
    return f32 ? ((const float*)p)[i]
               : __bfloat162float(((const bf16*)p)[i]);
}

__device__ __forceinline__ short bfbits(float f) {
    bf16 h = __float2bfloat16(f);
    short s;
    __builtin_memcpy(&s, &h, 2);
    return s;
}

__device__ __forceinline__ float b2f(short s) {
    unsigned int u = ((unsigned int)(unsigned short)s) << 16;
    float f;
    __builtin_memcpy(&f, &u, 4);
    return f;
}

// async global->LDS 16B (m97).  LDS dst wave-uniform base; HW adds lane*16.
__device__ __forceinline__ void gload_lds16(const void* g, void* l) {
    __builtin_amdgcn_global_load_lds(
        (const __attribute__((address_space(1))) unsigned int*)g,
        (__attribute__((address_space(3))) unsigned int*)l, 16, 0, 0);
}

#define F_OW  10   // runtime out-dtype flag (published by prep)

// Free per-wave dtype detect (proven r13): ballot over 128 sampled u16s.
__device__ __forceinline__ int wave_detect(const void* p, int tid) {
    const unsigned short* u = (const unsigned short*)p;
    const int lane = tid & 63;
    unsigned short v0 = u[lane * 2], v1 = u[lane * 2 + 1];
    int hit = ((((v0 >> 7) & 0xFF) >= 0xC0) || (((v1 >> 7) & 0xFF) >= 0xC0)) ? 1 : 0;
    unsigned long long b = __ballot(hit);
    return (__popcll(b) >= 2) ? 1 : 0;
}

// load 8 consecutive elems (bf16 bits) from src at elem offset base
__device__ __forceinline__ short8 ld8(const void* src, long base, int f) {
    short8 o;
    if (f) {
        const float4 f0 = *reinterpret_cast<const float4*>((const float*)src + base);
        const float4 f1 = *reinterpret_cast<const float4*>((const float*)src + base + 4);
        o[0]=bfbits(f0.x); o[1]=bfbits(f0.y); o[2]=bfbits(f0.z); o[3]=bfbits(f0.w);
        o[4]=bfbits(f1.x); o[5]=bfbits(f1.y); o[6]=bfbits(f1.z); o[7]=bfbits(f1.w);
    } else {
        o = *reinterpret_cast<const short8*>((const short*)src + base);
    }
    return o;
}

// ---------------------------------------------------------------------------
// Fused prep (ballot dtype detect), VECTORIZED x8: [0,1040) build_combined ;
// [1040,1296) mem_keys ; [1296,1808) weights -> bf16 ; [1808,1810) zero
// LN/expsum stat buffers.  Transposed-weight blocks (widx>=3) also emit
// per-tile column partial sums into csPart (race-free slots, data in LDS).
// ---------------------------------------------------------------------------
struct Ptr8 { const void* p[8]; };

__global__ __launch_bounds__(256) void prep_kernel(
    const void* __restrict__ x, const void* __restrict__ pm,
    const void* __restrict__ mk, Ptr8 wptrs,
    bf16* __restrict__ comb, bf16* __restrict__ mkbf, bf16* __restrict__ WT,
    bf16* __restrict__ BigB, int* __restrict__ flags,
    float* __restrict__ csPart, float* __restrict__ st)
{
    __shared__ short T[64][65];
    __shared__ float red2[4][64];
    const int blk = blockIdx.x;
    const int tid = threadIdx.x;
    if (blk < 1040) {
        long i8 = ((long)blk * 256 + tid) * 8;
        int d = (int)(i8 & (D_ - 1));
        int r = (int)(i8 >> 9);
        int s = r % S_;
        int b = r / S_;
        const void* src = (s < P_) ? pm : x;
        const int f = wave_detect(src, tid);
        long base = (s < P_) ? ((long)s * D_ + d)
                             : (((long)(b * L_ + (s - P_))) * D_ + d);
        *reinterpret_cast<short8*>((short*)comb + i8) = ld8(src, base, f);
        return;
    }
    if (blk < 1296) {
        const int f = wave_detect(mk, tid);
        long i8 = ((long)(blk - 1040) * 256 + tid) * 8;
        *reinterpret_cast<short8*>((short*)mkbf + i8) = ld8(mk, i8, f);
        return;
    }
    if (blk >= 1808) {
        // zero stats [2][N_][2] + expsum [2][N_]: 6*N_ f32
        const int t3 = (blk - 1808) * 256 + tid;
        for (int i = t3; i < 6 * N_; i += 512) st[i] = 0.f;
        return;
    }
    const int t = blk - 1296;
    const int widx = t >> 6;
    const int rem = t & 63;
    const int r0 = (rem >> 3) * 64, c0 = (rem & 7) * 64;
    const void* in = wptrs.p[widx];
    const int flag = wave_detect(in, tid);
    if (widx == 7 && rem == 0 && tid == 0) flags[F_OW] = flag;
    short* o;
    if (widx == 0)      o = (short*)WT;
    else if (widx == 2) o = (short*)(WT + 262144);
    else if (widx == 1) o = (short*)BigB;
    else                o = (short*)(WT + (long)(widx - 1) * 262144);
    if (widx == 0 || widx == 2) {
        #pragma unroll
        for (int i = 0; i < 2; ++i) {
            int ch = tid + i * 256;
            int r = ch >> 3, c8 = (ch & 7) * 8;
            long base = (long)(r0 + r) * 512 + c0 + c8;
            *reinterpret_cast<short8*>(o + base) = ld8(in, base, flag);
        }
        return;
    }
    #pragma unroll
    for (int i = 0; i < 2; ++i) {
        int ch = tid + i * 256;
        int r = ch >> 3, c8 = (ch & 7) * 8;
        long base = (long)(r0 + r) * 512 + c0 + c8;
        const short8 v = ld8(in, base, flag);
        #pragma unroll
        for (int k = 0; k < 8; ++k) T[r][c8+k] = v[k];
    }
    __syncthreads();
    #pragma unroll
    for (int i = 0; i < 2; ++i) {
        int ch = tid + i * 256;
        int n = ch >> 3, c8 = (ch & 7) * 8;
        #pragma unroll
        for (int k = 0; k < 8; ++k)
            o[(long)(c0 + n) * 512 + r0 + c8 + k] = T[c8 + k][n];
    }
    // column-sum partials (only attn_Wq/k/v, attn_Wo, out_W): T intact.
    if (widx >= 3) {
        const int c = tid & 63, q = tid >> 6;
        float s = 0.f;
        #pragma unroll
        for (int j = 0; j < 16; ++j) s += b2f(T[q * 16 + j][c]);
        red2[q][c] = s;
        __syncthreads();
        if (tid < 64) {
            float a = red2[0][tid] + red2[1][tid] + red2[2][tid] + red2[3][tid];
            csPart[(long)(widx - 3) * 4096 + (rem >> 3) * 512 + c0 + tid] = a;
        }
    }
}

// ---------------------------------------------------------------------------
// Fused softmax-scale (replaces softmax + transpose dispatches).
// Mega epilogue has accumulated esum[hf][row] = sum(exp(bf16 logit)).
// x<16:  transpose+scale Lg hf0 -> W1T (B,M,S)    (w_write^T, only consumer)
// x>=16: elementwise scale Lg hf1 -> wread (N_,M) (w_read row-major)
// ---------------------------------------------------------------------------
__global__ __launch_bounds__(256) void scale_kernel(
    const bf16* __restrict__ Lg, const float* __restrict__ esum,
    bf16* __restrict__ w1t, bf16* __restrict__ wread)
{
    const int tid = threadIdx.x;
    const int z = blockIdx.z, y = blockIdx.y, x = blockIdx.x;
    if (x >= 16) {
        int gi = (z * 33 + y) * 32 + (x - 16);
        long base = (long)gi * 2048 + (long)tid * 8;
        int row = (int)(base >> 10);
        if (row >= N_) return;
        int col = (int)(base & 1023);
        const float inv = 1.f / esum[N_ + row];
        const short8 v = *reinterpret_cast<const short8*>(
            (const short*)Lg + (long)row * 2048 + 1024 + col);
        short8 o;
        #pragma unroll
        for (int k = 0; k < 8; ++k) o[k] = bfbits(__expf(b2f(v[k])) * inv);
        *reinterpret_cast<short8*>((short*)wread + (long)row * 1024 + col) = o;
        return;
    }
    __shared__ short T[64][65];
    const int r0 = y * 64, c0 = x * 64;
    short* out = (short*)w1t + (long)z * M_ * S_;
    #pragma unroll
    for (int i = 0; i < 2; ++i) {
        int ch = tid + i * 256;
        int r = ch >> 3, c8 = (ch & 7) * 8;
        int s = imin(r0 + r, S_ - 1);
        long grow = (long)z * S_ + s;
        const float inv = 1.f / esum[grow];
        const short8 v = *reinterpret_cast<const short8*>(
            (const short*)Lg + grow * 2048 + c0 + c8);
        #pragma unroll
        for (int k = 0; k < 8; ++k) T[r][c8+k] = bfbits(__expf(b2f(v[k])) * inv);
    }
    __syncthreads();
    #pragma unroll
    for (int i = 0; i < 2; ++i) {
        int ch = tid + i * 256;
        int n = ch >> 3, c8 = (ch & 7) * 8;
        #pragma unroll
        for (int k = 0; k < 8; ++k) {
            int col = r0 + c8 + k;
            if (col < S_) out[(long)(c0 + n) * S_ + col] = T[c8 + k][n];
        }
    }
}

// ---------------------------------------------------------------------------
// 64-row MFMA GEMM, r9: DOUBLE-BUFFERED PREFETCH (T3 minimum 2-phase):
// STAGE(t+1) issued BEFORE compute(t); ONE barrier per tile (compiler's
// full drain at __syncthreads completes the in-flight stage).  Previous
// structure (stage-barrier-compute-barrier) had zero intra-block overlap.
// CMODE: 1 bf16 z-strided   2 runtime dtype (flags[F_OW]) (N_,512)
//        7 attn: grp0/1 (q,k) -> (B,H,S,HD) row-major; grp2 (v) -> C2 as
//        (B,H,HD,S) via in-LDS transpose.
// STAT=1: accumulate LN row stats.  FIX=1: LN-algebraic fixup (colsum from
// prep csPart, off the K-loop; r3 lesson).
// ---------------------------------------------------------------------------
template<int CMODE, int BN, int UN, int STAT, int FIX>
__global__ __launch_bounds__(256, 4) void gemm64(
    const bf16* __restrict__ A, const bf16* __restrict__ Bb,
    void* __restrict__ C0, void* __restrict__ C1, void* __restrict__ C2,
    const int* __restrict__ flags, float* __restrict__ st,
    const float* __restrict__ cs,
    int Mdim, int Kdim, int lda, int ldb, int ldc,
    long sA, long sB, long sC, int SK)
{
    constexpr int NH = BN / 64;
    constexpr int BUFE = UN * 2048 + UN * BN * 32;   // elems per LDS buffer
    __shared__ __align__(16) bf16 SM[2 * BUFE];
    const int tid = threadIdx.x, lane = tid & 63, wid = tid >> 6;
    constexpr int WNc = BN / 4;
    constexpr int NJ = WNc / 16;
    const int m0 = blockIdx.y * 64, n0 = blockIdx.x * BN;
    const int z = blockIdx.z;
    const int bz = z / SK, kc = z - bz * SK;
    const int kLen = Kdim / SK;
    const int kBeg = kc * kLen;
    const bf16* Ab = A + (long)bz * sA;
    const bf16* Bp = Bb + (long)bz * sB;

    const int sRow = tid >> 2, c8 = (tid & 3) * 8;
    int aRow = m0 + sRow;
    if (aRow >= Mdim) aRow = Mdim - 1;
    const bf16* aS = Ab + (long)aRow * lda + c8 + kBeg;
    const bf16* bS[NH];
    #pragma unroll
    for (int h = 0; h < NH; ++h)
        bS[h] = Bp + (long)(n0 + sRow + h * 64) * ldb + c8 + kBeg;

    const int g8 = (lane >> 4) * 8, l15 = lane & 15;
    f32x4 acc[4][NJ] = {};

#define STAGE_G64(K0, BUF) do {                                              \
        bf16* As_ = (BUF);                                                   \
        bf16* Bs_ = (BUF) + UN * 2048;                                       \
        _Pragma("unroll")                                                    \
        for (int t = 0; t < UN; ++t) {                                       \
            gload_lds16(aS + (K0) + t * 32, As_ + t * 2048 + wid * 512);     \
            _Pragma("unroll")                                                \
            for (int h = 0; h < NH; ++h)                                     \
                gload_lds16(bS[h] + (K0) + t * 32,                           \
                            Bs_ + t * BN * 32 + h * 2048 + wid * 512);       \
        }                                                                    \
    } while (0)

    STAGE_G64(0, SM);
    __syncthreads();
    const int NT = kLen / (UN * 32);
    int cur = 0;
    for (int it = 0; it < NT; ++it) {
        if (it + 1 < NT) STAGE_G64((it + 1) * (UN * 32), SM + (cur ^ 1) * BUFE);
        bf16* const As = SM + cur * BUFE;
        bf16* const Bs = As + UN * 2048;
        #pragma unroll
        for (int t = 0; t < UN; ++t) {
            short8 af[4], bfr[NJ];
            #pragma unroll
            for (int mi = 0; mi < 4; ++mi)
                af[mi] = *reinterpret_cast<const short8*>(
                    &As[t * 2048 + (mi * 16 + l15) * 32 + g8]);
            #pragma unroll
            for (int nj = 0; nj < NJ; ++nj)
                bfr[nj] = *reinterpret_cast<const short8*>(
                    &Bs[t * BN * 32 + (wid * WNc + nj * 16 + l15) * 32 + g8]);
            #pragma unroll
            for (int mi = 0; mi < 4; ++mi)
                #pragma unroll
                for (int nj = 0; nj < NJ; ++nj)
                    acc[mi][nj] = __builtin_amdgcn_mfma_f32_16x16x32_bf16(
                        af[mi], bfr[nj], acc[mi][nj], 0, 0, 0);
        }
        __syncthreads();   // drains in-flight STAGE (vmcnt) + all reads done
        cur ^= 1;
    }
#undef STAGE_G64

    const int g4 = (lane >> 4) * 4;

    // LN-algebraic fixup (consumer side): val = inv_r*(val - mu_r*colsum[col])
    if constexpr (FIX) {
        float csv[NJ];
        #pragma unroll
        for (int nj = 0; nj < NJ; ++nj) {
            int col = n0 + wid * WNc + nj * 16 + l15;
            const float* cp = cs + (long)(col >> 9) * 4096 + (col & 511);
            float s = 0.f;
            #pragma unroll
            for (int j = 0; j < 8; ++j) s += cp[j * 512];
            csv[nj] = s;
        }
        #pragma unroll
        for (int mi = 0; mi < 4; ++mi) {
            #pragma unroll
            for (int r = 0; r < 4; ++r) {
                int row = m0 + mi * 16 + g4 + r;
                float sv = st[(long)row * 2], qv = st[(long)row * 2 + 1];
                float mu = sv * (1.f / 512.f);
                float iv = rsqrtf(qv * (1.f / 512.f) - mu * mu + 1e-5f);
                #pragma unroll
                for (int nj = 0; nj < NJ; ++nj)
                    acc[mi][nj][r] = iv * (acc[mi][nj][r] - mu * csv[nj]);
            }
        }
    }

    // LN row-stat accumulation (producer side), on bf16-rounded values.
    if constexpr (STAT) {
        #pragma unroll
        for (int mi = 0; mi < 4; ++mi)
            #pragma unroll
            for (int nj = 0; nj < NJ; ++nj)
                #pragma unroll
                for (int r = 0; r < 4; ++r)
                    acc[mi][nj][r] = b2f(bfbits(acc[mi][nj][r]));
        float* red = (float*)SM;
        #pragma unroll
        for (int mi = 0; mi < 4; ++mi) {
            #pragma unroll
            for (int r = 0; r < 4; ++r) {
                float sv = 0.f, qv = 0.f;
                #pragma unroll
                for (int nj = 0; nj < NJ; ++nj) {
                    float v = acc[mi][nj][r];
                    sv += v; qv += v * v;
                }
                #pragma unroll
                for (int off = 1; off < 16; off <<= 1) {
                    sv += __shfl_xor(sv, off, 64);
                    qv += __shfl_xor(qv, off, 64);
                }
                if (l15 == 0) {
                    int rr = mi * 16 + g4 + r;
                    red[(wid * 64 + rr) * 2]     = sv;
                    red[(wid * 64 + rr) * 2 + 1] = qv;
                }
            }
        }
        __syncthreads();
        if (tid < 128) {
            int rr = tid & 63, which = tid >> 6;
            if (m0 + rr < Mdim) {
                const int zrow = (int)(sC / (long)ldc) * z;
                float a = red[rr * 2 + which] + red[(64 + rr) * 2 + which]
                        + red[(128 + rr) * 2 + which] + red[(192 + rr) * 2 + which];
                atomicAdd(&st[((long)(zrow + m0 + rr)) * 2 + which], a);
            }
        }
    }

    const int oflag = (CMODE == 2) ? flags[F_OW] : 0;
    const int grp = n0 >> 9;

    if (CMODE == 7 && grp == 2) {
        // v projection -> vhT (B,H,HD,S) via in-LDS transpose.
        bf16* T = SM;
        if constexpr (STAT) __syncthreads();
        #pragma unroll
        for (int mi = 0; mi < 4; ++mi)
            #pragma unroll
            for (int nj = 0; nj < NJ; ++nj)
                #pragma unroll
                for (int r = 0; r < 4; ++r)
                    T[(wid * WNc + nj * 16 + l15) * 72 + mi * 16 + g4 + r] =
                        __float2bfloat16(acc[mi][nj][r]);
        __syncthreads();
        #pragma unroll
        for (int it = 0; it < 2; ++it) {
            int idx = tid + it * 256;
            int d = idx >> 2;            // 0..127
            int sc = (idx & 3) * 16;     // 0..48; 16-chunks never cross s=2080
            int grow = m0 + sc;
            int b = grow / S_;
            int s = grow - b * S_;
            int dg = (n0 - 1024) + d;
            int h = dg >> 6, dd = dg & 63;
            bf16* dst = (bf16*)C2 + ((long)((b * H_ + h) * HD_ + dd)) * S_ + s;
            *reinterpret_cast<short8*>(dst) =
                *reinterpret_cast<const short8*>(&T[d * 72 + sc]);
            *reinterpret_cast<short8*>(dst + 8) =
                *reinterpret_cast<const short8*>(&T[d * 72 + sc + 8]);
        }
        return;
    }

    #pragma unroll
    for (int mi = 0; mi < 4; ++mi) {
        #pragma unroll
        for (int nj = 0; nj < NJ; ++nj) {
            #pragma unroll
            for (int r = 0; r < 4; ++r) {
                int row = m0 + mi * 16 + g4 + r;
                int col = n0 + wid * WNc + nj * 16 + l15;
                if (row >= Mdim) continue;
                float val = acc[mi][nj][r];
                if (CMODE == 1) {
                    ((bf16*)C0)[(long)z * sC + (long)row * ldc + col] = __float2bfloat16(val);
                } else if (CMODE == 2) {
                    long idx = (long)row * 512 + col;
                    if (oflag) ((float*)C0)[idx] = val;
                    else       ((bf16*)C0)[idx] = __float2bfloat16(val);
                } else {            // CMODE 7, grp 0/1
                    int b = row / S_, s = row - b * S_;
                    int c = col - (grp << 9);
                    int h = c >> 6, d = c & 63;
                    long idx = ((long)(b * H_ + h) * S_ + s) * HD_ + d;
                    if (grp == 0)      ((bf16*)C0)[idx] = __float2bfloat16(val);
                    else               ((bf16*)C1)[idx] = __float2bfloat16(val);
                }
            }
        }
    }
}

// ---------------------------------------------------------------------------
// 128x128 MFMA GEMM (m97 shape; r5-proven structure), UN=2 subtiles.
// Mega GEMM only: grid (20, 33).  A (M,K) lda; B (N,K) ldb.
// (NOT double-buffered: 64 KB LDS would drop occupancy to 2/CU — m132.)
// Epilogue: n0<512 -> vT (B,D,S) via in-LDS transpose; n0>=512 -> Lg
// + per-row exp-sum accumulation into esum (enables scale_kernel softmax).
// ---------------------------------------------------------------------------
__global__ __launch_bounds__(256) void gemm128_mega(
    const bf16* __restrict__ A, const bf16* __restrict__ Bb,
    void* __restrict__ C0, void* __restrict__ C1, float* __restrict__ esum,
    int Mdim, int Kdim, int lda, int ldb)
{
    __shared__ __align__(16) bf16 SM[4 * 4096];
    bf16* const As = SM;
    bf16* const Bs = SM + 2 * 4096;
    const int tid = threadIdx.x, lane = tid & 63, wid = tid >> 6;
    const int wr = wid >> 1, wc = wid & 1;
    const int m0 = blockIdx.y * 128, n0 = blockIdx.x * 128;

    int aRow0 = m0 + (tid >> 2);
    int aRow1 = aRow0 + 64;
    if (aRow0 >= Mdim) aRow0 = Mdim - 1;
    if (aRow1 >= Mdim) aRow1 = Mdim - 1;
    const int c8 = (tid & 3) * 8;
    const bf16* aSrc0 = A + (long)aRow0 * lda + c8;
    const bf16* aSrc1 = A + (long)aRow1 * lda + c8;
    const bf16* bSrc0 = Bb + (long)(n0 + (tid >> 2)) * ldb + c8;
    const bf16* bSrc1 = bSrc0 + 64 * (long)ldb;

    const int g8 = (lane >> 4) * 8, l15 = lane & 15;
    f32x4 acc[4][4] = {};

    for (int k0 = 0; k0 < Kdim; k0 += 64) {
        #pragma unroll
        for (int t = 0; t < 2; ++t) {
            gload_lds16(aSrc0 + k0 + t * 32, As + t * 4096 + wid * 512);
            gload_lds16(aSrc1 + k0 + t * 32, As + t * 4096 + 2048 + wid * 512);
            gload_lds16(bSrc0 + k0 + t * 32, Bs + t * 4096 + wid * 512);
            gload_lds16(bSrc1 + k0 + t * 32, Bs + t * 4096 + 2048 + wid * 512);
        }
        __syncthreads();
        #pragma unroll
        for (int t = 0; t < 2; ++t) {
            short8 af[4], bfr[4];
            #pragma unroll
            for (int mi = 0; mi < 4; ++mi)
                af[mi] = *reinterpret_cast<const short8*>(
                    &As[t * 4096 + (wr * 64 + mi * 16 + l15) * 32 + g8]);
            #pragma unroll
            for (int nj = 0; nj < 4; ++nj)
                bfr[nj] = *reinterpret_cast<const short8*>(
                    &Bs[t * 4096 + (wc * 64 + nj * 16 + l15) * 32 + g8]);
            #pragma unroll
            for (int mi = 0; mi < 4; ++mi)
                #pragma unroll
                for (int nj = 0; nj < 4; ++nj)
                    acc[mi][nj] = __builtin_amdgcn_mfma_f32_16x16x32_bf16(
                        af[mi], bfr[nj], acc[mi][nj], 0, 0, 0);
        }
        __syncthreads();
    }

    if (n0 >= 512) {
        // logits -> Lg + exp-sum accumulation (off K-loop; bounded logits)
        const int hfo = (n0 >= 1536) ? N_ : 0;
        #pragma unroll
        for (int mi = 0; mi < 4; ++mi) {
            #pragma unroll
            for (int r = 0; r < 4; ++r) {
                int row = m0 + wr * 64 + mi * 16 + (lane >> 4) * 4 + r;
                float ps = 0.f;
                short sb[4];
                #pragma unroll
                for (int nj = 0; nj < 4; ++nj) {
                    short bb = bfbits(acc[mi][nj][r]);
                    sb[nj] = bb;
                    ps += __expf(b2f(bb));
                }
                #pragma unroll
                for (int off = 1; off < 16; off <<= 1) ps += __shfl_xor(ps, off, 64);
                if (row < Mdim) {
                    #pragma unroll
                    for (int nj = 0; nj < 4; ++nj) {
                        int col = n0 + wc * 64 + nj * 16 + l15;
                        ((short*)C0)[(long)row * 2048 + col - 512] = sb[nj];
                    }
                    if (l15 == 0) atomicAdd(&esum[hfo + row], ps);
                }
            }
        }
        return;
    }

    // v region -> vT (B, 512, S_) via in-LDS transpose, two 64-col passes.
    {
        bf16* T = SM;
        const int g4 = (lane >> 4) * 4;
        #pragma unroll
        for (int p = 0; p < 2; ++p) {
            __syncthreads();
            if (wc == p) {
                #pragma unroll
                for (int mi = 0; mi < 4; ++mi)
                    #pragma unroll
                    for (int nj = 0; nj < 4; ++nj)
                        #pragma unroll
                        for (int r = 0; r < 4; ++r)
                            T[(nj * 16 + l15) * 136 + wr * 64 + mi * 16 + g4 + r] =
                                __float2bfloat16(acc[mi][nj][r]);
            }
            __syncthreads();
            #pragma unroll
            for (int it = 0; it < 2; ++it) {
                int idx = tid + it * 256;
                int d = idx >> 3;            // 0..63
                int sc = (idx & 7) * 16;     // 0..112; 16-chunks never cross s=2080
                int grow = m0 + sc;
                if (grow >= Mdim) continue;
                int b = grow / S_;
                int s = grow - b * S_;
                bf16* dst = (bf16*)C1 + ((long)b * 512 + n0 + p * 64 + d) * S_ + s;
                *reinterpret_cast<short8*>(dst) =
                    *reinterpret_cast<const short8*>(&T[d * 136 + sc]);
                *reinterpret_cast<short8*>(dst + 8) =
                    *reinterpret_cast<const short8*>(&T[d * 136 + sc + 8]);
            }
        }
    }
}

// ---------------------------------------------------------------------------
// Reduce split-K state partials: Pst bf16 (B*5, 2^19) -> stT bf16 (B,D,M).
// ---------------------------------------------------------------------------
__global__ __launch_bounds__(256) void reduce_state_kernel(
    const bf16* __restrict__ P, bf16* __restrict__ stT)
{
    long g = ((long)blockIdx.x * 256 + threadIdx.x) * 8;
    int b = (int)(g >> 19);
    long dm = g & ((1L << 19) - 1);
    float s[8] = {};
    #pragma unroll
    for (int c = 0; c < 5; ++c) {
        const short8 v = *reinterpret_cast<const short8*>(
            (const short*)P + (((long)(b * 5 + c)) << 19) + dm);
        #pragma unroll
        for (int k = 0; k < 8; ++k) s[k] += b2f(v[k]);
    }
    short8 o;
    #pragma unroll
    for (int k = 0; k < 8; ++k) o[k] = bfbits(s[k]);
    *reinterpret_cast<short8*>((short*)stT + g) = o;
}

// ---------------------------------------------------------------------------
// MFMA flash banded attention, fixed-max softmax (proven r9).  grid (33,H,B).
// ---------------------------------------------------------------------------
#define SC2_ 0.18033688f     // 0.125 * log2(e)
#define MF2_ 11.5415603f     // 8 * log2(e)

#define PRELOAD(JT) do {                                                     \
    _Pragma("unroll")                                                        \
    for (int i = 0; i < 2; ++i) {                                            \
        int ch = tid + i * 256;                                              \
        int r = ch >> 3, cc8 = (ch & 7) * 8;                                 \
        int j = imin((JT) * 64 + r, S_ - 1);                                 \
        kreg[i] = *reinterpret_cast<const short8*>(kb + (long)j * HD_ + cc8);\
        int jc = (JT) * 64 + cc8;                                            \
        if (jc + 8 <= S_) {                                                  \
            vreg[i] = *reinterpret_cast<const short8*>(vb + (long)r * S_ + jc); \
        } else {                                                             \
            short8 v;                                                        \
            _Pragma("unroll")                                                \
            for (int k = 0; k < 8; ++k)                                      \
                v[k] = ((const short*)vb)[(long)r * S_ + imin(jc + k, S_ - 1)]; \
            vreg[i] = v;                                                     \
        }                                                                    \
    }                                                                        \
} while (0)

__global__ __launch_bounds__(256) void flash_attn_kernel(
    const bf16* __restrict__ qh, const bf16* __restrict__ kh,
    const bf16* __restrict__ vhT, bf16* __restrict__ ao)
{
    const int qt = blockIdx.x, h = blockIdx.y, b = blockIdx.z;
    const int tid = threadIdx.x, w = tid >> 6, lane = tid & 63;
    const int g = lane >> 4, l15 = lane & 15, g8 = g * 8;
    const int q0 = qt * 64;
    __shared__ __align__(16) bf16 Qs[64 * 72];
    __shared__ __align__(16) bf16 Ks[64 * 72];
    __shared__ __align__(16) bf16 Vs[64 * 72];
    __shared__ __align__(16) bf16 Ps[4 * 16 * 88];
    const long bh = (long)(b * H_ + h);
    const bf16* qb = qh + bh * S_ * HD_;
    const bf16* kb = kh + bh * S_ * HD_;
    const bf16* vb = vhT + bh * HD_ * S_;

    #pragma unroll
    for (int i = 0; i < 2; ++i) {
        int ch = tid + i * 256;
        int r = ch >> 3, c8 = (ch & 7) * 8;
        int q = imin(q0 + r, S_ - 1);
        *reinterpret_cast<short8*>(&Qs[r * 72 + c8]) =
            *reinterpret_cast<const short8*>(qb + (long)q * HD_ + c8);
    }
    float lrow[4] = {};
    f32x4 O[4] = {};
    const int tstart = imax(0, q0 - (WIN_ - 1)) >> 6;
    const int tend = imin(S_ - 1, q0 + 63 + (WIN_ - 1)) >> 6;

    short8 kreg[2], vreg[2];
    PRELOAD(tstart);
    __syncthreads();
    const short8 aq0 = *reinterpret_cast<const short8*>(&Qs[(w * 16 + l15) * 72 + g8]);
    const short8 aq1 = *reinterpret_cast<const short8*>(&Qs[(w * 16 + l15) * 72 + 32 + g8]);

    for (int jt = tstart; jt <= tend; ++jt) {
        if (jt > tstart) __syncthreads();
        #pragma unroll
        for (int i = 0; i < 2; ++i) {
            int ch = tid + i * 256;
            int r = ch >> 3, c8 = (ch & 7) * 8;
            *reinterpret_cast<short8*>(&Ks[r * 72 + c8]) = kreg[i];
            *reinterpret_cast<short8*>(&Vs[r * 72 + c8]) = vreg[i];
        }
        __syncthreads();
        if (jt < tend) PRELOAD(jt + 1);

        f32x4 s[4] = {};
        __builtin_amdgcn_s_setprio(1);
        #pragma unroll
        for (int nj = 0; nj < 4; ++nj) {
            const short8 b0 = *reinterpret_cast<const short8*>(&Ks[(nj * 16 + l15) * 72 + g8]);
            const short8 b1 = *reinterpret_cast<const short8*>(&Ks[(nj * 16 + l15) * 72 + 32 + g8]);
            s[nj] = __builtin_amdgcn_mfma_f32_16x16x32_bf16(aq0, b0, s[nj], 0, 0, 0);
            s[nj] = __builtin_amdgcn_mfma_f32_16x16x32_bf16(aq1, b1, s[nj], 0, 0, 0);
        }
        __builtin_amdgcn_s_setprio(0);
        #pragma unroll
        for (int nj = 0; nj < 4; ++nj) {
            int j = jt * 64 + nj * 16 + l15;
            #pragma unroll
            for (int r = 0; r < 4; ++r) {
                int q = q0 + w * 16 + g * 4 + r;
                int dd = q - j;
                bool ok = (dd > -WIN_) && (dd < WIN_) && (q < S_) && (j < S_);
                s[nj][r] = ok ? fmaf(s[nj][r], SC2_, -MF2_) : -1e30f;
            }
        }
        #pragma unroll
        for (int r = 0; r < 4; ++r) {
            float ps = 0.f;
            #pragma unroll
            for (int nj = 0; nj < 4; ++nj) {
                float pv = exp2f(s[nj][r]);
                s[nj][r] = pv;
                ps += pv;
            }
            #pragma unroll
            for (int off = 8; off; off >>= 1) ps += __shfl_xor(ps, off, 64);
            lrow[r] += ps;
        }
        #pragma unroll
        for (int nj = 0; nj < 4; ++nj)
            #pragma unroll
            for (int r = 0; r < 4; ++r)
                Ps[w * 1408 + (g * 4 + r) * 88 + nj * 16 + l15] = __float2bfloat16(s[nj][r]);
        const short8 ap0 = *reinterpret_cast<const short8*>(&Ps[w * 1408 + l15 * 88 + g8]);
        const short8 ap1 = *reinterpret_cast<const short8*>(&Ps[w * 1408 + l15 * 88 + 32 + g8]);
        __builtin_amdgcn_s_setprio(1);
        #pragma unroll
        for (int nj = 0; nj < 4; ++nj) {
            const short8 b0 = *reinterpret_cast<const short8*>(&Vs[(nj * 16 + l15) * 72 + g8]);
            const short8 b1 = *reinterpret_cast<const short8*>(&Vs[(nj * 16 + l15) * 72 + 32 + g8]);
            O[nj] = __builtin_amdgcn_mfma_f32_16x16x32_bf16(ap0, b0, O[nj], 0, 0, 0);
            O[nj] = __builtin_amdgcn_mfma_f32_16x16x32_bf16(ap1, b1, O[nj], 0, 0, 0);
        }
        __builtin_amdgcn_s_setprio(0);
    }
    float inv[4];
    #pragma unroll
    for (int r = 0; r < 4; ++r) inv[r] = lrow[r] > 0.f ? 1.f / lrow[r] : 0.f;
    #pragma unroll
    for (int nj = 0; nj < 4; ++nj) {
        #pragma unroll
        for (int r = 0; r < 4; ++r) {
            int q = q0 + w * 16 + g * 4 + r;
            if (q < S_)
                ao[((long)b * S_ + q) * D_ + h * HD_ + nj * 16 + l15] =
                    __float2bfloat16(O[nj][r] * inv[r]);
        }
    }
}

// ---------------------------------------------------------------------------
// Launch (11 dispatches; r9: gemm64 double-buffered prefetch)
// ---------------------------------------------------------------------------
extern "C" void kernel_launch(void* const* d_in, const int* in_sizes, int n_in,
                              void* d_out, int out_size, void* d_ws, size_t ws_size,
                              hipStream_t stream)
{
    const void* x        = d_in[0];
    const void* pm       = d_in[1];
    const void* mem_keys = d_in[2];

    char* wsb = (char*)d_ws;
    bf16*  comb  = (bf16*)(wsb + 0x0);         // combined
    bf16*  qhB   = (bf16*)(wsb + 0x820000);    // attn q (B,H,S,HD)
    bf16*  khB   = (bf16*)(wsb + 0xC30000);    // attn k (B,H,S,HD)
    bf16*  vT    = (bf16*)(wsb + 0x1040000);   // vT (B,D,S) -> later: tmp (N_,512)
    bf16*  Lg    = (bf16*)(wsb + 0x1450000);   // logits bf16 (N_,2048) 17MB
    bf16*  W1    = (bf16*)(wsb + 0x2490000);   // probs: [unused | w_read] 17MB
    bf16*  W1T   = (bf16*)(wsb + 0x34D0000);   // w_write^T (B,M,S) 8.5MB
    bf16*  aobf  = (bf16*)(wsb + 0x34D0000);   // alias: ao after W1T dead
    bf16*  vhT   = (bf16*)(wsb + 0x3CF0000);   // (B,H,HD,S) 4.26MB
    bf16*  Pst   = (bf16*)(wsb + 0x4100000);   // split-K partials (10, 2^19) 10MB
    bf16*  stT   = (bf16*)(wsb + 0x4B00000);   // state^T (B,D,M) 2MB
    bf16*  BigB  = (bf16*)(wsb + 0x4D00000);   // [Wv^T | G_k | G_q] (2560,512)
    bf16*  WT    = (bf16*)(wsb + 0x4F80000);   // 7 slots: Wk,Wq plain; 5 transposed
    bf16*  mkbf  = (bf16*)(wsb + 0x5300000);   // mem_keys bf16 (M,D) 1MB
    int*   flags = (int*)(wsb + 0x5400000);
    float* csP   = (float*)(wsb + 0x5410000);  // colsum partials [5][8][512] f32
    float* stats = (float*)(wsb + 0x5440000);  // LN stats [2][N_][2] f32
    float* esum  = stats + 4 * N_;             // expsum [2][N_] f32 (contiguous)
    bf16*  tmp   = vT;                          // alias: vT dead after state GEMM

    Ptr8 p8;
    p8.p[0] = d_in[3]; p8.p[1] = d_in[4]; p8.p[2] = d_in[5]; p8.p[3] = d_in[6];
    p8.p[4] = d_in[7]; p8.p[5] = d_in[8]; p8.p[6] = d_in[9]; p8.p[7] = d_in[14];
    prep_kernel<<<1810, 256, 0, stream>>>(x, pm, mem_keys, p8, comb, mkbf, WT, BigB,
                                          flags, csP, stats);
    #define WTp(i) (WT + (long)(i) * 262144)

    // G = mem_keys @ {mem_Wk, mem_Wq}^T -> BigB rows 512..2559
    gemm64<1,64,2,0,0><<<dim3(8, 16, 2), 256, 0, stream>>>(
        mkbf, WT, BigB + 262144, nullptr, nullptr, flags, nullptr, nullptr,
        M_, 512, 512, 512, 512, 0, 262144L, 524288L, 1);

    // MEGA (128x128): comb @ BigB^T: cols<512 -> vT (transposed); rest -> Lg + esum
    gemm128_mega<<<dim3(20, 33), 256, 0, stream>>>(
        comb, BigB, Lg, vT, esum, N_, 512, 512, 512);

    // fused softmax-scale: hf0 -> W1T (transposed), hf1 -> w_read row-major
    scale_kernel<<<dim3(48, 33, 2), 256, 0, stream>>>(Lg, esum, W1T, W1 + (long)N_ * M_);

    // state^T[b] = vT[b] @ W1T[b]^T  (512 x 1024, K=2080), split-K=5
    gemm64<1,128,1,0,0><<<dim3(8, 8, 10), 256, 0, stream>>>(
        vT, W1T, Pst, nullptr, nullptr, flags, nullptr, nullptr,
        512, S_, S_, S_, 1024, (long)D_ * S_, (long)M_ * S_, (long)D_ * M_, 5);
    reduce_state_kernel<<<512, 256, 0, stream>>>(Pst, stT);

    // mem_out[b] = w_read[b] @ stT[b]^T -> tmp bf16 + LN1 row stats (stats[0])
    gemm64<1,64,2,1,0><<<dim3(8, 33, 2), 256, 0, stream>>>(
        W1 + (long)N_ * M_, stT, tmp, nullptr, nullptr, flags, stats, nullptr,
        S_, M_, M_, M_, 512, (long)S_ * M_, (long)D_ * M_, (long)S_ * D_, 1);

    // attn projections on raw tmp with LN1 fixup: q->qhB, k->khB, v->vhT
    gemm64<7,128,2,0,1><<<dim3(12, 65, 1), 256, 0, stream>>>(
        tmp, WTp(2), qhB, khB, vhT, flags, stats, csP,
        N_, 512, 512, 512, 0, 0, 0, 0, 1);

    flash_attn_kernel<<<dim3(33, H_, B_), 256, 0, stream>>>(qhB, khB, vhT, aobf);

    // ao @ Wo^T -> tmp bf16 + LN2 row stats (stats[1]); BN=64 -> 520 blocks
    gemm64<1,64,2,1,0><<<dim3(8, 65, 1), 256, 0, stream>>>(
        aobf, WTp(5), tmp, nullptr, nullptr, flags, stats + 2 * N_, nullptr,
        N_, 512, 512, 512, 512, 0, 0, 0, 1);

    // out = LN2-fixup(tmp @ outW^T) -> d_out; BN=64 -> 520 blocks; cs = csPart[4]
    gemm64<2,64,2,0,1><<<dim3(8, 65, 1), 256, 0, stream>>>(
        tmp, WTp(6), d_out, nullptr, nullptr, flags, stats + 2 * N_, csP + 4 * 4096,
        N_, 512, 512, 512, 512, 0, 0, 0, 1);
}